// Round 1
// baseline (7059.246 us; speedup 1.0000x reference)
//
#include <hip/hip_runtime.h>
#include <math.h>

#define N_NODES 20000
#define N_EDGES 320000
#define N_GRAPH 16
#define HID 256
#define NLAYER 4
#define NHEAD 4
#define DHEAD 64
#define EHID 16
#define NODE_DIMC 1280
#define ETOT (N_EDGES + N_NODES)

#define ENC_NEGMAX 0x00800000u  /* ordered-uint encoding of -FLT_MAX */

__device__ __forceinline__ float4 ld4(const float* p){ return *reinterpret_cast<const float4*>(p); }
__device__ __forceinline__ void st4(float* p, float4 v){ *reinterpret_cast<float4*>(p) = v; }
__device__ __forceinline__ float geluf(float x){ return 0.5f*x*(1.0f+erff(x*0.70710678118654752440f)); }
__device__ __forceinline__ float wsum64(float v){
  #pragma unroll
  for(int o=32;o;o>>=1) v += __shfl_xor(v,o,64);
  return v;
}
// monotonic float<->uint mapping for atomicMax on floats
__device__ __forceinline__ unsigned encF(float f){ unsigned u=__float_as_uint(f); return (u&0x80000000u)? ~u : (u|0x80000000u); }
__device__ __forceinline__ float decF(unsigned e){ unsigned u = (e&0x80000000u)? (e^0x80000000u) : ~e; return __uint_as_float(u); }

// ---------------- generic fp32 GEMM: C = A(MxK) @ B(KxN) + bias ----------------
// BM=BN=64, BK=16, 256 threads, 4x4 per thread. K%16==0, N%64==0 assumed.
__global__ __launch_bounds__(256) void k_gemm(const float* __restrict__ A, const float* __restrict__ B,
                       const float* __restrict__ bias, float* __restrict__ C,
                       int M, int N, int K){
  __shared__ float As[16][68];
  __shared__ float Bs[16][68];
  int tid = threadIdx.x;
  int bm = blockIdx.x * 64, bn = blockIdx.y * 64;
  int tr = tid >> 4, tc = tid & 15;
  float acc[4][4] = {{0.f}};
  int ar = tid >> 2;            // 0..63
  int ac = (tid & 3) * 4;       // 0,4,8,12
  int brr = tid >> 4;           // 0..15
  int bc = (tid & 15) * 4;      // 0..60
  bool aval = (bm + ar) < M;
  const float* Aptr = A + (long)(bm+ar)*K + ac;
  for(int k0=0;k0<K;k0+=16){
    float4 av = aval ? ld4(Aptr + k0) : make_float4(0.f,0.f,0.f,0.f);
    float4 bv = ld4(B + (long)(k0+brr)*N + bn + bc);
    As[ac+0][ar]=av.x; As[ac+1][ar]=av.y; As[ac+2][ar]=av.z; As[ac+3][ar]=av.w;
    st4(&Bs[brr][bc], bv);
    __syncthreads();
    #pragma unroll
    for(int kk=0;kk<16;kk++){
      float4 a4 = ld4(&As[kk][tr*4]);
      float4 b4 = ld4(&Bs[kk][tc*4]);
      float aa[4]={a4.x,a4.y,a4.z,a4.w}, bb[4]={b4.x,b4.y,b4.z,b4.w};
      #pragma unroll
      for(int i=0;i<4;i++)
        #pragma unroll
        for(int j=0;j<4;j++) acc[i][j] += aa[i]*bb[j];
    }
    __syncthreads();
  }
  #pragma unroll
  for(int i=0;i<4;i++){
    int gr = bm + tr*4 + i;
    if(gr >= M) continue;
    float4 o;
    o.x = acc[i][0] + bias[bn+tc*4+0];
    o.y = acc[i][1] + bias[bn+tc*4+1];
    o.z = acc[i][2] + bias[bn+tc*4+2];
    o.w = acc[i][3] + bias[bn+tc*4+3];
    st4(C + (long)gr*N + bn + tc*4, o);
  }
}

// ---------------- LayerNorm + GELU (input proj epilogue); one wave per row ----------------
__global__ __launch_bounds__(256) void k_ln_gelu(const float* __restrict__ in, const float* __restrict__ g,
                          const float* __restrict__ b, float* __restrict__ out){
  int gw = (int)((blockIdx.x * blockDim.x + threadIdx.x) >> 6);
  int lane = threadIdx.x & 63;
  if (gw >= N_NODES) return;
  long base = (long)gw*HID + lane*4;
  float4 v = ld4(in + base);
  float mu = wsum64(v.x+v.y+v.z+v.w) * (1.0f/HID);
  float dx=v.x-mu, dy=v.y-mu, dz=v.z-mu, dw=v.w-mu;
  float var = wsum64(dx*dx+dy*dy+dz*dz+dw*dw) * (1.0f/HID);
  float r = rsqrtf(var + 1e-5f);
  float4 gg = ld4(g + lane*4), bb = ld4(b + lane*4);
  float4 o;
  o.x = geluf(dx*r*gg.x + bb.x);
  o.y = geluf(dy*r*gg.y + bb.y);
  o.z = geluf(dz*r*gg.z + bb.z);
  o.w = geluf(dw*r*gg.w + bb.w);
  st4(out + base, o);
}

// ---------------- per-layer node epilogue: h = LN(gelu(agg+bconv)+h) ----------------
__global__ __launch_bounds__(256) void k_node_update(const float* __restrict__ agg, const float* __restrict__ bconv,
                              const float* __restrict__ g, const float* __restrict__ b,
                              float* __restrict__ h){
  int gw = (int)((blockIdx.x * blockDim.x + threadIdx.x) >> 6);
  int lane = threadIdx.x & 63;
  if (gw >= N_NODES) return;
  long base = (long)gw*HID + lane*4;
  float4 a4 = ld4(agg + base);
  float4 bc = ld4(bconv + lane*4);
  float4 h4 = ld4(h + base);
  float yx = geluf(a4.x+bc.x) + h4.x;
  float yy = geluf(a4.y+bc.y) + h4.y;
  float yz = geluf(a4.z+bc.z) + h4.z;
  float yw = geluf(a4.w+bc.w) + h4.w;
  float mu = wsum64(yx+yy+yz+yw) * (1.0f/HID);
  float dx=yx-mu, dy=yy-mu, dz=yz-mu, dw=yw-mu;
  float var = wsum64(dx*dx+dy*dy+dz*dz+dw*dw) * (1.0f/HID);
  float r = rsqrtf(var + 1e-5f);
  float4 gg = ld4(g + lane*4), bb = ld4(b + lane*4);
  float4 o;
  o.x = dx*r*gg.x + bb.x;
  o.y = dy*r*gg.y + bb.y;
  o.z = dz*r*gg.z + bb.z;
  o.w = dw*r*gg.w + bb.w;
  st4(h + base, o);
}

// ---------------- edge MLP: e = gelu(ea@W1+b1)@W2+b2; also partial sums for mean ----------------
__global__ __launch_bounds__(256) void k_edge_mlp(const float* __restrict__ ea, const float* __restrict__ W1,
                          const float* __restrict__ b1, const float* __restrict__ W2,
                          const float* __restrict__ b2, float* __restrict__ eout,
                          float* __restrict__ emean){
  __shared__ float sW1[16], sB1[16], sW2[256], sB2[16];
  int tid = threadIdx.x;
  if(tid<16){ sW1[tid]=W1[tid]; sB1[tid]=b1[tid]; sB2[tid]=b2[tid]; }
  sW2[tid] = W2[tid];
  __syncthreads();
  float local[16];
  #pragma unroll
  for(int j=0;j<16;j++) local[j]=0.f;
  for(int e = blockIdx.x*256+tid; e < N_EDGES; e += gridDim.x*256){
    float u = ea[e];
    float tv[16];
    #pragma unroll
    for(int j=0;j<16;j++) tv[j] = geluf(u*sW1[j] + sB1[j]);
    float ov[16];
    #pragma unroll
    for(int j=0;j<16;j++){
      float o = sB2[j];
      #pragma unroll
      for(int k=0;k<16;k++) o += tv[k]*sW2[k*16+j];
      ov[j] = o;
      local[j] += o;
    }
    float4* dst = (float4*)(eout + (long)e*16);
    dst[0] = make_float4(ov[0],ov[1],ov[2],ov[3]);
    dst[1] = make_float4(ov[4],ov[5],ov[6],ov[7]);
    dst[2] = make_float4(ov[8],ov[9],ov[10],ov[11]);
    dst[3] = make_float4(ov[12],ov[13],ov[14],ov[15]);
  }
  #pragma unroll
  for(int j=0;j<16;j++){
    float r = wsum64(local[j]);
    if((tid&63)==0) atomicAdd(&emean[j], r);
  }
}

// ---------------- finalize e-mean; precompute ep_loop[l] = mean(e) @ We[l] ----------------
__global__ void k_const(float* __restrict__ emean, const float* __restrict__ We, float* __restrict__ eploop){
  __shared__ float em[16];
  int tid = threadIdx.x;
  if(tid<16){ float v = emean[tid] * (1.0f/N_EDGES); em[tid]=v; emean[tid]=v; }
  __syncthreads();
  for(int l=0;l<NLAYER;l++){
    float acc = 0.f;
    #pragma unroll
    for(int k=0;k<16;k++) acc += em[k]*We[l*EHID*HID + k*HID + tid];
    eploop[l*HID + tid] = acc;
  }
}

__global__ void k_init_small(float* emean, unsigned* gmax, float* gden, float* pooled){
  int tid = threadIdx.x;
  if(tid<16){ emean[tid]=0.f; gmax[tid]=ENC_NEGMAX; gden[tid]=0.f; }
  for(int i=tid;i<N_GRAPH*HID;i+=256) pooled[i]=0.f;
}

__global__ void k_layer_init(float* __restrict__ agg, float* __restrict__ den, unsigned* __restrict__ amax){
  long i = (long)blockIdx.x*256 + threadIdx.x;
  long total = (long)N_NODES*HID;
  for(; i < total; i += (long)gridDim.x*256){
    agg[i] = 0.f;
    if(i < (long)N_NODES*NHEAD){ den[i]=0.f; amax[i]=ENC_NEGMAX; }
  }
}

// ---------------- pass A: per-edge attention logits + segment max ----------------
// one wave per edge; lane owns 4 dims; heads are 16-lane groups
__global__ __launch_bounds__(256) void k_passA(const float* __restrict__ xl, const float* __restrict__ xr,
                       const float* __restrict__ ebuf, const float* __restrict__ eploop,
                       const float* __restrict__ We_l, const float* __restrict__ att_l,
                       const int* __restrict__ ei, float* __restrict__ abuf,
                       unsigned* __restrict__ amax){
  __shared__ float sWe[EHID*HID];   // 16 KB
  __shared__ float sAtt[HID];
  int tid = threadIdx.x;
  for(int i=tid;i<EHID*HID/4;i+=256) st4(&sWe[i*4], ld4(We_l + i*4));
  if(tid < 64) st4(&sAtt[tid*4], ld4(att_l + tid*4));
  __syncthreads();
  int lane = tid & 63;
  int hh = lane >> 4;
  int wv = blockIdx.x*4 + (tid >> 6);
  int nw = gridDim.x*4;
  float4 at = ld4(&sAtt[lane*4]);
  for(int e=wv; e<ETOT; e+=nw){
    int s,d;
    if(e < N_EDGES){ s = ei[e]; d = ei[N_EDGES + e]; } else { s = e - N_EDGES; d = s; }
    float4 xl4 = ld4(xl + (long)s*HID + lane*4);
    float4 xr4 = ld4(xr + (long)d*HID + lane*4);
    float4 ep;
    if(e < N_EDGES){
      float ev = ebuf[(long)e*EHID + (lane & 15)];
      ep = make_float4(0.f,0.f,0.f,0.f);
      #pragma unroll
      for(int k=0;k<EHID;k++){
        float ek = __shfl(ev, k, 16);
        float4 w = ld4(&sWe[k*HID + lane*4]);
        ep.x += ek*w.x; ep.y += ek*w.y; ep.z += ek*w.z; ep.w += ek*w.w;
      }
    } else {
      ep = ld4(eploop + lane*4);
    }
    float mx = xl4.x+xr4.x+ep.x; mx = mx>0.f?mx:0.2f*mx;
    float my = xl4.y+xr4.y+ep.y; my = my>0.f?my:0.2f*my;
    float mz = xl4.z+xr4.z+ep.z; mz = mz>0.f?mz:0.2f*mz;
    float mw = xl4.w+xr4.w+ep.w; mw = mw>0.f?mw:0.2f*mw;
    float p = mx*at.x + my*at.y + mz*at.z + mw*at.w;
    p += __shfl_xor(p, 8, 16);
    p += __shfl_xor(p, 4, 16);
    p += __shfl_xor(p, 2, 16);
    p += __shfl_xor(p, 1, 16);
    if((lane & 15) == 0){
      abuf[(long)e*NHEAD + hh] = p;
      atomicMax(&amax[(long)d*NHEAD + hh], encF(p));
    }
  }
}

// ---------------- pass B: ex = exp(a - amax[dst]); den += ex ----------------
__global__ __launch_bounds__(256) void k_passB(float* __restrict__ abuf, const unsigned* __restrict__ amax,
                        float* __restrict__ den, const int* __restrict__ ei){
  long idx = (long)blockIdx.x*256 + threadIdx.x;
  if(idx >= (long)ETOT*NHEAD) return;
  int e = (int)(idx >> 2), hh = (int)(idx & 3);
  int d = (e < N_EDGES) ? ei[N_EDGES+e] : (e - N_EDGES);
  float m = decF(amax[(long)d*NHEAD+hh]);
  float ex = expf(abuf[idx] - m);
  abuf[idx] = ex;
  atomicAdd(&den[(long)d*NHEAD+hh], ex);
}

// ---------------- pass C: agg[dst] += alpha * xl[src] ----------------
__global__ __launch_bounds__(256) void k_passC(const float* __restrict__ abuf, const float* __restrict__ den,
                       const float* __restrict__ xl, const int* __restrict__ ei,
                       float* __restrict__ agg){
  int tid = threadIdx.x;
  int lane = tid & 63;
  int hh = lane >> 4;
  int wv = blockIdx.x*4 + (tid>>6);
  int nw = gridDim.x*4;
  for(int e=wv;e<ETOT;e+=nw){
    int s,d;
    if(e<N_EDGES){ s=ei[e]; d=ei[N_EDGES+e]; } else { s=e-N_EDGES; d=s; }
    float ex = abuf[(long)e*NHEAD+hh];
    float dn = den[(long)d*NHEAD+hh];
    float alpha = ex/dn;
    float4 v = ld4(xl + (long)s*HID + lane*4);
    float* base = agg + (long)d*HID + lane*4;
    atomicAdd(base+0, alpha*v.x);
    atomicAdd(base+1, alpha*v.y);
    atomicAdd(base+2, alpha*v.z);
    atomicAdd(base+3, alpha*v.w);
  }
}

// ---------------- gate MLP: gate = tanh(h@Wg1+bg1)@Wg2+bg2; segment max ----------------
__global__ __launch_bounds__(128) void k_gate(const float* __restrict__ h, const float* __restrict__ Wg1,
                      const float* __restrict__ bg1, const float* __restrict__ Wg2,
                      const float* __restrict__ bg2, const int* __restrict__ batch,
                      float* __restrict__ gate, unsigned* __restrict__ gmax){
  __shared__ float sh[HID];
  __shared__ float part[2];
  int v = blockIdx.x;
  int tid = threadIdx.x;
  sh[tid]      = h[(long)v*HID + tid];
  sh[tid+128]  = h[(long)v*HID + tid + 128];
  __syncthreads();
  float acc = bg1[tid];
  #pragma unroll 8
  for(int k=0;k<HID;k++) acc += sh[k]*Wg1[k*128 + tid];
  float t = tanhf(acc);
  float contrib = t * Wg2[tid];
  float r = wsum64(contrib);
  if((tid&63)==0) part[tid>>6] = r;
  __syncthreads();
  if(tid==0){
    float gv = part[0] + part[1] + bg2[0];
    gate[v] = gv;
    atomicMax(&gmax[batch[v]], encF(gv));
  }
}

__global__ __launch_bounds__(256) void k_gsoft(const float* __restrict__ gate, const int* __restrict__ batch,
                        const unsigned* __restrict__ gmax, float* __restrict__ gexp,
                        float* __restrict__ gden){
  int v = blockIdx.x*256 + threadIdx.x;
  if(v >= N_NODES) return;
  int b = batch[v];
  float ex = expf(gate[v] - decF(gmax[b]));
  gexp[v] = ex;
  atomicAdd(&gden[b], ex);
}

// ---------------- pooled[b] += w[v] * h[v]; batch is sorted -> register accumulate ----------------
__global__ __launch_bounds__(256) void k_pool(const float* __restrict__ h, const float* __restrict__ gexp,
                      const float* __restrict__ gden, const int* __restrict__ batch,
                      float* __restrict__ pooled){
  int c = threadIdx.x;
  int v0 = blockIdx.x * 128;
  float acc = 0.f;
  int cur = -1;
  for(int i=0;i<128;i++){
    int v = v0 + i;
    if(v >= N_NODES) break;
    int b = batch[v];
    if(b != cur){
      if(cur >= 0) atomicAdd(&pooled[cur*HID + c], acc);
      acc = 0.f; cur = b;
    }
    float w = gexp[v] / gden[b];
    acc += w * h[(long)v*HID + c];
  }
  if(cur >= 0) atomicAdd(&pooled[cur*HID + c], acc);
}

// ---------------- head: out = gelu(pooled@Wh1+bh1)@Wh2+bh2 ----------------
__global__ __launch_bounds__(64) void k_head(const float* __restrict__ pooled, const float* __restrict__ Wh1,
                      const float* __restrict__ bh1, const float* __restrict__ Wh2,
                      const float* __restrict__ bh2, float* __restrict__ out){
  __shared__ float sp[HID];
  int b = blockIdx.x, t = threadIdx.x;
  #pragma unroll
  for(int i=0;i<4;i++) sp[t + i*64] = pooled[b*HID + t + i*64];
  __syncthreads();
  float acc = bh1[t];
  #pragma unroll 8
  for(int k=0;k<HID;k++) acc += sp[k]*Wh1[k*64 + t];
  float g = geluf(acc);
  float contrib = g * Wh2[t];
  float r = wsum64(contrib);
  if(t==0) out[b] = r + bh2[0];
}

extern "C" void kernel_launch(void* const* d_in, const int* in_sizes, int n_in,
                              void* d_out, int out_size, void* d_ws, size_t ws_size,
                              hipStream_t stream) {
  const float* x        = (const float*)d_in[0];
  const float* edge_attr= (const float*)d_in[1];
  const float* W_in     = (const float*)d_in[2];
  const float* b_in     = (const float*)d_in[3];
  const float* ln_in_g  = (const float*)d_in[4];
  const float* ln_in_b  = (const float*)d_in[5];
  const float* W_e1     = (const float*)d_in[6];
  const float* b_e1     = (const float*)d_in[7];
  const float* W_e2     = (const float*)d_in[8];
  const float* b_e2     = (const float*)d_in[9];
  const float* Wl       = (const float*)d_in[10];
  const float* bl       = (const float*)d_in[11];
  const float* Wr       = (const float*)d_in[12];
  const float* br       = (const float*)d_in[13];
  const float* att      = (const float*)d_in[14];
  const float* We       = (const float*)d_in[15];
  const float* bconv    = (const float*)d_in[16];
  const float* ln_g     = (const float*)d_in[17];
  const float* ln_b     = (const float*)d_in[18];
  const float* Wg1      = (const float*)d_in[19];
  const float* bg1      = (const float*)d_in[20];
  const float* Wg2      = (const float*)d_in[21];
  const float* bg2      = (const float*)d_in[22];
  const float* Wh1      = (const float*)d_in[23];
  const float* bh1      = (const float*)d_in[24];
  const float* Wh2      = (const float*)d_in[25];
  const float* bh2      = (const float*)d_in[26];
  const int*   ei       = (const int*)d_in[27];
  const int*   batch    = (const int*)d_in[28];
  float* out = (float*)d_out;

  float* ws = (float*)d_ws;
  float* buf_h    = ws;                       // N*HID
  float* buf_t    = ws + 5120000;             // N*HID (gemm tmp / agg)
  float* buf_xl   = ws + 10240000;            // N*HID
  float* buf_xr   = ws + 15360000;            // N*HID
  float* buf_e    = ws + 20480000;            // E*16
  float* buf_a    = ws + 25600000;            // (E+N)*4
  unsigned* buf_amax = (unsigned*)(ws + 26960000); // N*4
  float* buf_den  = ws + 27040000;            // N*4
  float* buf_emean= ws + 27120000;            // 16
  float* buf_eploop = ws + 27120016;          // 4*256
  float* buf_gate = ws + 27121040;            // N
  float* buf_gexp = ws + 27141040;            // N
  unsigned* buf_gmax = (unsigned*)(ws + 27161040); // 16
  float* buf_gden = ws + 27161056;            // 16
  float* buf_pooled = ws + 27161072;          // 16*256

  dim3 gIn((N_NODES+63)/64, HID/64);

  k_init_small<<<1,256,0,stream>>>(buf_emean, buf_gmax, buf_gden, buf_pooled);
  k_gemm<<<gIn,256,0,stream>>>(x, W_in, b_in, buf_t, N_NODES, HID, NODE_DIMC);
  k_ln_gelu<<<(N_NODES+3)/4,256,0,stream>>>(buf_t, ln_in_g, ln_in_b, buf_h);
  k_edge_mlp<<<512,256,0,stream>>>(edge_attr, W_e1, b_e1, W_e2, b_e2, buf_e, buf_emean);
  k_const<<<1,256,0,stream>>>(buf_emean, We, buf_eploop);

  for(int l=0;l<NLAYER;l++){
    k_layer_init<<<2048,256,0,stream>>>(buf_t, buf_den, buf_amax);
    k_gemm<<<gIn,256,0,stream>>>(buf_h, Wl + l*HID*HID, bl + l*HID, buf_xl, N_NODES, HID, HID);
    k_gemm<<<gIn,256,0,stream>>>(buf_h, Wr + l*HID*HID, br + l*HID, buf_xr, N_NODES, HID, HID);
    k_passA<<<1024,256,0,stream>>>(buf_xl, buf_xr, buf_e, buf_eploop + l*HID,
                                   We + l*EHID*HID, att + l*NHEAD*DHEAD, ei, buf_a, buf_amax);
    k_passB<<<((long)ETOT*NHEAD+255)/256,256,0,stream>>>(buf_a, buf_amax, buf_den, ei);
    k_passC<<<1024,256,0,stream>>>(buf_a, buf_den, buf_xl, ei, buf_t);
    k_node_update<<<(N_NODES+3)/4,256,0,stream>>>(buf_t, bconv + l*HID, ln_g + l*HID, ln_b + l*HID, buf_h);
  }

  k_gate<<<N_NODES,128,0,stream>>>(buf_h, Wg1, bg1, Wg2, bg2, batch, buf_gate, buf_gmax);
  k_gsoft<<<(N_NODES+255)/256,256,0,stream>>>(buf_gate, batch, buf_gmax, buf_gexp, buf_gden);
  k_pool<<<(N_NODES+127)/128,256,0,stream>>>(buf_h, buf_gexp, buf_gden, batch, buf_pooled);
  k_head<<<N_GRAPH,64,0,stream>>>(buf_pooled, Wh1, bh1, Wh2, bh2, out);
}

// Round 2
// 2333.680 us; speedup vs baseline: 3.0249x; 3.0249x over previous
//
#include <hip/hip_runtime.h>
#include <math.h>

#define N_NODES 20000
#define N_EDGES 320000
#define N_GRAPH 16
#define HID 256
#define NLAYER 4
#define NHEAD 4
#define DHEAD 64
#define EHID 16
#define NODE_DIMC 1280

#define ENC_NEGMAX 0x00800000u  /* ordered-uint encoding of -FLT_MAX */

__device__ __forceinline__ float4 ld4(const float* p){ return *reinterpret_cast<const float4*>(p); }
__device__ __forceinline__ void st4(float* p, float4 v){ *reinterpret_cast<float4*>(p) = v; }
__device__ __forceinline__ float geluf(float x){ return 0.5f*x*(1.0f+erff(x*0.70710678118654752440f)); }
__device__ __forceinline__ float wsum64(float v){
  #pragma unroll
  for(int o=32;o;o>>=1) v += __shfl_xor(v,o,64);
  return v;
}
__device__ __forceinline__ unsigned encF(float f){ unsigned u=__float_as_uint(f); return (u&0x80000000u)? ~u : (u|0x80000000u); }
__device__ __forceinline__ float decF(unsigned e){ unsigned u = (e&0x80000000u)? (e^0x80000000u) : ~e; return __uint_as_float(u); }

// ---------------- generic fp32 GEMM: C = A(MxK) @ B(KxN) + bias ----------------
__global__ __launch_bounds__(256) void k_gemm(const float* __restrict__ A, const float* __restrict__ B,
                       const float* __restrict__ bias, float* __restrict__ C,
                       int M, int N, int K){
  __shared__ float As[16][68];
  __shared__ float Bs[16][68];
  int tid = threadIdx.x;
  int bm = blockIdx.x * 64, bn = blockIdx.y * 64;
  int tr = tid >> 4, tc = tid & 15;
  float acc[4][4] = {{0.f}};
  int ar = tid >> 2;
  int ac = (tid & 3) * 4;
  int brr = tid >> 4;
  int bc = (tid & 15) * 4;
  bool aval = (bm + ar) < M;
  const float* Aptr = A + (long)(bm+ar)*K + ac;
  for(int k0=0;k0<K;k0+=16){
    float4 av = aval ? ld4(Aptr + k0) : make_float4(0.f,0.f,0.f,0.f);
    float4 bv = ld4(B + (long)(k0+brr)*N + bn + bc);
    As[ac+0][ar]=av.x; As[ac+1][ar]=av.y; As[ac+2][ar]=av.z; As[ac+3][ar]=av.w;
    st4(&Bs[brr][bc], bv);
    __syncthreads();
    #pragma unroll
    for(int kk=0;kk<16;kk++){
      float4 a4 = ld4(&As[kk][tr*4]);
      float4 b4 = ld4(&Bs[kk][tc*4]);
      float aa[4]={a4.x,a4.y,a4.z,a4.w}, bb[4]={b4.x,b4.y,b4.z,b4.w};
      #pragma unroll
      for(int i=0;i<4;i++)
        #pragma unroll
        for(int j=0;j<4;j++) acc[i][j] += aa[i]*bb[j];
    }
    __syncthreads();
  }
  #pragma unroll
  for(int i=0;i<4;i++){
    int gr = bm + tr*4 + i;
    if(gr >= M) continue;
    float4 o;
    o.x = acc[i][0] + bias[bn+tc*4+0];
    o.y = acc[i][1] + bias[bn+tc*4+1];
    o.z = acc[i][2] + bias[bn+tc*4+2];
    o.w = acc[i][3] + bias[bn+tc*4+3];
    st4(C + (long)gr*N + bn + tc*4, o);
  }
}

// ---------------- LayerNorm + GELU (input proj epilogue) ----------------
__global__ __launch_bounds__(256) void k_ln_gelu(const float* __restrict__ in, const float* __restrict__ g,
                          const float* __restrict__ b, float* __restrict__ out){
  int gw = (int)((blockIdx.x * blockDim.x + threadIdx.x) >> 6);
  int lane = threadIdx.x & 63;
  if (gw >= N_NODES) return;
  long base = (long)gw*HID + lane*4;
  float4 v = ld4(in + base);
  float mu = wsum64(v.x+v.y+v.z+v.w) * (1.0f/HID);
  float dx=v.x-mu, dy=v.y-mu, dz=v.z-mu, dw=v.w-mu;
  float var = wsum64(dx*dx+dy*dy+dz*dz+dw*dw) * (1.0f/HID);
  float r = rsqrtf(var + 1e-5f);
  float4 gg = ld4(g + lane*4), bb = ld4(b + lane*4);
  float4 o;
  o.x = geluf(dx*r*gg.x + bb.x);
  o.y = geluf(dy*r*gg.y + bb.y);
  o.z = geluf(dz*r*gg.z + bb.z);
  o.w = geluf(dw*r*gg.w + bb.w);
  st4(out + base, o);
}

// ---------------- edge MLP + partial sums for mean ----------------
__global__ __launch_bounds__(256) void k_edge_mlp(const float* __restrict__ ea, const float* __restrict__ W1,
                          const float* __restrict__ b1, const float* __restrict__ W2,
                          const float* __restrict__ b2, float* __restrict__ eout,
                          float* __restrict__ emean){
  __shared__ float sW1[16], sB1[16], sW2[256], sB2[16];
  int tid = threadIdx.x;
  if(tid<16){ sW1[tid]=W1[tid]; sB1[tid]=b1[tid]; sB2[tid]=b2[tid]; }
  sW2[tid] = W2[tid];
  __syncthreads();
  float local[16];
  #pragma unroll
  for(int j=0;j<16;j++) local[j]=0.f;
  for(int e = blockIdx.x*256+tid; e < N_EDGES; e += gridDim.x*256){
    float u = ea[e];
    float tv[16];
    #pragma unroll
    for(int j=0;j<16;j++) tv[j] = geluf(u*sW1[j] + sB1[j]);
    float ov[16];
    #pragma unroll
    for(int j=0;j<16;j++){
      float o = sB2[j];
      #pragma unroll
      for(int k=0;k<16;k++) o += tv[k]*sW2[k*16+j];
      ov[j] = o;
      local[j] += o;
    }
    float4* dst = (float4*)(eout + (long)e*16);
    dst[0] = make_float4(ov[0],ov[1],ov[2],ov[3]);
    dst[1] = make_float4(ov[4],ov[5],ov[6],ov[7]);
    dst[2] = make_float4(ov[8],ov[9],ov[10],ov[11]);
    dst[3] = make_float4(ov[12],ov[13],ov[14],ov[15]);
  }
  #pragma unroll
  for(int j=0;j<16;j++){
    float r = wsum64(local[j]);
    if((tid&63)==0) atomicAdd(&emean[j], r);
  }
}

// ---------------- finalize e-mean; ep_loop[l] = mean(e) @ We[l] ----------------
__global__ void k_const(float* __restrict__ emean, const float* __restrict__ We, float* __restrict__ eploop){
  __shared__ float em[16];
  int tid = threadIdx.x;
  if(tid<16){ float v = emean[tid] * (1.0f/N_EDGES); em[tid]=v; emean[tid]=v; }
  __syncthreads();
  for(int l=0;l<NLAYER;l++){
    float acc = 0.f;
    #pragma unroll
    for(int k=0;k<16;k++) acc += em[k]*We[l*EHID*HID + k*HID + tid];
    eploop[l*HID + tid] = acc;
  }
}

__global__ void k_init_small(float* emean, unsigned* gmax, float* gden, float* pooled){
  int tid = threadIdx.x;
  if(tid<16){ emean[tid]=0.f; gmax[tid]=ENC_NEGMAX; gden[tid]=0.f; }
  for(int i=tid;i<N_GRAPH*HID;i+=256) pooled[i]=0.f;
}

// ---------------- CSR build ----------------
__global__ __launch_bounds__(256) void k_csr_zero(int* __restrict__ counts){
  int i = blockIdx.x*256 + threadIdx.x;
  if(i < N_NODES) counts[i] = 0;
}

__global__ __launch_bounds__(256) void k_csr_count(const int* __restrict__ ei, int* __restrict__ counts){
  int e = blockIdx.x*256 + threadIdx.x;
  if(e < N_EDGES) atomicAdd(&counts[ei[N_EDGES + e]], 1);
}

// single block, 1024 threads: exclusive scan of counts -> offs; cursor = offs copy
__global__ __launch_bounds__(1024) void k_csr_scan(const int* __restrict__ counts, int* __restrict__ offs,
                                                   int* __restrict__ cursor){
  __shared__ int part[1024];
  int t = threadIdx.x;
  const int chunk = (N_NODES + 1023) / 1024;   // 20
  int b0 = t * chunk;
  int s = 0;
  for(int i=0;i<chunk;i++){ int idx=b0+i; if(idx<N_NODES) s += counts[idx]; }
  part[t] = s;
  __syncthreads();
  for(int off=1; off<1024; off<<=1){
    int v = part[t];
    int add = (t>=off) ? part[t-off] : 0;
    __syncthreads();
    part[t] = v + add;
    __syncthreads();
  }
  int run = (t==0) ? 0 : part[t-1];
  for(int i=0;i<chunk;i++){
    int idx = b0+i;
    if(idx < N_NODES){
      int c = counts[idx];
      offs[idx] = run; cursor[idx] = run;
      run += c;
    }
  }
  if(t == 1023) offs[N_NODES] = part[1023];
}

__global__ __launch_bounds__(256) void k_csr_fill(const int* __restrict__ ei, int* __restrict__ cursor,
                          int* __restrict__ csr_src, int* __restrict__ csr_eid){
  int e = blockIdx.x*256 + threadIdx.x;
  if(e >= N_EDGES) return;
  int d = ei[N_EDGES + e];
  int pos = atomicAdd(&cursor[d], 1);
  csr_src[pos] = ei[e];
  csr_eid[pos] = e;
}

// ---------------- fused per-layer: gather + online segment-softmax + agg + GELU + residual + LN ----------------
// one wave per dst node (grid-stride); lane owns 4 contiguous dims; head = lane>>4
#define LAYER_BLOCKS 1280
__global__ __launch_bounds__(256) void k_layer(
    const float* __restrict__ xl, const float* __restrict__ xr,
    float* __restrict__ h, const float* __restrict__ ebuf,
    const float* __restrict__ eploop_l, const float* __restrict__ We_l,
    const float* __restrict__ att_l, const int* __restrict__ offs,
    const int* __restrict__ csr_src, const int* __restrict__ csr_eid,
    const float* __restrict__ bconv_l, const float* __restrict__ g_l,
    const float* __restrict__ b_l){
  int lane = threadIdx.x & 63;
  int wv = blockIdx.x*4 + (threadIdx.x >> 6);
  const int NW = LAYER_BLOCKS*4;
  // We columns for this lane's 4 dims, all 16 k-rows, in registers
  float4 rW[16];
  #pragma unroll
  for(int k=0;k<16;k++) rW[k] = ld4(We_l + k*HID + lane*4);
  float4 at4 = ld4(att_l + lane*4);   // att[(lane>>4)][ (lane&15)*4 .. ] == att_l + lane*4
  float4 epl = ld4(eploop_l + lane*4);
  float4 bc4 = ld4(bconv_l + lane*4);
  float4 gg4 = ld4(g_l + lane*4);
  float4 bb4 = ld4(b_l + lane*4);
  for(int d = wv; d < N_NODES; d += NW){
    long dbase = (long)d*HID + lane*4;
    float4 xr4 = ld4(xr + dbase);
    float4 xld = ld4(xl + dbase);
    // ---- self-loop seeds the online softmax ----
    float ax = xld.x + xr4.x + epl.x; ax = ax>0.f?ax:0.2f*ax;
    float ay = xld.y + xr4.y + epl.y; ay = ay>0.f?ay:0.2f*ay;
    float az = xld.z + xr4.z + epl.z; az = az>0.f?az:0.2f*az;
    float aw = xld.w + xr4.w + epl.w; aw = aw>0.f?aw:0.2f*aw;
    float p = ax*at4.x + ay*at4.y + az*at4.z + aw*at4.w;
    p += __shfl_xor(p, 1, 16);
    p += __shfl_xor(p, 2, 16);
    p += __shfl_xor(p, 4, 16);
    p += __shfl_xor(p, 8, 16);
    float m_run = p;
    float den = 1.f;
    float4 acc = xld;
    int beg = offs[d], end = offs[d+1];
    for(int i=beg;i<end;i++){
      int s = csr_src[i];
      int eid = csr_eid[i];
      float4 xs = ld4(xl + (long)s*HID + lane*4);
      const float4* ev = (const float4*)(ebuf + (long)eid*EHID);
      float4 e0 = ev[0], e1 = ev[1], e2 = ev[2], e3 = ev[3];
      float evs[16] = {e0.x,e0.y,e0.z,e0.w, e1.x,e1.y,e1.z,e1.w,
                       e2.x,e2.y,e2.z,e2.w, e3.x,e3.y,e3.z,e3.w};
      float epx=0.f, epy=0.f, epz=0.f, epw=0.f;
      #pragma unroll
      for(int k=0;k<16;k++){
        epx += evs[k]*rW[k].x; epy += evs[k]*rW[k].y;
        epz += evs[k]*rW[k].z; epw += evs[k]*rW[k].w;
      }
      float mx = xs.x + xr4.x + epx; mx = mx>0.f?mx:0.2f*mx;
      float my = xs.y + xr4.y + epy; my = my>0.f?my:0.2f*my;
      float mz = xs.z + xr4.z + epz; mz = mz>0.f?mz:0.2f*mz;
      float mw = xs.w + xr4.w + epw; mw = mw>0.f?mw:0.2f*mw;
      float q = mx*at4.x + my*at4.y + mz*at4.z + mw*at4.w;
      q += __shfl_xor(q, 1, 16);
      q += __shfl_xor(q, 2, 16);
      q += __shfl_xor(q, 4, 16);
      q += __shfl_xor(q, 8, 16);
      float nm = fmaxf(m_run, q);
      float sc = __expf(m_run - nm);
      float pe = __expf(q - nm);
      den = den*sc + pe;
      acc.x = acc.x*sc + pe*xs.x;
      acc.y = acc.y*sc + pe*xs.y;
      acc.z = acc.z*sc + pe*xs.z;
      acc.w = acc.w*sc + pe*xs.w;
      m_run = nm;
    }
    float inv = 1.f/den;
    float4 h4 = ld4(h + dbase);
    float yx = geluf(acc.x*inv + bc4.x) + h4.x;
    float yy = geluf(acc.y*inv + bc4.y) + h4.y;
    float yz = geluf(acc.z*inv + bc4.z) + h4.z;
    float yw = geluf(acc.w*inv + bc4.w) + h4.w;
    float mu = wsum64(yx+yy+yz+yw) * (1.0f/HID);
    float dx=yx-mu, dy=yy-mu, dz=yz-mu, dw=yw-mu;
    float var = wsum64(dx*dx+dy*dy+dz*dz+dw*dw) * (1.0f/HID);
    float r = rsqrtf(var + 1e-5f);
    float4 o;
    o.x = dx*r*gg4.x + bb4.x;
    o.y = dy*r*gg4.y + bb4.y;
    o.z = dz*r*gg4.z + bb4.z;
    o.w = dw*r*gg4.w + bb4.w;
    st4(h + dbase, o);
  }
}

// ---------------- gate MLP ----------------
__global__ __launch_bounds__(128) void k_gate(const float* __restrict__ h, const float* __restrict__ Wg1,
                      const float* __restrict__ bg1, const float* __restrict__ Wg2,
                      const float* __restrict__ bg2, const int* __restrict__ batch,
                      float* __restrict__ gate, unsigned* __restrict__ gmax){
  __shared__ float sh[HID];
  __shared__ float part[2];
  int v = blockIdx.x;
  int tid = threadIdx.x;
  sh[tid]      = h[(long)v*HID + tid];
  sh[tid+128]  = h[(long)v*HID + tid + 128];
  __syncthreads();
  float acc = bg1[tid];
  #pragma unroll 8
  for(int k=0;k<HID;k++) acc += sh[k]*Wg1[k*128 + tid];
  float t = tanhf(acc);
  float contrib = t * Wg2[tid];
  float r = wsum64(contrib);
  if((tid&63)==0) part[tid>>6] = r;
  __syncthreads();
  if(tid==0){
    float gv = part[0] + part[1] + bg2[0];
    gate[v] = gv;
    atomicMax(&gmax[batch[v]], encF(gv));
  }
}

__global__ __launch_bounds__(256) void k_gsoft(const float* __restrict__ gate, const int* __restrict__ batch,
                        const unsigned* __restrict__ gmax, float* __restrict__ gexp,
                        float* __restrict__ gden){
  int v = blockIdx.x*256 + threadIdx.x;
  if(v >= N_NODES) return;
  int b = batch[v];
  float ex = expf(gate[v] - decF(gmax[b]));
  gexp[v] = ex;
  atomicAdd(&gden[b], ex);
}

__global__ __launch_bounds__(256) void k_pool(const float* __restrict__ h, const float* __restrict__ gexp,
                      const float* __restrict__ gden, const int* __restrict__ batch,
                      float* __restrict__ pooled){
  int c = threadIdx.x;
  int v0 = blockIdx.x * 128;
  float acc = 0.f;
  int cur = -1;
  for(int i=0;i<128;i++){
    int v = v0 + i;
    if(v >= N_NODES) break;
    int b = batch[v];
    if(b != cur){
      if(cur >= 0) atomicAdd(&pooled[cur*HID + c], acc);
      acc = 0.f; cur = b;
    }
    float w = gexp[v] / gden[b];
    acc += w * h[(long)v*HID + c];
  }
  if(cur >= 0) atomicAdd(&pooled[cur*HID + c], acc);
}

__global__ __launch_bounds__(64) void k_head(const float* __restrict__ pooled, const float* __restrict__ Wh1,
                      const float* __restrict__ bh1, const float* __restrict__ Wh2,
                      const float* __restrict__ bh2, float* __restrict__ out){
  __shared__ float sp[HID];
  int b = blockIdx.x, t = threadIdx.x;
  #pragma unroll
  for(int i=0;i<4;i++) sp[t + i*64] = pooled[b*HID + t + i*64];
  __syncthreads();
  float acc = bh1[t];
  #pragma unroll 8
  for(int k=0;k<HID;k++) acc += sp[k]*Wh1[k*64 + t];
  float g = geluf(acc);
  float contrib = g * Wh2[t];
  float r = wsum64(contrib);
  if(t==0) out[b] = r + bh2[0];
}

extern "C" void kernel_launch(void* const* d_in, const int* in_sizes, int n_in,
                              void* d_out, int out_size, void* d_ws, size_t ws_size,
                              hipStream_t stream) {
  const float* x        = (const float*)d_in[0];
  const float* edge_attr= (const float*)d_in[1];
  const float* W_in     = (const float*)d_in[2];
  const float* b_in     = (const float*)d_in[3];
  const float* ln_in_g  = (const float*)d_in[4];
  const float* ln_in_b  = (const float*)d_in[5];
  const float* W_e1     = (const float*)d_in[6];
  const float* b_e1     = (const float*)d_in[7];
  const float* W_e2     = (const float*)d_in[8];
  const float* b_e2     = (const float*)d_in[9];
  const float* Wl       = (const float*)d_in[10];
  const float* bl       = (const float*)d_in[11];
  const float* Wr       = (const float*)d_in[12];
  const float* br       = (const float*)d_in[13];
  const float* att      = (const float*)d_in[14];
  const float* We       = (const float*)d_in[15];
  const float* bconv    = (const float*)d_in[16];
  const float* ln_g     = (const float*)d_in[17];
  const float* ln_b     = (const float*)d_in[18];
  const float* Wg1      = (const float*)d_in[19];
  const float* bg1      = (const float*)d_in[20];
  const float* Wg2      = (const float*)d_in[21];
  const float* bg2      = (const float*)d_in[22];
  const float* Wh1      = (const float*)d_in[23];
  const float* bh1      = (const float*)d_in[24];
  const float* Wh2      = (const float*)d_in[25];
  const float* bh2      = (const float*)d_in[26];
  const int*   ei       = (const int*)d_in[27];
  const int*   batch    = (const int*)d_in[28];
  float* out = (float*)d_out;

  float* ws = (float*)d_ws;
  float* buf_h    = ws;                        // N*HID
  float* buf_t    = ws + 5120000;              // N*HID (input-proj tmp)
  float* buf_xl   = ws + 10240000;             // N*HID
  float* buf_xr   = ws + 15360000;             // N*HID
  float* buf_e    = ws + 20480000;             // E*16
  float* buf_emean= ws + 25600000;             // 16
  float* buf_eploop = ws + 25600016;           // 4*256
  float* buf_gate = ws + 25601040;             // N
  float* buf_gexp = ws + 25621040;             // N
  unsigned* buf_gmax = (unsigned*)(ws + 25641040); // 16
  float* buf_gden = ws + 25641056;             // 16
  float* buf_pooled = ws + 25641072;           // 16*256
  int* csr_offs   = (int*)(ws + 25645200);     // N+1
  int* csr_cursor = (int*)(ws + 25665300);     // N
  int* csr_src    = (int*)(ws + 25685300);     // E
  int* csr_eid    = (int*)(ws + 26005300);     // E

  dim3 gIn((N_NODES+63)/64, HID/64);

  k_init_small<<<1,256,0,stream>>>(buf_emean, buf_gmax, buf_gden, buf_pooled);
  // CSR over dst (counts use csr_cursor as scratch)
  k_csr_zero<<<(N_NODES+255)/256,256,0,stream>>>(csr_cursor);
  k_csr_count<<<(N_EDGES+255)/256,256,0,stream>>>(ei, csr_cursor);
  k_csr_scan<<<1,1024,0,stream>>>(csr_cursor, csr_offs, csr_cursor);
  k_csr_fill<<<(N_EDGES+255)/256,256,0,stream>>>(ei, csr_cursor, csr_src, csr_eid);

  k_gemm<<<gIn,256,0,stream>>>(x, W_in, b_in, buf_t, N_NODES, HID, NODE_DIMC);
  k_ln_gelu<<<(N_NODES+3)/4,256,0,stream>>>(buf_t, ln_in_g, ln_in_b, buf_h);
  k_edge_mlp<<<512,256,0,stream>>>(edge_attr, W_e1, b_e1, W_e2, b_e2, buf_e, buf_emean);
  k_const<<<1,256,0,stream>>>(buf_emean, We, buf_eploop);

  for(int l=0;l<NLAYER;l++){
    k_gemm<<<gIn,256,0,stream>>>(buf_h, Wl + l*HID*HID, bl + l*HID, buf_xl, N_NODES, HID, HID);
    k_gemm<<<gIn,256,0,stream>>>(buf_h, Wr + l*HID*HID, br + l*HID, buf_xr, N_NODES, HID, HID);
    k_layer<<<LAYER_BLOCKS,256,0,stream>>>(buf_xl, buf_xr, buf_h, buf_e,
                                   buf_eploop + l*HID, We + l*EHID*HID, att + l*NHEAD*DHEAD,
                                   csr_offs, csr_src, csr_eid,
                                   bconv + l*HID, ln_g + l*HID, ln_b + l*HID);
  }

  k_gate<<<N_NODES,128,0,stream>>>(buf_h, Wg1, bg1, Wg2, bg2, batch, buf_gate, buf_gmax);
  k_gsoft<<<(N_NODES+255)/256,256,0,stream>>>(buf_gate, batch, buf_gmax, buf_gexp, buf_gden);
  k_pool<<<(N_NODES+127)/128,256,0,stream>>>(buf_h, buf_gexp, buf_gden, batch, buf_pooled);
  k_head<<<N_GRAPH,64,0,stream>>>(buf_pooled, Wh1, bh1, Wh2, bh2, out);
}

// Round 3
// 1517.007 us; speedup vs baseline: 4.6534x; 1.5383x over previous
//
#include <hip/hip_runtime.h>
#include <math.h>

#define N_NODES 20000
#define N_EDGES 320000
#define N_GRAPH 16
#define HID 256
#define NLAYER 4
#define NHEAD 4
#define DHEAD 64
#define EHID 16
#define NODE_DIMC 1280
#define EMLP_BLOCKS 1250   /* 1250*256 == 320000 exactly */

__device__ __forceinline__ float4 ld4(const float* p){ return *reinterpret_cast<const float4*>(p); }
__device__ __forceinline__ void st4(float* p, float4 v){ *reinterpret_cast<float4*>(p) = v; }
__device__ __forceinline__ float geluf(float x){ return 0.5f*x*(1.0f+erff(x*0.70710678118654752440f)); }
__device__ __forceinline__ float wsum64(float v){
  #pragma unroll
  for(int o=32;o;o>>=1) v += __shfl_xor(v,o,64);
  return v;
}
__device__ __forceinline__ float wmax64(float v){
  #pragma unroll
  for(int o=32;o;o>>=1) v = fmaxf(v, __shfl_xor(v,o,64));
  return v;
}
__device__ __forceinline__ int lbound(const int* __restrict__ a, int val){
  int lo=0, hi=N_NODES;
  while(lo<hi){ int mid=(lo+hi)>>1; if(a[mid]<val) lo=mid+1; else hi=mid; }
  return lo;
}

// ---------------- generic fp32 GEMM: C = A(MxK) @ B(KxN) + bias ----------------
__global__ __launch_bounds__(256) void k_gemm(const float* __restrict__ A, const float* __restrict__ B,
                       const float* __restrict__ bias, float* __restrict__ C,
                       int M, int N, int K){
  __shared__ float As[16][68];
  __shared__ float Bs[16][68];
  int tid = threadIdx.x;
  int bm = blockIdx.x * 64, bn = blockIdx.y * 64;
  int tr = tid >> 4, tc = tid & 15;
  float acc[4][4] = {{0.f}};
  int ar = tid >> 2;
  int ac = (tid & 3) * 4;
  int brr = tid >> 4;
  int bc = (tid & 15) * 4;
  bool aval = (bm + ar) < M;
  const float* Aptr = A + (long)(bm+ar)*K + ac;
  for(int k0=0;k0<K;k0+=16){
    float4 av = aval ? ld4(Aptr + k0) : make_float4(0.f,0.f,0.f,0.f);
    float4 bv = ld4(B + (long)(k0+brr)*N + bn + bc);
    As[ac+0][ar]=av.x; As[ac+1][ar]=av.y; As[ac+2][ar]=av.z; As[ac+3][ar]=av.w;
    st4(&Bs[brr][bc], bv);
    __syncthreads();
    #pragma unroll
    for(int kk=0;kk<16;kk++){
      float4 a4 = ld4(&As[kk][tr*4]);
      float4 b4 = ld4(&Bs[kk][tc*4]);
      float aa[4]={a4.x,a4.y,a4.z,a4.w}, bb[4]={b4.x,b4.y,b4.z,b4.w};
      #pragma unroll
      for(int i=0;i<4;i++)
        #pragma unroll
        for(int j=0;j<4;j++) acc[i][j] += aa[i]*bb[j];
    }
    __syncthreads();
  }
  #pragma unroll
  for(int i=0;i<4;i++){
    int gr = bm + tr*4 + i;
    if(gr >= M) continue;
    float4 o;
    o.x = acc[i][0] + bias[bn+tc*4+0];
    o.y = acc[i][1] + bias[bn+tc*4+1];
    o.z = acc[i][2] + bias[bn+tc*4+2];
    o.w = acc[i][3] + bias[bn+tc*4+3];
    st4(C + (long)gr*N + bn + tc*4, o);
  }
}

// ---------------- LayerNorm + GELU (input proj epilogue) ----------------
__global__ __launch_bounds__(256) void k_ln_gelu(const float* __restrict__ in, const float* __restrict__ g,
                          const float* __restrict__ b, float* __restrict__ out){
  int gw = (int)((blockIdx.x * blockDim.x + threadIdx.x) >> 6);
  int lane = threadIdx.x & 63;
  if (gw >= N_NODES) return;
  long base = (long)gw*HID + lane*4;
  float4 v = ld4(in + base);
  float mu = wsum64(v.x+v.y+v.z+v.w) * (1.0f/HID);
  float dx=v.x-mu, dy=v.y-mu, dz=v.z-mu, dw=v.w-mu;
  float var = wsum64(dx*dx+dy*dy+dz*dz+dw*dw) * (1.0f/HID);
  float r = rsqrtf(var + 1e-5f);
  float4 gg = ld4(g + lane*4), bb = ld4(b + lane*4);
  float4 o;
  o.x = geluf(dx*r*gg.x + bb.x);
  o.y = geluf(dy*r*gg.y + bb.y);
  o.z = geluf(dz*r*gg.z + bb.z);
  o.w = geluf(dw*r*gg.w + bb.w);
  st4(out + base, o);
}

// ---------------- edge MLP; per-block partial sums (NO hot-line atomics) ----------------
__global__ __launch_bounds__(256) void k_edge_mlp(const float* __restrict__ ea, const float* __restrict__ W1,
                          const float* __restrict__ b1, const float* __restrict__ W2,
                          const float* __restrict__ b2, float* __restrict__ eout,
                          float* __restrict__ epart){
  __shared__ float sW1[16], sB1[16], sW2[256], sB2[16];
  __shared__ float red[4][16];
  int tid = threadIdx.x;
  if(tid<16){ sW1[tid]=W1[tid]; sB1[tid]=b1[tid]; sB2[tid]=b2[tid]; }
  sW2[tid] = W2[tid];
  __syncthreads();
  int e = blockIdx.x*256 + tid;   // exact cover: 1250*256 == N_EDGES
  float u = ea[e];
  float tv[16];
  #pragma unroll
  for(int j=0;j<16;j++) tv[j] = geluf(u*sW1[j] + sB1[j]);
  float ov[16];
  #pragma unroll
  for(int j=0;j<16;j++){
    float o = sB2[j];
    #pragma unroll
    for(int k=0;k<16;k++) o += tv[k]*sW2[k*16+j];
    ov[j] = o;
  }
  float4* dst = (float4*)(eout + (long)e*16);
  dst[0] = make_float4(ov[0],ov[1],ov[2],ov[3]);
  dst[1] = make_float4(ov[4],ov[5],ov[6],ov[7]);
  dst[2] = make_float4(ov[8],ov[9],ov[10],ov[11]);
  dst[3] = make_float4(ov[12],ov[13],ov[14],ov[15]);
  int wv = tid >> 6, lane = tid & 63;
  #pragma unroll
  for(int j=0;j<16;j++){
    float r = wsum64(ov[j]);
    if(lane == 0) red[wv][j] = r;
  }
  __syncthreads();
  if(tid < 16) epart[blockIdx.x*16 + tid] = red[0][tid]+red[1][tid]+red[2][tid]+red[3][tid];
}

// ---------------- reduce epart -> mean; ep_loop[l] = mean(e) @ We[l] ----------------
__global__ __launch_bounds__(256) void k_const(const float* __restrict__ epart, const float* __restrict__ We,
                                               float* __restrict__ eploop){
  __shared__ float red[16][16];
  __shared__ float em[16];
  int tid = threadIdx.x;
  int j = tid & 15, p0 = tid >> 4;
  float s = 0.f;
  for(int p = p0; p < EMLP_BLOCKS; p += 16) s += epart[p*16 + j];
  red[p0][j] = s;
  __syncthreads();
  if(tid < 16){
    float t = 0.f;
    #pragma unroll
    for(int k=0;k<16;k++) t += red[k][tid];
    em[tid] = t * (1.0f/N_EDGES);
  }
  __syncthreads();
  for(int l=0;l<NLAYER;l++){
    float acc = 0.f;
    #pragma unroll
    for(int k=0;k<16;k++) acc += em[k]*We[l*EHID*HID + k*HID + tid];
    eploop[l*HID + tid] = acc;
  }
}

__global__ void k_init_small(float* pooled){
  int tid = threadIdx.x;
  for(int i=tid;i<N_GRAPH*HID;i+=256) pooled[i]=0.f;
}

// ---------------- CSR build ----------------
__global__ __launch_bounds__(256) void k_csr_zero(int* __restrict__ counts){
  int i = blockIdx.x*256 + threadIdx.x;
  if(i < N_NODES) counts[i] = 0;
}

__global__ __launch_bounds__(256) void k_csr_count(const int* __restrict__ ei, int* __restrict__ counts){
  int e = blockIdx.x*256 + threadIdx.x;
  if(e < N_EDGES) atomicAdd(&counts[ei[N_EDGES + e]], 1);
}

__global__ __launch_bounds__(1024) void k_csr_scan(const int* __restrict__ counts, int* __restrict__ offs,
                                                   int* __restrict__ cursor){
  __shared__ int part[1024];
  int t = threadIdx.x;
  const int chunk = (N_NODES + 1023) / 1024;
  int b0 = t * chunk;
  int s = 0;
  for(int i=0;i<chunk;i++){ int idx=b0+i; if(idx<N_NODES) s += counts[idx]; }
  part[t] = s;
  __syncthreads();
  for(int off=1; off<1024; off<<=1){
    int v = part[t];
    int add = (t>=off) ? part[t-off] : 0;
    __syncthreads();
    part[t] = v + add;
    __syncthreads();
  }
  int run = (t==0) ? 0 : part[t-1];
  for(int i=0;i<chunk;i++){
    int idx = b0+i;
    if(idx < N_NODES){
      int c = counts[idx];
      offs[idx] = run; cursor[idx] = run;
      run += c;
    }
  }
  if(t == 1023) offs[N_NODES] = part[1023];
}

__global__ __launch_bounds__(256) void k_csr_fill(const int* __restrict__ ei, int* __restrict__ cursor,
                          int* __restrict__ csr_src, int* __restrict__ csr_eid){
  int e = blockIdx.x*256 + threadIdx.x;
  if(e >= N_EDGES) return;
  int d = ei[N_EDGES + e];
  int pos = atomicAdd(&cursor[d], 1);
  csr_src[pos] = ei[e];
  csr_eid[pos] = e;
}

// ---------------- fused per-layer: gather + online segment-softmax + agg + GELU + residual + LN ----------------
#define LAYER_BLOCKS 1280
__global__ __launch_bounds__(256) void k_layer(
    const float* __restrict__ xl, const float* __restrict__ xr,
    float* __restrict__ h, const float* __restrict__ ebuf,
    const float* __restrict__ eploop_l, const float* __restrict__ We_l,
    const float* __restrict__ att_l, const int* __restrict__ offs,
    const int* __restrict__ csr_src, const int* __restrict__ csr_eid,
    const float* __restrict__ bconv_l, const float* __restrict__ g_l,
    const float* __restrict__ b_l){
  int lane = threadIdx.x & 63;
  int wv = blockIdx.x*4 + (threadIdx.x >> 6);
  const int NW = LAYER_BLOCKS*4;
  float4 rW[16];
  #pragma unroll
  for(int k=0;k<16;k++) rW[k] = ld4(We_l + k*HID + lane*4);
  float4 at4 = ld4(att_l + lane*4);
  float4 epl = ld4(eploop_l + lane*4);
  float4 bc4 = ld4(bconv_l + lane*4);
  float4 gg4 = ld4(g_l + lane*4);
  float4 bb4 = ld4(b_l + lane*4);
  for(int d = wv; d < N_NODES; d += NW){
    long dbase = (long)d*HID + lane*4;
    float4 xr4 = ld4(xr + dbase);
    float4 xld = ld4(xl + dbase);
    float ax = xld.x + xr4.x + epl.x; ax = ax>0.f?ax:0.2f*ax;
    float ay = xld.y + xr4.y + epl.y; ay = ay>0.f?ay:0.2f*ay;
    float az = xld.z + xr4.z + epl.z; az = az>0.f?az:0.2f*az;
    float aw = xld.w + xr4.w + epl.w; aw = aw>0.f?aw:0.2f*aw;
    float p = ax*at4.x + ay*at4.y + az*at4.z + aw*at4.w;
    p += __shfl_xor(p, 1, 16);
    p += __shfl_xor(p, 2, 16);
    p += __shfl_xor(p, 4, 16);
    p += __shfl_xor(p, 8, 16);
    float m_run = p;
    float den = 1.f;
    float4 acc = xld;
    int beg = offs[d], end = offs[d+1];
    for(int i=beg;i<end;i++){
      int s = csr_src[i];
      int eid = csr_eid[i];
      float4 xs = ld4(xl + (long)s*HID + lane*4);
      const float4* ev = (const float4*)(ebuf + (long)eid*EHID);
      float4 e0 = ev[0], e1 = ev[1], e2 = ev[2], e3 = ev[3];
      float evs[16] = {e0.x,e0.y,e0.z,e0.w, e1.x,e1.y,e1.z,e1.w,
                       e2.x,e2.y,e2.z,e2.w, e3.x,e3.y,e3.z,e3.w};
      float epx=0.f, epy=0.f, epz=0.f, epw=0.f;
      #pragma unroll
      for(int k=0;k<16;k++){
        epx += evs[k]*rW[k].x; epy += evs[k]*rW[k].y;
        epz += evs[k]*rW[k].z; epw += evs[k]*rW[k].w;
      }
      float mx = xs.x + xr4.x + epx; mx = mx>0.f?mx:0.2f*mx;
      float my = xs.y + xr4.y + epy; my = my>0.f?my:0.2f*my;
      float mz = xs.z + xr4.z + epz; mz = mz>0.f?mz:0.2f*mz;
      float mw = xs.w + xr4.w + epw; mw = mw>0.f?mw:0.2f*mw;
      float q = mx*at4.x + my*at4.y + mz*at4.z + mw*at4.w;
      q += __shfl_xor(q, 1, 16);
      q += __shfl_xor(q, 2, 16);
      q += __shfl_xor(q, 4, 16);
      q += __shfl_xor(q, 8, 16);
      float nm = fmaxf(m_run, q);
      float sc = __expf(m_run - nm);
      float pe = __expf(q - nm);
      den = den*sc + pe;
      acc.x = acc.x*sc + pe*xs.x;
      acc.y = acc.y*sc + pe*xs.y;
      acc.z = acc.z*sc + pe*xs.z;
      acc.w = acc.w*sc + pe*xs.w;
      m_run = nm;
    }
    float inv = 1.f/den;
    float4 h4 = ld4(h + dbase);
    float yx = geluf(acc.x*inv + bc4.x) + h4.x;
    float yy = geluf(acc.y*inv + bc4.y) + h4.y;
    float yz = geluf(acc.z*inv + bc4.z) + h4.z;
    float yw = geluf(acc.w*inv + bc4.w) + h4.w;
    float mu = wsum64(yx+yy+yz+yw) * (1.0f/HID);
    float dx=yx-mu, dy=yy-mu, dz=yz-mu, dw=yw-mu;
    float var = wsum64(dx*dx+dy*dy+dz*dz+dw*dw) * (1.0f/HID);
    float r = rsqrtf(var + 1e-5f);
    float4 o;
    o.x = dx*r*gg4.x + bb4.x;
    o.y = dy*r*gg4.y + bb4.y;
    o.z = dz*r*gg4.z + bb4.z;
    o.w = dw*r*gg4.w + bb4.w;
    st4(h + dbase, o);
  }
}

// ---------------- gate value per node: gate[v] = tanh(gh[v]) . Wg2 + bg2 ----------------
// gh = h@Wg1+bg1 computed by k_gemm. One wave per node; lane owns 2 of 128 dims.
__global__ __launch_bounds__(256) void k_gate2(const float* __restrict__ gh, const float* __restrict__ Wg2,
                       const float* __restrict__ bg2, float* __restrict__ gate){
  int gw = (int)((blockIdx.x * blockDim.x + threadIdx.x) >> 6);
  int lane = threadIdx.x & 63;
  if(gw >= N_NODES) return;
  const float* p = gh + (long)gw*128 + lane*2;
  float t0 = tanhf(p[0]) * Wg2[lane*2];
  float t1 = tanhf(p[1]) * Wg2[lane*2+1];
  float r = wsum64(t0 + t1);
  if(lane == 0) gate[gw] = r + bg2[0];
}

// ---------------- per-graph softmax stats: gmax[b], gden[b] ----------------
__global__ __launch_bounds__(256) void k_gsm(const float* __restrict__ gate, const int* __restrict__ batch,
                     float* __restrict__ gmax, float* __restrict__ gden){
  __shared__ int sr[2];
  __shared__ float red[4];
  int g = blockIdx.x, tid = threadIdx.x;
  if(tid == 0){ sr[0] = lbound(batch, g); sr[1] = lbound(batch, g+1); }
  __syncthreads();
  int r0 = sr[0], r1 = sr[1];
  float mx = -3.4e38f;
  for(int v = r0 + tid; v < r1; v += 256) mx = fmaxf(mx, gate[v]);
  mx = wmax64(mx);
  if((tid&63)==0) red[tid>>6] = mx;
  __syncthreads();
  float m = fmaxf(fmaxf(red[0],red[1]), fmaxf(red[2],red[3]));
  float s = 0.f;
  for(int v = r0 + tid; v < r1; v += 256) s += __expf(gate[v] - m);
  s = wsum64(s);
  if((tid&63)==0) red[tid>>6] = s;
  __syncthreads();
  if(tid == 0){
    gmax[g] = m;
    gden[g] = red[0]+red[1]+red[2]+red[3];
  }
}

// ---------------- pooled[g] += w[v]*h[v]; grid (chunks=16, graphs=16) ----------------
__global__ __launch_bounds__(256) void k_gpool(const float* __restrict__ h, const float* __restrict__ gate,
                       const float* __restrict__ gmax, const float* __restrict__ gden,
                       const int* __restrict__ batch, float* __restrict__ pooled){
  __shared__ int sr[2];
  int g = blockIdx.y, c = threadIdx.x;
  if(c == 0){ sr[0] = lbound(batch, g); sr[1] = lbound(batch, g+1); }
  __syncthreads();
  int r0 = sr[0], r1 = sr[1];
  float m = gmax[g], inv = 1.f/gden[g];
  float acc = 0.f;
  for(int v = r0 + blockIdx.x; v < r1; v += 16){
    float w = __expf(gate[v] - m) * inv;
    acc += w * h[(long)v*HID + c];
  }
  atomicAdd(&pooled[g*HID + c], acc);
}

__global__ __launch_bounds__(64) void k_head(const float* __restrict__ pooled, const float* __restrict__ Wh1,
                      const float* __restrict__ bh1, const float* __restrict__ Wh2,
                      const float* __restrict__ bh2, float* __restrict__ out){
  __shared__ float sp[HID];
  int b = blockIdx.x, t = threadIdx.x;
  #pragma unroll
  for(int i=0;i<4;i++) sp[t + i*64] = pooled[b*HID + t + i*64];
  __syncthreads();
  float acc = bh1[t];
  #pragma unroll 8
  for(int k=0;k<HID;k++) acc += sp[k]*Wh1[k*64 + t];
  float g = geluf(acc);
  float contrib = g * Wh2[t];
  float r = wsum64(contrib);
  if(t==0) out[b] = r + bh2[0];
}

extern "C" void kernel_launch(void* const* d_in, const int* in_sizes, int n_in,
                              void* d_out, int out_size, void* d_ws, size_t ws_size,
                              hipStream_t stream) {
  const float* x        = (const float*)d_in[0];
  const float* edge_attr= (const float*)d_in[1];
  const float* W_in     = (const float*)d_in[2];
  const float* b_in     = (const float*)d_in[3];
  const float* ln_in_g  = (const float*)d_in[4];
  const float* ln_in_b  = (const float*)d_in[5];
  const float* W_e1     = (const float*)d_in[6];
  const float* b_e1     = (const float*)d_in[7];
  const float* W_e2     = (const float*)d_in[8];
  const float* b_e2     = (const float*)d_in[9];
  const float* Wl       = (const float*)d_in[10];
  const float* bl       = (const float*)d_in[11];
  const float* Wr       = (const float*)d_in[12];
  const float* br       = (const float*)d_in[13];
  const float* att      = (const float*)d_in[14];
  const float* We       = (const float*)d_in[15];
  const float* bconv    = (const float*)d_in[16];
  const float* ln_g     = (const float*)d_in[17];
  const float* ln_b     = (const float*)d_in[18];
  const float* Wg1      = (const float*)d_in[19];
  const float* bg1      = (const float*)d_in[20];
  const float* Wg2      = (const float*)d_in[21];
  const float* bg2      = (const float*)d_in[22];
  const float* Wh1      = (const float*)d_in[23];
  const float* bh1      = (const float*)d_in[24];
  const float* Wh2      = (const float*)d_in[25];
  const float* bh2      = (const float*)d_in[26];
  const int*   ei       = (const int*)d_in[27];
  const int*   batch    = (const int*)d_in[28];
  float* out = (float*)d_out;

  float* ws = (float*)d_ws;
  float* buf_h    = ws;                        // N*HID
  float* buf_t    = ws + 5120000;              // N*HID (input-proj tmp; reused later)
  float* buf_xl   = ws + 10240000;             // N*HID
  float* buf_xr   = ws + 15360000;             // N*HID
  float* buf_e    = ws + 20480000;             // E*16
  float* buf_eploop = ws + 25600016;           // 4*256
  float* buf_gate = ws + 25601040;             // N
  float* buf_gmax = ws + 25621040;             // 16
  float* buf_gden = ws + 25621056;             // 16
  float* buf_pooled = ws + 25621072;           // 16*256
  int* csr_offs   = (int*)(ws + 25645200);     // N+1
  int* csr_cursor = (int*)(ws + 25665300);     // N
  int* csr_src    = (int*)(ws + 25685300);     // E
  int* csr_eid    = (int*)(ws + 26005300);     // E
  // buf_t reuse (free after k_ln_gelu): gate hidden (N*128) and edge partials
  float* buf_gh   = buf_t;                     // N*128 = 2.56M
  float* buf_epart= buf_t + 2600000;           // 1250*16

  dim3 gIn((N_NODES+63)/64, HID/64);

  k_init_small<<<1,256,0,stream>>>(buf_pooled);
  k_csr_zero<<<(N_NODES+255)/256,256,0,stream>>>(csr_cursor);
  k_csr_count<<<(N_EDGES+255)/256,256,0,stream>>>(ei, csr_cursor);
  k_csr_scan<<<1,1024,0,stream>>>(csr_cursor, csr_offs, csr_cursor);
  k_csr_fill<<<(N_EDGES+255)/256,256,0,stream>>>(ei, csr_cursor, csr_src, csr_eid);

  k_gemm<<<gIn,256,0,stream>>>(x, W_in, b_in, buf_t, N_NODES, HID, NODE_DIMC);
  k_ln_gelu<<<(N_NODES+3)/4,256,0,stream>>>(buf_t, ln_in_g, ln_in_b, buf_h);
  k_edge_mlp<<<EMLP_BLOCKS,256,0,stream>>>(edge_attr, W_e1, b_e1, W_e2, b_e2, buf_e, buf_epart);
  k_const<<<1,256,0,stream>>>(buf_epart, We, buf_eploop);

  for(int l=0;l<NLAYER;l++){
    k_gemm<<<gIn,256,0,stream>>>(buf_h, Wl + l*HID*HID, bl + l*HID, buf_xl, N_NODES, HID, HID);
    k_gemm<<<gIn,256,0,stream>>>(buf_h, Wr + l*HID*HID, br + l*HID, buf_xr, N_NODES, HID, HID);
    k_layer<<<LAYER_BLOCKS,256,0,stream>>>(buf_xl, buf_xr, buf_h, buf_e,
                                   buf_eploop + l*HID, We + l*EHID*HID, att + l*NHEAD*DHEAD,
                                   csr_offs, csr_src, csr_eid,
                                   bconv + l*HID, ln_g + l*HID, ln_b + l*HID);
  }

  dim3 gG((N_NODES+63)/64, 128/64);
  k_gemm<<<gG,256,0,stream>>>(buf_h, Wg1, bg1, buf_gh, N_NODES, 128, HID);
  k_gate2<<<(N_NODES+3)/4,256,0,stream>>>(buf_gh, Wg2, bg2, buf_gate);
  k_gsm<<<N_GRAPH,256,0,stream>>>(buf_gate, batch, buf_gmax, buf_gden);
  dim3 gP(16, N_GRAPH);
  k_gpool<<<gP,256,0,stream>>>(buf_h, buf_gate, buf_gmax, buf_gden, batch, buf_pooled);
  k_head<<<N_GRAPH,64,0,stream>>>(buf_pooled, Wh1, bh1, Wh2, bh2, out);
}

// Round 4
// 1183.748 us; speedup vs baseline: 5.9635x; 1.2815x over previous
//
#include <hip/hip_runtime.h>
#include <hip/hip_bf16.h>
#include <math.h>

#define N_NODES 20000
#define N_EDGES 320000
#define N_GRAPH 16
#define HID 256
#define NLAYER 4
#define NHEAD 4
#define DHEAD 64
#define EHID 16
#define NODE_DIMC 1280
#define EMLP_BLOCKS 1250   /* 1250*256 == 320000 exactly */
#define XLRS 512           /* stride of combined xl|xr buffer */

typedef short short8 __attribute__((ext_vector_type(8)));
typedef float f32x4 __attribute__((ext_vector_type(4)));

__device__ __forceinline__ float4 ld4(const float* p){ return *reinterpret_cast<const float4*>(p); }
__device__ __forceinline__ void st4(float* p, float4 v){ *reinterpret_cast<float4*>(p) = v; }
__device__ __forceinline__ float geluf(float x){ return 0.5f*x*(1.0f+erff(x*0.70710678118654752440f)); }
__device__ __forceinline__ float wsum64(float v){
  #pragma unroll
  for(int o=32;o;o>>=1) v += __shfl_xor(v,o,64);
  return v;
}
__device__ __forceinline__ float wmax64(float v){
  #pragma unroll
  for(int o=32;o;o>>=1) v = fmaxf(v, __shfl_xor(v,o,64));
  return v;
}
__device__ __forceinline__ int lbound(const int* __restrict__ a, int val){
  int lo=0, hi=N_NODES;
  while(lo<hi){ int mid=(lo+hi)>>1; if(a[mid]<val) lo=mid+1; else hi=mid; }
  return lo;
}
__device__ __forceinline__ short cvt_bf16(float f){
  __hip_bfloat16 h = __float2bfloat16(f);
  return *reinterpret_cast<short*>(&h);
}

// ---------------- weight transpose + cvt: Wt[n*K+k] = bf16(W[k*N+n]) ----------------
__global__ __launch_bounds__(256) void k_wt(const float* __restrict__ W, short* __restrict__ Wt, int K, int N){
  int idx = blockIdx.x*256 + threadIdx.x;
  if(idx >= K*N) return;
  int n = idx / K, k = idx - n*K;
  Wt[idx] = cvt_bf16(W[(long)k*N + n]);
}

__global__ void k_bcat(const float* __restrict__ bl, const float* __restrict__ br, float* __restrict__ blr){
  int t = threadIdx.x;
  for(int l=0;l<NLAYER;l++){
    blr[l*512 + t]       = bl[l*256 + t];
    blr[l*512 + 256 + t] = br[l*256 + t];
  }
}

// ---------------- bf16 MFMA GEMM: C = A(MxK,fp32) @ Bt(N x K, bf16)^T + bias ----------------
// BM=128, BN=128 (grid.y covers N/128), BK=32, 256 thr, wave w -> rows [w*32,w*32+32)
__global__ __launch_bounds__(256) void k_gemm_bf16(const float* __restrict__ A,
    const short* __restrict__ Bt, const float* __restrict__ bias,
    float* __restrict__ C, int M, int K, int ldc){
  __shared__ short As[128][40];
  __shared__ short Bs[128][40];
  int tid = threadIdx.x;
  int bm = blockIdx.x*128, bn = blockIdx.y*128;
  int w = tid>>6, lane = tid&63;
  int g = lane>>4, m = lane&15;
  f32x4 acc[2][8];
  #pragma unroll
  for(int i=0;i<2;i++)
    #pragma unroll
    for(int j=0;j<8;j++) acc[i][j] = (f32x4){0.f,0.f,0.f,0.f};
  int arow = tid>>1;
  int akoff = (tid&1)*16;
  bool aval = (bm+arow) < M;
  const float* Ap = A + (long)(bm+arow)*K + akoff;
  for(int k0=0;k0<K;k0+=32){
    short8 p0, p1;
    if(aval){
      float4 f0 = ld4(Ap+k0+0), f1 = ld4(Ap+k0+4), f2 = ld4(Ap+k0+8), f3 = ld4(Ap+k0+12);
      p0[0]=cvt_bf16(f0.x); p0[1]=cvt_bf16(f0.y); p0[2]=cvt_bf16(f0.z); p0[3]=cvt_bf16(f0.w);
      p0[4]=cvt_bf16(f1.x); p0[5]=cvt_bf16(f1.y); p0[6]=cvt_bf16(f1.z); p0[7]=cvt_bf16(f1.w);
      p1[0]=cvt_bf16(f2.x); p1[1]=cvt_bf16(f2.y); p1[2]=cvt_bf16(f2.z); p1[3]=cvt_bf16(f2.w);
      p1[4]=cvt_bf16(f3.x); p1[5]=cvt_bf16(f3.y); p1[6]=cvt_bf16(f3.z); p1[7]=cvt_bf16(f3.w);
    } else {
      p0 = (short8){0,0,0,0,0,0,0,0}; p1 = p0;
    }
    *(short8*)&As[arow][akoff]   = p0;
    *(short8*)&As[arow][akoff+8] = p1;
    // B: 128 rows x 32 k bf16 -> 512 chunks of 16B; 2 per thread
    #pragma unroll
    for(int c = tid; c < 512; c += 256){
      int brow = c>>2, bk = (c&3)*8;
      *(short8*)&Bs[brow][bk] = *(const short8*)&Bt[(long)(bn+brow)*K + k0 + bk];
    }
    __syncthreads();
    short8 af0 = *(short8*)&As[w*32 + m][g*8];
    short8 af1 = *(short8*)&As[w*32 + 16 + m][g*8];
    #pragma unroll
    for(int j=0;j<8;j++){
      short8 bf = *(short8*)&Bs[j*16 + m][g*8];
      acc[0][j] = __builtin_amdgcn_mfma_f32_16x16x32_bf16(af0, bf, acc[0][j], 0,0,0);
      acc[1][j] = __builtin_amdgcn_mfma_f32_16x16x32_bf16(af1, bf, acc[1][j], 0,0,0);
    }
    __syncthreads();
  }
  #pragma unroll
  for(int i=0;i<2;i++){
    int r0 = bm + w*32 + i*16 + g*4;
    #pragma unroll
    for(int j=0;j<8;j++){
      int col = bn + j*16 + m;
      float bv = bias[col];
      #pragma unroll
      for(int r=0;r<4;r++){
        int row = r0 + r;
        if(row < M) C[(long)row*ldc + col] = acc[i][j][r] + bv;
      }
    }
  }
}

// ---------------- LayerNorm + GELU (input proj epilogue) ----------------
__global__ __launch_bounds__(256) void k_ln_gelu(const float* __restrict__ in, const float* __restrict__ g,
                          const float* __restrict__ b, float* __restrict__ out){
  int gw = (int)((blockIdx.x * blockDim.x + threadIdx.x) >> 6);
  int lane = threadIdx.x & 63;
  if (gw >= N_NODES) return;
  long base = (long)gw*HID + lane*4;
  float4 v = ld4(in + base);
  float mu = wsum64(v.x+v.y+v.z+v.w) * (1.0f/HID);
  float dx=v.x-mu, dy=v.y-mu, dz=v.z-mu, dw=v.w-mu;
  float var = wsum64(dx*dx+dy*dy+dz*dz+dw*dw) * (1.0f/HID);
  float r = rsqrtf(var + 1e-5f);
  float4 gg = ld4(g + lane*4), bb = ld4(b + lane*4);
  float4 o;
  o.x = geluf(dx*r*gg.x + bb.x);
  o.y = geluf(dy*r*gg.y + bb.y);
  o.z = geluf(dz*r*gg.z + bb.z);
  o.w = geluf(dw*r*gg.w + bb.w);
  st4(out + base, o);
}

// ---------------- edge MLP; per-block partial sums ----------------
__global__ __launch_bounds__(256) void k_edge_mlp(const float* __restrict__ ea, const float* __restrict__ W1,
                          const float* __restrict__ b1, const float* __restrict__ W2,
                          const float* __restrict__ b2, float* __restrict__ eout,
                          float* __restrict__ epart){
  __shared__ float sW1[16], sB1[16], sW2[256], sB2[16];
  __shared__ float red[4][16];
  int tid = threadIdx.x;
  if(tid<16){ sW1[tid]=W1[tid]; sB1[tid]=b1[tid]; sB2[tid]=b2[tid]; }
  sW2[tid] = W2[tid];
  __syncthreads();
  int e = blockIdx.x*256 + tid;
  float u = ea[e];
  float tv[16];
  #pragma unroll
  for(int j=0;j<16;j++) tv[j] = geluf(u*sW1[j] + sB1[j]);
  float ov[16];
  #pragma unroll
  for(int j=0;j<16;j++){
    float o = sB2[j];
    #pragma unroll
    for(int k=0;k<16;k++) o += tv[k]*sW2[k*16+j];
    ov[j] = o;
  }
  float4* dst = (float4*)(eout + (long)e*16);
  dst[0] = make_float4(ov[0],ov[1],ov[2],ov[3]);
  dst[1] = make_float4(ov[4],ov[5],ov[6],ov[7]);
  dst[2] = make_float4(ov[8],ov[9],ov[10],ov[11]);
  dst[3] = make_float4(ov[12],ov[13],ov[14],ov[15]);
  int wv = tid >> 6, lane = tid & 63;
  #pragma unroll
  for(int j=0;j<16;j++){
    float r = wsum64(ov[j]);
    if(lane == 0) red[wv][j] = r;
  }
  __syncthreads();
  if(tid < 16) epart[blockIdx.x*16 + tid] = red[0][tid]+red[1][tid]+red[2][tid]+red[3][tid];
}

// ---------------- reduce epart -> mean; ep_loop[l] = mean(e) @ We[l] ----------------
__global__ __launch_bounds__(256) void k_const(const float* __restrict__ epart, const float* __restrict__ We,
                                               float* __restrict__ eploop){
  __shared__ float red[16][16];
  __shared__ float em[16];
  int tid = threadIdx.x;
  int j = tid & 15, p0 = tid >> 4;
  float s = 0.f;
  for(int p = p0; p < EMLP_BLOCKS; p += 16) s += epart[p*16 + j];
  red[p0][j] = s;
  __syncthreads();
  if(tid < 16){
    float t = 0.f;
    #pragma unroll
    for(int k=0;k<16;k++) t += red[k][tid];
    em[tid] = t * (1.0f/N_EDGES);
  }
  __syncthreads();
  for(int l=0;l<NLAYER;l++){
    float acc = 0.f;
    #pragma unroll
    for(int k=0;k<16;k++) acc += em[k]*We[l*EHID*HID + k*HID + tid];
    eploop[l*HID + tid] = acc;
  }
}

__global__ void k_init_small(float* pooled){
  int tid = threadIdx.x;
  for(int i=tid;i<N_GRAPH*HID;i+=256) pooled[i]=0.f;
}

// ---------------- CSR build ----------------
__global__ __launch_bounds__(256) void k_csr_zero(int* __restrict__ counts){
  int i = blockIdx.x*256 + threadIdx.x;
  if(i < N_NODES) counts[i] = 0;
}

__global__ __launch_bounds__(256) void k_csr_count(const int* __restrict__ ei, int* __restrict__ counts){
  int e = blockIdx.x*256 + threadIdx.x;
  if(e < N_EDGES) atomicAdd(&counts[ei[N_EDGES + e]], 1);
}

__global__ __launch_bounds__(1024) void k_csr_scan(const int* __restrict__ counts, int* __restrict__ offs,
                                                   int* __restrict__ cursor){
  __shared__ int part[1024];
  int t = threadIdx.x;
  const int chunk = (N_NODES + 1023) / 1024;
  int b0 = t * chunk;
  int s = 0;
  for(int i=0;i<chunk;i++){ int idx=b0+i; if(idx<N_NODES) s += counts[idx]; }
  part[t] = s;
  __syncthreads();
  for(int off=1; off<1024; off<<=1){
    int v = part[t];
    int add = (t>=off) ? part[t-off] : 0;
    __syncthreads();
    part[t] = v + add;
    __syncthreads();
  }
  int run = (t==0) ? 0 : part[t-1];
  for(int i=0;i<chunk;i++){
    int idx = b0+i;
    if(idx < N_NODES){
      int c = counts[idx];
      offs[idx] = run; cursor[idx] = run;
      run += c;
    }
  }
  if(t == 1023) offs[N_NODES] = part[1023];
}

__global__ __launch_bounds__(256) void k_csr_fill(const int* __restrict__ ei, int* __restrict__ cursor,
                          int* __restrict__ csr_src, int* __restrict__ csr_eid){
  int e = blockIdx.x*256 + threadIdx.x;
  if(e >= N_EDGES) return;
  int d = ei[N_EDGES + e];
  int pos = atomicAdd(&cursor[d], 1);
  csr_src[pos] = ei[e];
  csr_eid[pos] = e;
}

// ---------------- fused per-layer: gather + online segment-softmax + agg + GELU + residual + LN ----------------
// xlr: [N][512], cols 0..255 = xl, 256..511 = xr
#define LAYER_BLOCKS 1280
__global__ __launch_bounds__(256) void k_layer(
    const float* __restrict__ xlr, float* __restrict__ h, const float* __restrict__ ebuf,
    const float* __restrict__ eploop_l, const float* __restrict__ We_l,
    const float* __restrict__ att_l, const int* __restrict__ offs,
    const int* __restrict__ csr_src, const int* __restrict__ csr_eid,
    const float* __restrict__ bconv_l, const float* __restrict__ g_l,
    const float* __restrict__ b_l){
  int lane = threadIdx.x & 63;
  int wv = blockIdx.x*4 + (threadIdx.x >> 6);
  const int NW = LAYER_BLOCKS*4;
  float4 rW[16];
  #pragma unroll
  for(int k=0;k<16;k++) rW[k] = ld4(We_l + k*HID + lane*4);
  float4 at4 = ld4(att_l + lane*4);
  float4 epl = ld4(eploop_l + lane*4);
  float4 bc4 = ld4(bconv_l + lane*4);
  float4 gg4 = ld4(g_l + lane*4);
  float4 bb4 = ld4(b_l + lane*4);
  for(int d = wv; d < N_NODES; d += NW){
    long dbase = (long)d*XLRS + lane*4;
    float4 xr4 = ld4(xlr + dbase + 256);
    float4 xld = ld4(xlr + dbase);
    float ax = xld.x + xr4.x + epl.x; ax = ax>0.f?ax:0.2f*ax;
    float ay = xld.y + xr4.y + epl.y; ay = ay>0.f?ay:0.2f*ay;
    float az = xld.z + xr4.z + epl.z; az = az>0.f?az:0.2f*az;
    float aw = xld.w + xr4.w + epl.w; aw = aw>0.f?aw:0.2f*aw;
    float p = ax*at4.x + ay*at4.y + az*at4.z + aw*at4.w;
    p += __shfl_xor(p, 1, 16);
    p += __shfl_xor(p, 2, 16);
    p += __shfl_xor(p, 4, 16);
    p += __shfl_xor(p, 8, 16);
    float m_run = p;
    float den = 1.f;
    float4 acc = xld;
    int beg = offs[d], end = offs[d+1];
    for(int i=beg;i<end;i++){
      int s = csr_src[i];
      int eid = csr_eid[i];
      float4 xs = ld4(xlr + (long)s*XLRS + lane*4);
      const float4* ev = (const float4*)(ebuf + (long)eid*EHID);
      float4 e0 = ev[0], e1 = ev[1], e2 = ev[2], e3 = ev[3];
      float evs[16] = {e0.x,e0.y,e0.z,e0.w, e1.x,e1.y,e1.z,e1.w,
                       e2.x,e2.y,e2.z,e2.w, e3.x,e3.y,e3.z,e3.w};
      float epx=0.f, epy=0.f, epz=0.f, epw=0.f;
      #pragma unroll
      for(int k=0;k<16;k++){
        epx += evs[k]*rW[k].x; epy += evs[k]*rW[k].y;
        epz += evs[k]*rW[k].z; epw += evs[k]*rW[k].w;
      }
      float mx = xs.x + xr4.x + epx; mx = mx>0.f?mx:0.2f*mx;
      float my = xs.y + xr4.y + epy; my = my>0.f?my:0.2f*my;
      float mz = xs.z + xr4.z + epz; mz = mz>0.f?mz:0.2f*mz;
      float mw = xs.w + xr4.w + epw; mw = mw>0.f?mw:0.2f*mw;
      float q = mx*at4.x + my*at4.y + mz*at4.z + mw*at4.w;
      q += __shfl_xor(q, 1, 16);
      q += __shfl_xor(q, 2, 16);
      q += __shfl_xor(q, 4, 16);
      q += __shfl_xor(q, 8, 16);
      float nm = fmaxf(m_run, q);
      float sc = __expf(m_run - nm);
      float pe = __expf(q - nm);
      den = den*sc + pe;
      acc.x = acc.x*sc + pe*xs.x;
      acc.y = acc.y*sc + pe*xs.y;
      acc.z = acc.z*sc + pe*xs.z;
      acc.w = acc.w*sc + pe*xs.w;
      m_run = nm;
    }
    float inv = 1.f/den;
    long hbase = (long)d*HID + lane*4;
    float4 h4 = ld4(h + hbase);
    float yx = geluf(acc.x*inv + bc4.x) + h4.x;
    float yy = geluf(acc.y*inv + bc4.y) + h4.y;
    float yz = geluf(acc.z*inv + bc4.z) + h4.z;
    float yw = geluf(acc.w*inv + bc4.w) + h4.w;
    float mu = wsum64(yx+yy+yz+yw) * (1.0f/HID);
    float dx=yx-mu, dy=yy-mu, dz=yz-mu, dw=yw-mu;
    float var = wsum64(dx*dx+dy*dy+dz*dz+dw*dw) * (1.0f/HID);
    float r = rsqrtf(var + 1e-5f);
    float4 o;
    o.x = dx*r*gg4.x + bb4.x;
    o.y = dy*r*gg4.y + bb4.y;
    o.z = dz*r*gg4.z + bb4.z;
    o.w = dw*r*gg4.w + bb4.w;
    st4(h + hbase, o);
  }
}

// ---------------- gate value per node ----------------
__global__ __launch_bounds__(256) void k_gate2(const float* __restrict__ gh, const float* __restrict__ Wg2,
                       const float* __restrict__ bg2, float* __restrict__ gate){
  int gw = (int)((blockIdx.x * blockDim.x + threadIdx.x) >> 6);
  int lane = threadIdx.x & 63;
  if(gw >= N_NODES) return;
  const float* p = gh + (long)gw*128 + lane*2;
  float t0 = tanhf(p[0]) * Wg2[lane*2];
  float t1 = tanhf(p[1]) * Wg2[lane*2+1];
  float r = wsum64(t0 + t1);
  if(lane == 0) gate[gw] = r + bg2[0];
}

// ---------------- per-graph softmax stats ----------------
__global__ __launch_bounds__(256) void k_gsm(const float* __restrict__ gate, const int* __restrict__ batch,
                     float* __restrict__ gmax, float* __restrict__ gden){
  __shared__ int sr[2];
  __shared__ float red[4];
  int g = blockIdx.x, tid = threadIdx.x;
  if(tid == 0){ sr[0] = lbound(batch, g); sr[1] = lbound(batch, g+1); }
  __syncthreads();
  int r0 = sr[0], r1 = sr[1];
  float mx = -3.4e38f;
  for(int v = r0 + tid; v < r1; v += 256) mx = fmaxf(mx, gate[v]);
  mx = wmax64(mx);
  if((tid&63)==0) red[tid>>6] = mx;
  __syncthreads();
  float m = fmaxf(fmaxf(red[0],red[1]), fmaxf(red[2],red[3]));
  float s = 0.f;
  for(int v = r0 + tid; v < r1; v += 256) s += __expf(gate[v] - m);
  s = wsum64(s);
  if((tid&63)==0) red[tid>>6] = s;
  __syncthreads();
  if(tid == 0){
    gmax[g] = m;
    gden[g] = red[0]+red[1]+red[2]+red[3];
  }
}

// ---------------- pooled[g] += w[v]*h[v] ----------------
__global__ __launch_bounds__(256) void k_gpool(const float* __restrict__ h, const float* __restrict__ gate,
                       const float* __restrict__ gmax, const float* __restrict__ gden,
                       const int* __restrict__ batch, float* __restrict__ pooled){
  __shared__ int sr[2];
  int g = blockIdx.y, c = threadIdx.x;
  if(c == 0){ sr[0] = lbound(batch, g); sr[1] = lbound(batch, g+1); }
  __syncthreads();
  int r0 = sr[0], r1 = sr[1];
  float m = gmax[g], inv = 1.f/gden[g];
  float acc = 0.f;
  for(int v = r0 + blockIdx.x; v < r1; v += 16){
    float w = __expf(gate[v] - m) * inv;
    acc += w * h[(long)v*HID + c];
  }
  atomicAdd(&pooled[g*HID + c], acc);
}

__global__ __launch_bounds__(64) void k_head(const float* __restrict__ pooled, const float* __restrict__ Wh1,
                      const float* __restrict__ bh1, const float* __restrict__ Wh2,
                      const float* __restrict__ bh2, float* __restrict__ out){
  __shared__ float sp[HID];
  int b = blockIdx.x, t = threadIdx.x;
  #pragma unroll
  for(int i=0;i<4;i++) sp[t + i*64] = pooled[b*HID + t + i*64];
  __syncthreads();
  float acc = bh1[t];
  #pragma unroll 8
  for(int k=0;k<HID;k++) acc += sp[k]*Wh1[k*64 + t];
  float g = geluf(acc);
  float contrib = g * Wh2[t];
  float r = wsum64(contrib);
  if(t==0) out[b] = r + bh2[0];
}

extern "C" void kernel_launch(void* const* d_in, const int* in_sizes, int n_in,
                              void* d_out, int out_size, void* d_ws, size_t ws_size,
                              hipStream_t stream) {
  const float* x        = (const float*)d_in[0];
  const float* edge_attr= (const float*)d_in[1];
  const float* W_in     = (const float*)d_in[2];
  const float* b_in     = (const float*)d_in[3];
  const float* ln_in_g  = (const float*)d_in[4];
  const float* ln_in_b  = (const float*)d_in[5];
  const float* W_e1     = (const float*)d_in[6];
  const float* b_e1     = (const float*)d_in[7];
  const float* W_e2     = (const float*)d_in[8];
  const float* b_e2     = (const float*)d_in[9];
  const float* Wl       = (const float*)d_in[10];
  const float* bl       = (const float*)d_in[11];
  const float* Wr       = (const float*)d_in[12];
  const float* br       = (const float*)d_in[13];
  const float* att      = (const float*)d_in[14];
  const float* We       = (const float*)d_in[15];
  const float* bconv    = (const float*)d_in[16];
  const float* ln_g     = (const float*)d_in[17];
  const float* ln_b     = (const float*)d_in[18];
  const float* Wg1      = (const float*)d_in[19];
  const float* bg1      = (const float*)d_in[20];
  const float* Wg2      = (const float*)d_in[21];
  const float* bg2      = (const float*)d_in[22];
  const float* Wh1      = (const float*)d_in[23];
  const float* bh1      = (const float*)d_in[24];
  const float* Wh2      = (const float*)d_in[25];
  const float* bh2      = (const float*)d_in[26];
  const int*   ei       = (const int*)d_in[27];
  const int*   batch    = (const int*)d_in[28];
  float* out = (float*)d_out;

  float* ws = (float*)d_ws;
  float* buf_h    = ws;                        // N*HID
  float* buf_t    = ws + 5120000;              // gate hidden + epart + bf16 weights
  float* buf_xlr  = ws + 10240000;             // N*512 (also input-proj tmp ld=256)
  float* buf_e    = ws + 20480000;             // E*16
  float* buf_eploop = ws + 25600000;           // 4*256
  float* buf_gate = ws + 25601040;             // N
  float* buf_gmax = ws + 25621040;             // 16
  float* buf_gden = ws + 25621056;             // 16
  float* buf_pooled = ws + 25621072;           // 16*256
  int* csr_offs   = (int*)(ws + 25625200);     // N+1
  int* csr_cursor = (int*)(ws + 25645300);     // N
  int* csr_src    = (int*)(ws + 25665300);     // E
  int* csr_eid    = (int*)(ws + 25985300);     // E
  // buf_t sub-allocation:
  float* buf_gh   = buf_t;                     // N*128 (gate hidden, used at end)
  float* buf_epart= buf_t + 2600000;           // 1250*16
  short* W_in_t   = (short*)(buf_t + 2700000); // 256 x 1280 bf16
  short* Wlr_t    = (short*)(buf_t + 2863840); // 4 x 512 x 256 bf16
  short* Wg1_t    = (short*)(buf_t + 3126000); // 128 x 256 bf16
  float* buf_blr  = buf_t + 3143000;           // 4*512

  // weight conversions (transpose + bf16)
  k_wt<<<1280,256,0,stream>>>(W_in, W_in_t, 1280, 256);
  for(int l=0;l<NLAYER;l++){
    k_wt<<<256,256,0,stream>>>(Wl + l*65536, Wlr_t + (long)l*131072, 256, 256);
    k_wt<<<256,256,0,stream>>>(Wr + l*65536, Wlr_t + (long)l*131072 + 65536, 256, 256);
  }
  k_wt<<<128,256,0,stream>>>(Wg1, Wg1_t, 256, 128);
  k_bcat<<<1,256,0,stream>>>(bl, br, buf_blr);

  k_init_small<<<1,256,0,stream>>>(buf_pooled);
  k_csr_zero<<<(N_NODES+255)/256,256,0,stream>>>(csr_cursor);
  k_csr_count<<<(N_EDGES+255)/256,256,0,stream>>>(ei, csr_cursor);
  k_csr_scan<<<1,1024,0,stream>>>(csr_cursor, csr_offs, csr_cursor);
  k_csr_fill<<<(N_EDGES+255)/256,256,0,stream>>>(ei, csr_cursor, csr_src, csr_eid);

  // input proj: x(20000x1280) @ W_in -> buf_xlr (ld=256)
  k_gemm_bf16<<<dim3(157,2),256,0,stream>>>(x, W_in_t, b_in, buf_xlr, N_NODES, NODE_DIMC, 256);
  k_ln_gelu<<<(N_NODES+3)/4,256,0,stream>>>(buf_xlr, ln_in_g, ln_in_b, buf_h);
  k_edge_mlp<<<EMLP_BLOCKS,256,0,stream>>>(edge_attr, W_e1, b_e1, W_e2, b_e2, buf_e, buf_epart);
  k_const<<<1,256,0,stream>>>(buf_epart, We, buf_eploop);

  for(int l=0;l<NLAYER;l++){
    // combined xl|xr: h(20000x256) @ [Wl|Wr] -> buf_xlr (ld=512)
    k_gemm_bf16<<<dim3(157,4),256,0,stream>>>(buf_h, Wlr_t + (long)l*131072,
                                              buf_blr + l*512, buf_xlr, N_NODES, HID, XLRS);
    k_layer<<<LAYER_BLOCKS,256,0,stream>>>(buf_xlr, buf_h, buf_e,
                                   buf_eploop + l*HID, We + l*EHID*HID, att + l*NHEAD*DHEAD,
                                   csr_offs, csr_src, csr_eid,
                                   bconv + l*HID, ln_g + l*HID, ln_b + l*HID);
  }

  k_gemm_bf16<<<dim3(157,1),256,0,stream>>>(buf_h, Wg1_t, bg1, buf_gh, N_NODES, HID, 128);
  k_gate2<<<(N_NODES+3)/4,256,0,stream>>>(buf_gh, Wg2, bg2, buf_gate);
  k_gsm<<<N_GRAPH,256,0,stream>>>(buf_gate, batch, buf_gmax, buf_gden);
  dim3 gP(16, N_GRAPH);
  k_gpool<<<gP,256,0,stream>>>(buf_h, buf_gate, buf_gmax, buf_gden, batch, buf_pooled);
  k_head<<<N_GRAPH,64,0,stream>>>(buf_pooled, Wh1, bh1, Wh2, bh2, out);
}

// Round 5
// 1077.214 us; speedup vs baseline: 6.5532x; 1.0989x over previous
//
#include <hip/hip_runtime.h>
#include <hip/hip_bf16.h>
#include <math.h>

#define N_NODES 20000
#define N_EDGES 320000
#define N_GRAPH 16
#define HID 256
#define NLAYER 4
#define NHEAD 4
#define DHEAD 64
#define EHID 16
#define NODE_DIMC 1280
#define EMLP_BLOCKS 1250   /* 1250*256 == 320000 exactly */
#define XLRS 512           /* stride of combined xl|xr buffer */

typedef short short8 __attribute__((ext_vector_type(8)));
typedef float f32x4 __attribute__((ext_vector_type(4)));

__device__ __forceinline__ float4 ld4(const float* p){ return *reinterpret_cast<const float4*>(p); }
__device__ __forceinline__ void st4(float* p, float4 v){ *reinterpret_cast<float4*>(p) = v; }
__device__ __forceinline__ float geluf(float x){ return 0.5f*x*(1.0f+erff(x*0.70710678118654752440f)); }
__device__ __forceinline__ float wsum64(float v){
  #pragma unroll
  for(int o=32;o;o>>=1) v += __shfl_xor(v,o,64);
  return v;
}
__device__ __forceinline__ float wmax64(float v){
  #pragma unroll
  for(int o=32;o;o>>=1) v = fmaxf(v, __shfl_xor(v,o,64));
  return v;
}
__device__ __forceinline__ int lbound(const int* __restrict__ a, int val){
  int lo=0, hi=N_NODES;
  while(lo<hi){ int mid=(lo+hi)>>1; if(a[mid]<val) lo=mid+1; else hi=mid; }
  return lo;
}
__device__ __forceinline__ short cvt_bf16(float f){
  __hip_bfloat16 h = __float2bfloat16(f);
  return *reinterpret_cast<short*>(&h);
}

// ---------------- weight transpose + cvt: Wt[n*K+k] = bf16(W[k*N+n]) ----------------
__global__ __launch_bounds__(256) void k_wt(const float* __restrict__ W, short* __restrict__ Wt, int K, int N){
  int idx = blockIdx.x*256 + threadIdx.x;
  if(idx >= K*N) return;
  int n = idx / K, k = idx - n*K;
  Wt[idx] = cvt_bf16(W[(long)k*N + n]);
}

// all layers of Wl|Wr -> Wlr_t[l][n(512)][k(256)]
__global__ __launch_bounds__(256) void k_wt_lr(const float* __restrict__ Wl, const float* __restrict__ Wr,
                                               short* __restrict__ Wt){
  int idx = blockIdx.x*256 + threadIdx.x;   // l*131072 + n*256 + k
  if(idx >= NLAYER*512*256) return;
  int l = idx >> 17;
  int rem = idx & 131071;
  int n = rem >> 8, k = rem & 255;
  const float* W = (n < 256) ? (Wl + (long)l*65536 + (long)k*256 + n)
                             : (Wr + (long)l*65536 + (long)k*256 + (n-256));
  Wt[idx] = cvt_bf16(*W);
}

__global__ void k_bcat(const float* __restrict__ bl, const float* __restrict__ br, float* __restrict__ blr){
  int t = threadIdx.x;
  for(int l=0;l<NLAYER;l++){
    blr[l*512 + t]       = bl[l*256 + t];
    blr[l*512 + 256 + t] = br[l*256 + t];
  }
}

// ---------------- bf16 MFMA GEMM: C = A(MxK,fp32) @ Bt(N x K, bf16)^T + bias ----------------
__global__ __launch_bounds__(256) void k_gemm_bf16(const float* __restrict__ A,
    const short* __restrict__ Bt, const float* __restrict__ bias,
    float* __restrict__ C, int M, int K, int ldc){
  __shared__ short As[128][40];
  __shared__ short Bs[128][40];
  int tid = threadIdx.x;
  int bm = blockIdx.x*128, bn = blockIdx.y*128;
  int w = tid>>6, lane = tid&63;
  int g = lane>>4, m = lane&15;
  f32x4 acc[2][8];
  #pragma unroll
  for(int i=0;i<2;i++)
    #pragma unroll
    for(int j=0;j<8;j++) acc[i][j] = (f32x4){0.f,0.f,0.f,0.f};
  int arow = tid>>1;
  int akoff = (tid&1)*16;
  bool aval = (bm+arow) < M;
  const float* Ap = A + (long)(bm+arow)*K + akoff;
  for(int k0=0;k0<K;k0+=32){
    short8 p0, p1;
    if(aval){
      float4 f0 = ld4(Ap+k0+0), f1 = ld4(Ap+k0+4), f2 = ld4(Ap+k0+8), f3 = ld4(Ap+k0+12);
      p0[0]=cvt_bf16(f0.x); p0[1]=cvt_bf16(f0.y); p0[2]=cvt_bf16(f0.z); p0[3]=cvt_bf16(f0.w);
      p0[4]=cvt_bf16(f1.x); p0[5]=cvt_bf16(f1.y); p0[6]=cvt_bf16(f1.z); p0[7]=cvt_bf16(f1.w);
      p1[0]=cvt_bf16(f2.x); p1[1]=cvt_bf16(f2.y); p1[2]=cvt_bf16(f2.z); p1[3]=cvt_bf16(f2.w);
      p1[4]=cvt_bf16(f3.x); p1[5]=cvt_bf16(f3.y); p1[6]=cvt_bf16(f3.z); p1[7]=cvt_bf16(f3.w);
    } else {
      p0 = (short8){0,0,0,0,0,0,0,0}; p1 = p0;
    }
    *(short8*)&As[arow][akoff]   = p0;
    *(short8*)&As[arow][akoff+8] = p1;
    #pragma unroll
    for(int c = tid; c < 512; c += 256){
      int brow = c>>2, bk = (c&3)*8;
      *(short8*)&Bs[brow][bk] = *(const short8*)&Bt[(long)(bn+brow)*K + k0 + bk];
    }
    __syncthreads();
    short8 af0 = *(short8*)&As[w*32 + m][g*8];
    short8 af1 = *(short8*)&As[w*32 + 16 + m][g*8];
    #pragma unroll
    for(int j=0;j<8;j++){
      short8 bf = *(short8*)&Bs[j*16 + m][g*8];
      acc[0][j] = __builtin_amdgcn_mfma_f32_16x16x32_bf16(af0, bf, acc[0][j], 0,0,0);
      acc[1][j] = __builtin_amdgcn_mfma_f32_16x16x32_bf16(af1, bf, acc[1][j], 0,0,0);
    }
    __syncthreads();
  }
  #pragma unroll
  for(int i=0;i<2;i++){
    int r0 = bm + w*32 + i*16 + g*4;
    #pragma unroll
    for(int j=0;j<8;j++){
      int col = bn + j*16 + m;
      float bv = bias[col];
      #pragma unroll
      for(int r=0;r<4;r++){
        int row = r0 + r;
        if(row < M) C[(long)row*ldc + col] = acc[i][j][r] + bv;
      }
    }
  }
}

// ---------------- LayerNorm + GELU (input proj epilogue) ----------------
__global__ __launch_bounds__(256) void k_ln_gelu(const float* __restrict__ in, const float* __restrict__ g,
                          const float* __restrict__ b, float* __restrict__ out){
  int gw = (int)((blockIdx.x * blockDim.x + threadIdx.x) >> 6);
  int lane = threadIdx.x & 63;
  if (gw >= N_NODES) return;
  long base = (long)gw*HID + lane*4;
  float4 v = ld4(in + base);
  float mu = wsum64(v.x+v.y+v.z+v.w) * (1.0f/HID);
  float dx=v.x-mu, dy=v.y-mu, dz=v.z-mu, dw=v.w-mu;
  float var = wsum64(dx*dx+dy*dy+dz*dz+dw*dw) * (1.0f/HID);
  float r = rsqrtf(var + 1e-5f);
  float4 gg = ld4(g + lane*4), bb = ld4(b + lane*4);
  float4 o;
  o.x = geluf(dx*r*gg.x + bb.x);
  o.y = geluf(dy*r*gg.y + bb.y);
  o.z = geluf(dz*r*gg.z + bb.z);
  o.w = geluf(dw*r*gg.w + bb.w);
  st4(out + base, o);
}

// ---------------- edge MLP; per-block partial sums ----------------
__global__ __launch_bounds__(256) void k_edge_mlp(const float* __restrict__ ea, const float* __restrict__ W1,
                          const float* __restrict__ b1, const float* __restrict__ W2,
                          const float* __restrict__ b2, float* __restrict__ eout,
                          float* __restrict__ epart){
  __shared__ float sW1[16], sB1[16], sW2[256], sB2[16];
  __shared__ float red[4][16];
  int tid = threadIdx.x;
  if(tid<16){ sW1[tid]=W1[tid]; sB1[tid]=b1[tid]; sB2[tid]=b2[tid]; }
  sW2[tid] = W2[tid];
  __syncthreads();
  int e = blockIdx.x*256 + tid;
  float u = ea[e];
  float tv[16];
  #pragma unroll
  for(int j=0;j<16;j++) tv[j] = geluf(u*sW1[j] + sB1[j]);
  float ov[16];
  #pragma unroll
  for(int j=0;j<16;j++){
    float o = sB2[j];
    #pragma unroll
    for(int k=0;k<16;k++) o += tv[k]*sW2[k*16+j];
    ov[j] = o;
  }
  float4* dst = (float4*)(eout + (long)e*16);
  dst[0] = make_float4(ov[0],ov[1],ov[2],ov[3]);
  dst[1] = make_float4(ov[4],ov[5],ov[6],ov[7]);
  dst[2] = make_float4(ov[8],ov[9],ov[10],ov[11]);
  dst[3] = make_float4(ov[12],ov[13],ov[14],ov[15]);
  int wv = tid >> 6, lane = tid & 63;
  #pragma unroll
  for(int j=0;j<16;j++){
    float r = wsum64(ov[j]);
    if(lane == 0) red[wv][j] = r;
  }
  __syncthreads();
  if(tid < 16) epart[blockIdx.x*16 + tid] = red[0][tid]+red[1][tid]+red[2][tid]+red[3][tid];
}

// ---------------- reduce epart -> mean; ep_loop[l] = mean(e) @ We[l] ----------------
__global__ __launch_bounds__(256) void k_const(const float* __restrict__ epart, const float* __restrict__ We,
                                               float* __restrict__ eploop){
  __shared__ float red[16][16];
  __shared__ float em[16];
  int tid = threadIdx.x;
  int j = tid & 15, p0 = tid >> 4;
  float s = 0.f;
  for(int p = p0; p < EMLP_BLOCKS; p += 16) s += epart[p*16 + j];
  red[p0][j] = s;
  __syncthreads();
  if(tid < 16){
    float t = 0.f;
    #pragma unroll
    for(int k=0;k<16;k++) t += red[k][tid];
    em[tid] = t * (1.0f/N_EDGES);
  }
  __syncthreads();
  for(int l=0;l<NLAYER;l++){
    float acc = 0.f;
    #pragma unroll
    for(int k=0;k<16;k++) acc += em[k]*We[l*EHID*HID + k*HID + tid];
    eploop[l*HID + tid] = acc;
  }
}

__global__ void k_init_small(float* pooled){
  int tid = threadIdx.x;
  for(int i=tid;i<N_GRAPH*HID;i+=256) pooled[i]=0.f;
}

// ---------------- CSR build ----------------
__global__ __launch_bounds__(256) void k_csr_zero(int* __restrict__ counts){
  int i = blockIdx.x*256 + threadIdx.x;
  if(i < N_NODES) counts[i] = 0;
}

__global__ __launch_bounds__(256) void k_csr_count(const int* __restrict__ ei, int* __restrict__ counts){
  int e = blockIdx.x*256 + threadIdx.x;
  if(e < N_EDGES) atomicAdd(&counts[ei[N_EDGES + e]], 1);
}

__global__ __launch_bounds__(1024) void k_csr_scan(const int* __restrict__ counts, int* __restrict__ offs,
                                                   int* __restrict__ cursor){
  __shared__ int part[1024];
  int t = threadIdx.x;
  const int chunk = (N_NODES + 1023) / 1024;
  int b0 = t * chunk;
  int s = 0;
  for(int i=0;i<chunk;i++){ int idx=b0+i; if(idx<N_NODES) s += counts[idx]; }
  part[t] = s;
  __syncthreads();
  for(int off=1; off<1024; off<<=1){
    int v = part[t];
    int add = (t>=off) ? part[t-off] : 0;
    __syncthreads();
    part[t] = v + add;
    __syncthreads();
  }
  int run = (t==0) ? 0 : part[t-1];
  for(int i=0;i<chunk;i++){
    int idx = b0+i;
    if(idx < N_NODES){
      int c = counts[idx];
      offs[idx] = run; cursor[idx] = run;
      run += c;
    }
  }
  if(t == 1023) offs[N_NODES] = part[1023];
}

__global__ __launch_bounds__(256) void k_csr_fill(const int* __restrict__ ei, int* __restrict__ cursor,
                          int* __restrict__ csr_src, int* __restrict__ csr_eid){
  int e = blockIdx.x*256 + threadIdx.x;
  if(e >= N_EDGES) return;
  int d = ei[N_EDGES + e];
  int pos = atomicAdd(&cursor[d], 1);
  csr_src[pos] = ei[e];
  csr_eid[pos] = e;
}

// ---------------- fused per-layer: gather + online segment-softmax + agg + GELU + residual + LN ----------------
// xlr: [N][512], cols 0..255 = xl, 256..511 = xr. Edge loop software-pipelined:
// next edge's xs-gather + ebuf row are issued before computing the current edge.
#define LAYER_BLOCKS 1280
__global__ __launch_bounds__(256) void k_layer(
    const float* __restrict__ xlr, float* __restrict__ h, const float* __restrict__ ebuf,
    const float* __restrict__ eploop_l, const float* __restrict__ We_l,
    const float* __restrict__ att_l, const int* __restrict__ offs,
    const int* __restrict__ csr_src, const int* __restrict__ csr_eid,
    const float* __restrict__ bconv_l, const float* __restrict__ g_l,
    const float* __restrict__ b_l){
  int lane = threadIdx.x & 63;
  int wv = blockIdx.x*4 + (threadIdx.x >> 6);
  const int NW = LAYER_BLOCKS*4;
  float4 rW[16];
  #pragma unroll
  for(int k=0;k<16;k++) rW[k] = ld4(We_l + k*HID + lane*4);
  float4 at4 = ld4(att_l + lane*4);
  float4 epl = ld4(eploop_l + lane*4);
  float4 bc4 = ld4(bconv_l + lane*4);
  float4 gg4 = ld4(g_l + lane*4);
  float4 bb4 = ld4(b_l + lane*4);
  for(int d = wv; d < N_NODES; d += NW){
    long dbase = (long)d*XLRS + lane*4;
    float4 xr4 = ld4(xlr + dbase + 256);
    float4 xld = ld4(xlr + dbase);
    long hbase = (long)d*HID + lane*4;
    float4 h4 = ld4(h + hbase);
    int beg = offs[d], end = offs[d+1];
    // ---- prefetch first edge ----
    float4 xsP = make_float4(0.f,0.f,0.f,0.f);
    float4 evP0=xsP, evP1=xsP, evP2=xsP, evP3=xsP;
    if(beg < end){
      int s0 = csr_src[beg], ei0 = csr_eid[beg];
      xsP = ld4(xlr + (long)s0*XLRS + lane*4);
      const float4* ev = (const float4*)(ebuf + (long)ei0*EHID);
      evP0=ev[0]; evP1=ev[1]; evP2=ev[2]; evP3=ev[3];
    }
    // ---- self-loop seeds the online softmax (overlaps prefetch latency) ----
    float ax = xld.x + xr4.x + epl.x; ax = ax>0.f?ax:0.2f*ax;
    float ay = xld.y + xr4.y + epl.y; ay = ay>0.f?ay:0.2f*ay;
    float az = xld.z + xr4.z + epl.z; az = az>0.f?az:0.2f*az;
    float aw = xld.w + xr4.w + epl.w; aw = aw>0.f?aw:0.2f*aw;
    float p = ax*at4.x + ay*at4.y + az*at4.z + aw*at4.w;
    p += __shfl_xor(p, 1, 16);
    p += __shfl_xor(p, 2, 16);
    p += __shfl_xor(p, 4, 16);
    p += __shfl_xor(p, 8, 16);
    float m_run = p;
    float den = 1.f;
    float4 acc = xld;
    for(int i=beg;i<end;i++){
      // consume prefetched values
      float4 xs = xsP;
      float evs[16] = {evP0.x,evP0.y,evP0.z,evP0.w, evP1.x,evP1.y,evP1.z,evP1.w,
                       evP2.x,evP2.y,evP2.z,evP2.w, evP3.x,evP3.y,evP3.z,evP3.w};
      // issue next edge's loads (clamped) before computing
      {
        int ip = (i+1 < end) ? i+1 : i;
        int sN = csr_src[ip], eiN = csr_eid[ip];
        xsP = ld4(xlr + (long)sN*XLRS + lane*4);
        const float4* evn = (const float4*)(ebuf + (long)eiN*EHID);
        evP0=evn[0]; evP1=evn[1]; evP2=evn[2]; evP3=evn[3];
      }
      float epx=0.f, epy=0.f, epz=0.f, epw=0.f;
      #pragma unroll
      for(int k=0;k<16;k++){
        epx += evs[k]*rW[k].x; epy += evs[k]*rW[k].y;
        epz += evs[k]*rW[k].z; epw += evs[k]*rW[k].w;
      }
      float mx = xs.x + xr4.x + epx; mx = mx>0.f?mx:0.2f*mx;
      float my = xs.y + xr4.y + epy; my = my>0.f?my:0.2f*my;
      float mz = xs.z + xr4.z + epz; mz = mz>0.f?mz:0.2f*mz;
      float mw = xs.w + xr4.w + epw; mw = mw>0.f?mw:0.2f*mw;
      float q = mx*at4.x + my*at4.y + mz*at4.z + mw*at4.w;
      q += __shfl_xor(q, 1, 16);
      q += __shfl_xor(q, 2, 16);
      q += __shfl_xor(q, 4, 16);
      q += __shfl_xor(q, 8, 16);
      float nm = fmaxf(m_run, q);
      float sc = __expf(m_run - nm);
      float pe = __expf(q - nm);
      den = den*sc + pe;
      acc.x = acc.x*sc + pe*xs.x;
      acc.y = acc.y*sc + pe*xs.y;
      acc.z = acc.z*sc + pe*xs.z;
      acc.w = acc.w*sc + pe*xs.w;
      m_run = nm;
    }
    float inv = 1.f/den;
    float yx = geluf(acc.x*inv + bc4.x) + h4.x;
    float yy = geluf(acc.y*inv + bc4.y) + h4.y;
    float yz = geluf(acc.z*inv + bc4.z) + h4.z;
    float yw = geluf(acc.w*inv + bc4.w) + h4.w;
    float mu = wsum64(yx+yy+yz+yw) * (1.0f/HID);
    float dx=yx-mu, dy=yy-mu, dz=yz-mu, dw=yw-mu;
    float var = wsum64(dx*dx+dy*dy+dz*dz+dw*dw) * (1.0f/HID);
    float r = rsqrtf(var + 1e-5f);
    float4 o;
    o.x = dx*r*gg4.x + bb4.x;
    o.y = dy*r*gg4.y + bb4.y;
    o.z = dz*r*gg4.z + bb4.z;
    o.w = dw*r*gg4.w + bb4.w;
    st4(h + hbase, o);
  }
}

// ---------------- gate value per node ----------------
__global__ __launch_bounds__(256) void k_gate2(const float* __restrict__ gh, const float* __restrict__ Wg2,
                       const float* __restrict__ bg2, float* __restrict__ gate){
  int gw = (int)((blockIdx.x * blockDim.x + threadIdx.x) >> 6);
  int lane = threadIdx.x & 63;
  if(gw >= N_NODES) return;
  const float* p = gh + (long)gw*128 + lane*2;
  float t0 = tanhf(p[0]) * Wg2[lane*2];
  float t1 = tanhf(p[1]) * Wg2[lane*2+1];
  float r = wsum64(t0 + t1);
  if(lane == 0) gate[gw] = r + bg2[0];
}

// ---------------- per-graph softmax stats ----------------
__global__ __launch_bounds__(256) void k_gsm(const float* __restrict__ gate, const int* __restrict__ batch,
                     float* __restrict__ gmax, float* __restrict__ gden){
  __shared__ int sr[2];
  __shared__ float red[4];
  int g = blockIdx.x, tid = threadIdx.x;
  if(tid == 0){ sr[0] = lbound(batch, g); sr[1] = lbound(batch, g+1); }
  __syncthreads();
  int r0 = sr[0], r1 = sr[1];
  float mx = -3.4e38f;
  for(int v = r0 + tid; v < r1; v += 256) mx = fmaxf(mx, gate[v]);
  mx = wmax64(mx);
  if((tid&63)==0) red[tid>>6] = mx;
  __syncthreads();
  float m = fmaxf(fmaxf(red[0],red[1]), fmaxf(red[2],red[3]));
  float s = 0.f;
  for(int v = r0 + tid; v < r1; v += 256) s += __expf(gate[v] - m);
  s = wsum64(s);
  if((tid&63)==0) red[tid>>6] = s;
  __syncthreads();
  if(tid == 0){
    gmax[g] = m;
    gden[g] = red[0]+red[1]+red[2]+red[3];
  }
}

// ---------------- pooled[g] += w[v]*h[v] ----------------
__global__ __launch_bounds__(256) void k_gpool(const float* __restrict__ h, const float* __restrict__ gate,
                       const float* __restrict__ gmax, const float* __restrict__ gden,
                       const int* __restrict__ batch, float* __restrict__ pooled){
  __shared__ int sr[2];
  int g = blockIdx.y, c = threadIdx.x;
  if(c == 0){ sr[0] = lbound(batch, g); sr[1] = lbound(batch, g+1); }
  __syncthreads();
  int r0 = sr[0], r1 = sr[1];
  float m = gmax[g], inv = 1.f/gden[g];
  float acc = 0.f;
  for(int v = r0 + blockIdx.x; v < r1; v += 16){
    float w = __expf(gate[v] - m) * inv;
    acc += w * h[(long)v*HID + c];
  }
  atomicAdd(&pooled[g*HID + c], acc);
}

__global__ __launch_bounds__(64) void k_head(const float* __restrict__ pooled, const float* __restrict__ Wh1,
                      const float* __restrict__ bh1, const float* __restrict__ Wh2,
                      const float* __restrict__ bh2, float* __restrict__ out){
  __shared__ float sp[HID];
  int b = blockIdx.x, t = threadIdx.x;
  #pragma unroll
  for(int i=0;i<4;i++) sp[t + i*64] = pooled[b*HID + t + i*64];
  __syncthreads();
  float acc = bh1[t];
  #pragma unroll 8
  for(int k=0;k<HID;k++) acc += sp[k]*Wh1[k*64 + t];
  float g = geluf(acc);
  float contrib = g * Wh2[t];
  float r = wsum64(contrib);
  if(t==0) out[b] = r + bh2[0];
}

extern "C" void kernel_launch(void* const* d_in, const int* in_sizes, int n_in,
                              void* d_out, int out_size, void* d_ws, size_t ws_size,
                              hipStream_t stream) {
  const float* x        = (const float*)d_in[0];
  const float* edge_attr= (const float*)d_in[1];
  const float* W_in     = (const float*)d_in[2];
  const float* b_in     = (const float*)d_in[3];
  const float* ln_in_g  = (const float*)d_in[4];
  const float* ln_in_b  = (const float*)d_in[5];
  const float* W_e1     = (const float*)d_in[6];
  const float* b_e1     = (const float*)d_in[7];
  const float* W_e2     = (const float*)d_in[8];
  const float* b_e2     = (const float*)d_in[9];
  const float* Wl       = (const float*)d_in[10];
  const float* bl       = (const float*)d_in[11];
  const float* Wr       = (const float*)d_in[12];
  const float* br       = (const float*)d_in[13];
  const float* att      = (const float*)d_in[14];
  const float* We       = (const float*)d_in[15];
  const float* bconv    = (const float*)d_in[16];
  const float* ln_g     = (const float*)d_in[17];
  const float* ln_b     = (const float*)d_in[18];
  const float* Wg1      = (const float*)d_in[19];
  const float* bg1      = (const float*)d_in[20];
  const float* Wg2      = (const float*)d_in[21];
  const float* bg2      = (const float*)d_in[22];
  const float* Wh1      = (const float*)d_in[23];
  const float* bh1      = (const float*)d_in[24];
  const float* Wh2      = (const float*)d_in[25];
  const float* bh2      = (const float*)d_in[26];
  const int*   ei       = (const int*)d_in[27];
  const int*   batch    = (const int*)d_in[28];
  float* out = (float*)d_out;

  float* ws = (float*)d_ws;
  float* buf_h    = ws;                        // N*HID
  float* buf_t    = ws + 5120000;              // gate hidden + epart + bf16 weights
  float* buf_xlr  = ws + 10240000;             // N*512 (also input-proj tmp ld=256)
  float* buf_e    = ws + 20480000;             // E*16
  float* buf_eploop = ws + 25600000;           // 4*256
  float* buf_gate = ws + 25601040;             // N
  float* buf_gmax = ws + 25621040;             // 16
  float* buf_gden = ws + 25621056;             // 16
  float* buf_pooled = ws + 25621072;           // 16*256
  int* csr_offs   = (int*)(ws + 25625200);     // N+1
  int* csr_cursor = (int*)(ws + 25645300);     // N
  int* csr_src    = (int*)(ws + 25665300);     // E
  int* csr_eid    = (int*)(ws + 25985300);     // E
  float* buf_gh   = buf_t;                     // N*128 (gate hidden, used at end)
  float* buf_epart= buf_t + 2600000;           // 1250*16
  short* W_in_t   = (short*)(buf_t + 2700000); // 256 x 1280 bf16
  short* Wlr_t    = (short*)(buf_t + 2863840); // 4 x 512 x 256 bf16
  short* Wg1_t    = (short*)(buf_t + 3126000); // 128 x 256 bf16
  float* buf_blr  = buf_t + 3143000;           // 4*512

  // weight conversions (transpose + bf16)
  k_wt<<<1280,256,0,stream>>>(W_in, W_in_t, 1280, 256);
  k_wt_lr<<<2048,256,0,stream>>>(Wl, Wr, Wlr_t);
  k_wt<<<128,256,0,stream>>>(Wg1, Wg1_t, 256, 128);
  k_bcat<<<1,256,0,stream>>>(bl, br, buf_blr);

  k_init_small<<<1,256,0,stream>>>(buf_pooled);
  k_csr_zero<<<(N_NODES+255)/256,256,0,stream>>>(csr_cursor);
  k_csr_count<<<(N_EDGES+255)/256,256,0,stream>>>(ei, csr_cursor);
  k_csr_scan<<<1,1024,0,stream>>>(csr_cursor, csr_offs, csr_cursor);
  k_csr_fill<<<(N_EDGES+255)/256,256,0,stream>>>(ei, csr_cursor, csr_src, csr_eid);

  // input proj: x(20000x1280) @ W_in -> buf_xlr (ld=256)
  k_gemm_bf16<<<dim3(157,2),256,0,stream>>>(x, W_in_t, b_in, buf_xlr, N_NODES, NODE_DIMC, 256);
  k_ln_gelu<<<(N_NODES+3)/4,256,0,stream>>>(buf_xlr, ln_in_g, ln_in_b, buf_h);
  k_edge_mlp<<<EMLP_BLOCKS,256,0,stream>>>(edge_attr, W_e1, b_e1, W_e2, b_e2, buf_e, buf_epart);
  k_const<<<1,256,0,stream>>>(buf_epart, We, buf_eploop);

  for(int l=0;l<NLAYER;l++){
    k_gemm_bf16<<<dim3(157,4),256,0,stream>>>(buf_h, Wlr_t + (long)l*131072,
                                              buf_blr + l*512, buf_xlr, N_NODES, HID, XLRS);
    k_layer<<<LAYER_BLOCKS,256,0,stream>>>(buf_xlr, buf_h, buf_e,
                                   buf_eploop + l*HID, We + l*EHID*HID, att + l*NHEAD*DHEAD,
                                   csr_offs, csr_src, csr_eid,
                                   bconv + l*HID, ln_g + l*HID, ln_b + l*HID);
  }

  k_gemm_bf16<<<dim3(157,1),256,0,stream>>>(buf_h, Wg1_t, bg1, buf_gh, N_NODES, HID, 128);
  k_gate2<<<(N_NODES+3)/4,256,0,stream>>>(buf_gh, Wg2, bg2, buf_gate);
  k_gsm<<<N_GRAPH,256,0,stream>>>(buf_gate, batch, buf_gmax, buf_gden);
  dim3 gP(16, N_GRAPH);
  k_gpool<<<gP,256,0,stream>>>(buf_h, buf_gate, buf_gmax, buf_gden, batch, buf_pooled);
  k_head<<<N_GRAPH,64,0,stream>>>(buf_pooled, Wh1, bh1, Wh2, bh2, out);
}

// Round 6
// 911.783 us; speedup vs baseline: 7.7422x; 1.1814x over previous
//
#include <hip/hip_runtime.h>
#include <hip/hip_bf16.h>
#include <math.h>

#define N_NODES 20000
#define N_EDGES 320000
#define N_GRAPH 16
#define HID 256
#define NLAYER 4
#define NHEAD 4
#define DHEAD 64
#define EHID 16
#define NODE_DIMC 1280
#define EMLP_BLOCKS 1250   /* 1250*256 == 320000 exactly */
#define XLRS 512           /* stride of combined xl|xr buffer (in elements) */
#define TABN 4096          /* ep lookup-table knots (rows = TABN+1) */

typedef short short8 __attribute__((ext_vector_type(8)));
typedef float f32x4 __attribute__((ext_vector_type(4)));

__device__ __forceinline__ float4 ld4(const float* p){ return *reinterpret_cast<const float4*>(p); }
__device__ __forceinline__ void st4(float* p, float4 v){ *reinterpret_cast<float4*>(p) = v; }
__device__ __forceinline__ float geluf(float x){ return 0.5f*x*(1.0f+erff(x*0.70710678118654752440f)); }
__device__ __forceinline__ float wsum64(float v){
  #pragma unroll
  for(int o=32;o;o>>=1) v += __shfl_xor(v,o,64);
  return v;
}
__device__ __forceinline__ float wmax64(float v){
  #pragma unroll
  for(int o=32;o;o>>=1) v = fmaxf(v, __shfl_xor(v,o,64));
  return v;
}
__device__ __forceinline__ int lbound(const int* __restrict__ a, int val){
  int lo=0, hi=N_NODES;
  while(lo<hi){ int mid=(lo+hi)>>1; if(a[mid]<val) lo=mid+1; else hi=mid; }
  return lo;
}
__device__ __forceinline__ short cvt_bf16(float f){
  __hip_bfloat16 h = __float2bfloat16(f);
  return *reinterpret_cast<short*>(&h);
}
__device__ __forceinline__ float bf2f(short s){
  return __uint_as_float(((unsigned)(unsigned short)s) << 16);
}
__device__ __forceinline__ float4 cvt4(short4 s){
  float4 r; r.x=bf2f(s.x); r.y=bf2f(s.y); r.z=bf2f(s.z); r.w=bf2f(s.w); return r;
}

// ---------------- weight transpose + cvt: Wt[n*K+k] = bf16(W[k*N+n]) ----------------
__global__ __launch_bounds__(256) void k_wt(const float* __restrict__ W, short* __restrict__ Wt, int K, int N){
  int idx = blockIdx.x*256 + threadIdx.x;
  if(idx >= K*N) return;
  int n = idx / K, k = idx - n*K;
  Wt[idx] = cvt_bf16(W[(long)k*N + n]);
}

// all layers of Wl|Wr -> Wlr_t[l][n(512)][k(256)]
__global__ __launch_bounds__(256) void k_wt_lr(const float* __restrict__ Wl, const float* __restrict__ Wr,
                                               short* __restrict__ Wt){
  int idx = blockIdx.x*256 + threadIdx.x;
  if(idx >= NLAYER*512*256) return;
  int l = idx >> 17;
  int rem = idx & 131071;
  int n = rem >> 8, k = rem & 255;
  const float* W = (n < 256) ? (Wl + (long)l*65536 + (long)k*256 + n)
                             : (Wr + (long)l*65536 + (long)k*256 + (n-256));
  Wt[idx] = cvt_bf16(*W);
}

__global__ void k_bcat(const float* __restrict__ bl, const float* __restrict__ br, float* __restrict__ blr){
  int t = threadIdx.x;
  for(int l=0;l<NLAYER;l++){
    blr[l*512 + t]       = bl[l*256 + t];
    blr[l*512 + 256 + t] = br[l*256 + t];
  }
}

// ---------------- W2e[l][k][d] = sum_j W2[k][j]*We[l][j][d]; be[l][d] = sum_j b2[j]*We[l][j][d] ----------------
__global__ __launch_bounds__(256) void k_wecomb(const float* __restrict__ W2, const float* __restrict__ b2,
                        const float* __restrict__ We, float* __restrict__ W2e, float* __restrict__ be){
  int l = blockIdx.x, d = threadIdx.x;
  float sb = 0.f;
  #pragma unroll
  for(int j=0;j<16;j++) sb += b2[j]*We[l*4096 + j*256 + d];
  be[l*256 + d] = sb;
  for(int k=0;k<16;k++){
    float s = 0.f;
    #pragma unroll
    for(int j=0;j<16;j++) s += W2[k*16+j]*We[l*4096 + j*256 + d];
    W2e[(l*16+k)*256 + d] = s;
  }
}

// ---------------- ep lookup table: tab[l][idx][d] = bf16( f_l(idx/TABN) ) ----------------
__global__ __launch_bounds__(256) void k_etab(const float* __restrict__ W1, const float* __restrict__ b1,
                      const float* __restrict__ W2e, const float* __restrict__ be,
                      short* __restrict__ tab){
  __shared__ float t[16];
  int idx = blockIdx.x, l = blockIdx.y, d = threadIdx.x;
  if(d < 16) t[d] = geluf(((float)idx*(1.0f/TABN))*W1[d] + b1[d]);
  __syncthreads();
  float s = be[l*256 + d];
  #pragma unroll
  for(int k=0;k<16;k++) s += t[k]*W2e[(l*16+k)*256 + d];
  tab[((long)l*(TABN+1) + idx)*256 + d] = cvt_bf16(s);
}

// ---------------- GEMM BM=64, BN=256: C = A(MxK,fp32) @ Bt(N x K bf16)^T + bias ----------------
template<int OUTB>
__global__ __launch_bounds__(256) void k_gemm_n256(const float* __restrict__ A,
    const short* __restrict__ Bt, const float* __restrict__ bias,
    float* __restrict__ Cf, short* __restrict__ Cb, int M, int K, int ldc){
  __shared__ short As[64][44];
  __shared__ short Bs[256][44];
  int tid = threadIdx.x;
  int bm = blockIdx.x*64, bn = blockIdx.y*256;
  int w = tid>>6, lane = tid&63, g = lane>>4, m = lane&15;
  f32x4 acc[4][4];
  #pragma unroll
  for(int i=0;i<4;i++)
    #pragma unroll
    for(int j=0;j<4;j++) acc[i][j] = (f32x4){0.f,0.f,0.f,0.f};
  int arow = tid>>2, koff = (tid&3)*8;
  bool aval = (bm+arow) < M;
  const float* Ap = A + (long)(bm+arow)*K + koff;
  const short* Bp = Bt + (long)(bn+tid)*K;
  for(int k0=0;k0<K;k0+=32){
    short8 av;
    if(aval){
      float4 f0 = ld4(Ap+k0), f1 = ld4(Ap+k0+4);
      av[0]=cvt_bf16(f0.x); av[1]=cvt_bf16(f0.y); av[2]=cvt_bf16(f0.z); av[3]=cvt_bf16(f0.w);
      av[4]=cvt_bf16(f1.x); av[5]=cvt_bf16(f1.y); av[6]=cvt_bf16(f1.z); av[7]=cvt_bf16(f1.w);
    } else av = (short8){0,0,0,0,0,0,0,0};
    *(short8*)&As[arow][koff] = av;
    #pragma unroll
    for(int c=0;c<4;c++) *(short8*)&Bs[tid][c*8] = *(const short8*)(Bp + k0 + c*8);
    __syncthreads();
    short8 af[4];
    #pragma unroll
    for(int mi=0;mi<4;mi++) af[mi] = *(short8*)&As[mi*16+m][g*8];
    #pragma unroll
    for(int ni=0;ni<4;ni++){
      short8 bf = *(short8*)&Bs[w*64 + ni*16 + m][g*8];
      #pragma unroll
      for(int mi=0;mi<4;mi++)
        acc[mi][ni] = __builtin_amdgcn_mfma_f32_16x16x32_bf16(af[mi], bf, acc[mi][ni], 0,0,0);
    }
    __syncthreads();
  }
  #pragma unroll
  for(int mi=0;mi<4;mi++){
    int r0 = bm + mi*16 + g*4;
    #pragma unroll
    for(int ni=0;ni<4;ni++){
      int col = bn + w*64 + ni*16 + m;
      float bv = bias[col];
      #pragma unroll
      for(int r=0;r<4;r++){
        int row = r0 + r;
        if(row < M){
          float v = acc[mi][ni][r] + bv;
          if(OUTB) Cb[(long)row*ldc + col] = cvt_bf16(v);
          else     Cf[(long)row*ldc + col] = v;
        }
      }
    }
  }
}

// ---------------- bf16 MFMA GEMM 128x128 (kept for gate: N=128) ----------------
__global__ __launch_bounds__(256) void k_gemm_bf16(const float* __restrict__ A,
    const short* __restrict__ Bt, const float* __restrict__ bias,
    float* __restrict__ C, int M, int K, int ldc){
  __shared__ short As[128][40];
  __shared__ short Bs[128][40];
  int tid = threadIdx.x;
  int bm = blockIdx.x*128, bn = blockIdx.y*128;
  int w = tid>>6, lane = tid&63;
  int g = lane>>4, m = lane&15;
  f32x4 acc[2][8];
  #pragma unroll
  for(int i=0;i<2;i++)
    #pragma unroll
    for(int j=0;j<8;j++) acc[i][j] = (f32x4){0.f,0.f,0.f,0.f};
  int arow = tid>>1;
  int akoff = (tid&1)*16;
  bool aval = (bm+arow) < M;
  const float* Ap = A + (long)(bm+arow)*K + akoff;
  for(int k0=0;k0<K;k0+=32){
    short8 p0, p1;
    if(aval){
      float4 f0 = ld4(Ap+k0+0), f1 = ld4(Ap+k0+4), f2 = ld4(Ap+k0+8), f3 = ld4(Ap+k0+12);
      p0[0]=cvt_bf16(f0.x); p0[1]=cvt_bf16(f0.y); p0[2]=cvt_bf16(f0.z); p0[3]=cvt_bf16(f0.w);
      p0[4]=cvt_bf16(f1.x); p0[5]=cvt_bf16(f1.y); p0[6]=cvt_bf16(f1.z); p0[7]=cvt_bf16(f1.w);
      p1[0]=cvt_bf16(f2.x); p1[1]=cvt_bf16(f2.y); p1[2]=cvt_bf16(f2.z); p1[3]=cvt_bf16(f2.w);
      p1[4]=cvt_bf16(f3.x); p1[5]=cvt_bf16(f3.y); p1[6]=cvt_bf16(f3.z); p1[7]=cvt_bf16(f3.w);
    } else {
      p0 = (short8){0,0,0,0,0,0,0,0}; p1 = p0;
    }
    *(short8*)&As[arow][akoff]   = p0;
    *(short8*)&As[arow][akoff+8] = p1;
    #pragma unroll
    for(int c = tid; c < 512; c += 256){
      int brow = c>>2, bk = (c&3)*8;
      *(short8*)&Bs[brow][bk] = *(const short8*)&Bt[(long)(bn+brow)*K + k0 + bk];
    }
    __syncthreads();
    short8 af0 = *(short8*)&As[w*32 + m][g*8];
    short8 af1 = *(short8*)&As[w*32 + 16 + m][g*8];
    #pragma unroll
    for(int j=0;j<8;j++){
      short8 bf = *(short8*)&Bs[j*16 + m][g*8];
      acc[0][j] = __builtin_amdgcn_mfma_f32_16x16x32_bf16(af0, bf, acc[0][j], 0,0,0);
      acc[1][j] = __builtin_amdgcn_mfma_f32_16x16x32_bf16(af1, bf, acc[1][j], 0,0,0);
    }
    __syncthreads();
  }
  #pragma unroll
  for(int i=0;i<2;i++){
    int r0 = bm + w*32 + i*16 + g*4;
    #pragma unroll
    for(int j=0;j<8;j++){
      int col = bn + j*16 + m;
      float bv = bias[col];
      #pragma unroll
      for(int r=0;r<4;r++){
        int row = r0 + r;
        if(row < M) C[(long)row*ldc + col] = acc[i][j][r] + bv;
      }
    }
  }
}

// ---------------- LayerNorm + GELU (input proj epilogue) ----------------
__global__ __launch_bounds__(256) void k_ln_gelu(const float* __restrict__ in, const float* __restrict__ g,
                          const float* __restrict__ b, float* __restrict__ out){
  int gw = (int)((blockIdx.x * blockDim.x + threadIdx.x) >> 6);
  int lane = threadIdx.x & 63;
  if (gw >= N_NODES) return;
  long base = (long)gw*HID + lane*4;
  float4 v = ld4(in + base);
  float mu = wsum64(v.x+v.y+v.z+v.w) * (1.0f/HID);
  float dx=v.x-mu, dy=v.y-mu, dz=v.z-mu, dw=v.w-mu;
  float var = wsum64(dx*dx+dy*dy+dz*dz+dw*dw) * (1.0f/HID);
  float r = rsqrtf(var + 1e-5f);
  float4 gg = ld4(g + lane*4), bb = ld4(b + lane*4);
  float4 o;
  o.x = geluf(dx*r*gg.x + bb.x);
  o.y = geluf(dy*r*gg.y + bb.y);
  o.z = geluf(dz*r*gg.z + bb.z);
  o.w = geluf(dw*r*gg.w + bb.w);
  st4(out + base, o);
}

// ---------------- edge MLP t-partials only (mean path) ----------------
__global__ __launch_bounds__(256) void k_edge_mlp(const float* __restrict__ ea, const float* __restrict__ W1,
                          const float* __restrict__ b1, float* __restrict__ epart){
  __shared__ float sW1[16], sB1[16];
  __shared__ float red[4][16];
  int tid = threadIdx.x;
  if(tid<16){ sW1[tid]=W1[tid]; sB1[tid]=b1[tid]; }
  __syncthreads();
  int e = blockIdx.x*256 + tid;
  float u = ea[e];
  int wv = tid>>6, lane = tid&63;
  #pragma unroll
  for(int j=0;j<16;j++){
    float t = geluf(u*sW1[j] + sB1[j]);
    float r = wsum64(t);
    if(lane == 0) red[wv][j] = r;
  }
  __syncthreads();
  if(tid < 16) epart[blockIdx.x*16 + tid] = red[0][tid]+red[1][tid]+red[2][tid]+red[3][tid];
}

// ---------------- reduce t-partials -> e_mean -> ep_loop[l] ----------------
__global__ __launch_bounds__(256) void k_const(const float* __restrict__ epart, const float* __restrict__ W2,
                       const float* __restrict__ b2, const float* __restrict__ We,
                       float* __restrict__ eploop){
  __shared__ float red[16][16];
  __shared__ float em[16];
  int tid = threadIdx.x;
  int j = tid & 15, p0 = tid >> 4;
  float s = 0.f;
  for(int p = p0; p < EMLP_BLOCKS; p += 16) s += epart[p*16 + j];
  red[p0][j] = s;
  __syncthreads();
  if(tid < 16){
    float tm[16];
    #pragma unroll
    for(int k=0;k<16;k++){
      float t = 0.f;
      #pragma unroll
      for(int q=0;q<16;q++) t += red[q][k];
      tm[k] = 0.f; // placeholder (set below)
      red[0][k] = t * (1.0f/N_EDGES);   // tm stored in red[0]
    }
    (void)tm;
  }
  __syncthreads();
  if(tid < 16){
    float acc = b2[tid];
    #pragma unroll
    for(int k=0;k<16;k++) acc += red[0][k]*W2[k*16 + tid];
    em[tid] = acc;
  }
  __syncthreads();
  for(int l=0;l<NLAYER;l++){
    float acc = 0.f;
    #pragma unroll
    for(int k=0;k<16;k++) acc += em[k]*We[l*EHID*HID + k*HID + tid];
    eploop[l*HID + tid] = acc;
  }
}

__global__ void k_init_small(float* pooled){
  int tid = threadIdx.x;
  for(int i=tid;i<N_GRAPH*HID;i+=256) pooled[i]=0.f;
}

// ---------------- CSR build ----------------
__global__ __launch_bounds__(256) void k_csr_zero(int* __restrict__ counts){
  int i = blockIdx.x*256 + threadIdx.x;
  if(i < N_NODES) counts[i] = 0;
}

__global__ __launch_bounds__(256) void k_csr_count(const int* __restrict__ ei, int* __restrict__ counts){
  int e = blockIdx.x*256 + threadIdx.x;
  if(e < N_EDGES) atomicAdd(&counts[ei[N_EDGES + e]], 1);
}

__global__ __launch_bounds__(1024) void k_csr_scan(const int* __restrict__ counts, int* __restrict__ offs,
                                                   int* __restrict__ cursor){
  __shared__ int part[1024];
  int t = threadIdx.x;
  const int chunk = (N_NODES + 1023) / 1024;
  int b0 = t * chunk;
  int s = 0;
  for(int i=0;i<chunk;i++){ int idx=b0+i; if(idx<N_NODES) s += counts[idx]; }
  part[t] = s;
  __syncthreads();
  for(int off=1; off<1024; off<<=1){
    int v = part[t];
    int add = (t>=off) ? part[t-off] : 0;
    __syncthreads();
    part[t] = v + add;
    __syncthreads();
  }
  int run = (t==0) ? 0 : part[t-1];
  for(int i=0;i<chunk;i++){
    int idx = b0+i;
    if(idx < N_NODES){
      int c = counts[idx];
      offs[idx] = run; cursor[idx] = run;
      run += c;
    }
  }
  if(t == 1023) offs[N_NODES] = part[1023];
}

__global__ __launch_bounds__(256) void k_csr_fill(const int* __restrict__ ei, const float* __restrict__ ea,
                          int* __restrict__ cursor, int2* __restrict__ meta){
  int e = blockIdx.x*256 + threadIdx.x;
  if(e >= N_EDGES) return;
  int d = ei[N_EDGES + e];
  int pos = atomicAdd(&cursor[d], 1);
  meta[pos] = make_int2(ei[e], __float_as_int(ea[e]));
}

// ---------------- fused per-layer: gather + table-ep + online softmax + agg + GELU + residual + LN ----------------
// one wave per node (5000 blocks x 4 waves = 20000). xlr is bf16 [N][512] (xl|xr).
__global__ __launch_bounds__(256) void k_layer(
    const short* __restrict__ xlr, float* __restrict__ h, const short* __restrict__ tab_l,
    const float* __restrict__ eploop_l, const float* __restrict__ att_l,
    const int* __restrict__ offs, const int2* __restrict__ meta,
    const float* __restrict__ bconv_l, const float* __restrict__ g_l,
    const float* __restrict__ b_l){
  int tid = threadIdx.x;
  int lane = tid & 63;
  int d = blockIdx.x*4 + (tid >> 6);
  float4 at4 = ld4(att_l + lane*4);
  float4 epl = ld4(eploop_l + lane*4);
  float4 bc4 = ld4(bconv_l + lane*4);
  float4 gg4 = ld4(g_l + lane*4);
  float4 bb4 = ld4(b_l + lane*4);
  const short4* xp = (const short4*)(xlr + (long)d*XLRS);
  float4 xld = cvt4(xp[lane]);
  float4 xr4 = cvt4(xp[64 + lane]);
  long hbase = (long)d*HID + lane*4;
  float4 h4 = ld4(h + hbase);
  int beg = offs[d], end = offs[d+1];

  short4 xsb[2], ta[2], tb[2];
  float frv[2];
  auto issue = [&](int slot, int j){
    int2 mm = meta[j];
    float u = __int_as_float(mm.y);
    float f = u * (float)TABN;
    f = fminf(fmaxf(f, 0.f), (float)TABN - 0.001f);
    int i0 = (int)f;
    frv[slot] = f - (float)i0;
    xsb[slot] = ((const short4*)(xlr + (long)mm.x*XLRS))[lane];
    const short4* tp = (const short4*)(tab_l + (long)i0*256);
    ta[slot] = tp[lane];
    tb[slot] = tp[64 + lane];
  };
  auto logit = [&](int slot, float4 &xsf)->float{
    xsf = cvt4(xsb[slot]);
    float4 t0 = cvt4(ta[slot]), t1 = cvt4(tb[slot]);
    float fr = frv[slot];
    float ex = t0.x + fr*(t1.x - t0.x);
    float ey = t0.y + fr*(t1.y - t0.y);
    float ez = t0.z + fr*(t1.z - t0.z);
    float ew = t0.w + fr*(t1.w - t0.w);
    float mx = xsf.x + xr4.x + ex; mx = mx>0.f?mx:0.2f*mx;
    float my = xsf.y + xr4.y + ey; my = my>0.f?my:0.2f*my;
    float mz = xsf.z + xr4.z + ez; mz = mz>0.f?mz:0.2f*mz;
    float mw = xsf.w + xr4.w + ew; mw = mw>0.f?mw:0.2f*mw;
    float q = mx*at4.x + my*at4.y + mz*at4.z + mw*at4.w;
    q += __shfl_xor(q, 1, 16);
    q += __shfl_xor(q, 2, 16);
    q += __shfl_xor(q, 4, 16);
    q += __shfl_xor(q, 8, 16);
    return q;
  };

  int i = beg;
  if(i < end)   issue(0, i);
  if(i+1 < end) issue(1, i+1);
  // self-loop seed (overlaps first prefetch)
  float ax = xld.x + xr4.x + epl.x; ax = ax>0.f?ax:0.2f*ax;
  float ay = xld.y + xr4.y + epl.y; ay = ay>0.f?ay:0.2f*ay;
  float az = xld.z + xr4.z + epl.z; az = az>0.f?az:0.2f*az;
  float aw = xld.w + xr4.w + epl.w; aw = aw>0.f?aw:0.2f*aw;
  float p = ax*at4.x + ay*at4.y + az*at4.z + aw*at4.w;
  p += __shfl_xor(p, 1, 16);
  p += __shfl_xor(p, 2, 16);
  p += __shfl_xor(p, 4, 16);
  p += __shfl_xor(p, 8, 16);
  float m_run = p;
  float den = 1.f;
  float4 acc = xld;

  for(; i+1 < end; i += 2){
    float4 xs0, xs1;
    float q0 = logit(0, xs0);
    float q1 = logit(1, xs1);
    if(i+2 < end) issue(0, i+2);
    if(i+3 < end) issue(1, i+3);
    float nm = fmaxf(m_run, fmaxf(q0, q1));
    float sc = __expf(m_run - nm);
    float p0 = __expf(q0 - nm);
    float p1 = __expf(q1 - nm);
    den = den*sc + p0 + p1;
    acc.x = acc.x*sc + p0*xs0.x + p1*xs1.x;
    acc.y = acc.y*sc + p0*xs0.y + p1*xs1.y;
    acc.z = acc.z*sc + p0*xs0.z + p1*xs1.z;
    acc.w = acc.w*sc + p0*xs0.w + p1*xs1.w;
    m_run = nm;
  }
  if(i < end){
    float4 xs0;
    float q0 = logit(0, xs0);
    float nm = fmaxf(m_run, q0);
    float sc = __expf(m_run - nm);
    float p0 = __expf(q0 - nm);
    den = den*sc + p0;
    acc.x = acc.x*sc + p0*xs0.x;
    acc.y = acc.y*sc + p0*xs0.y;
    acc.z = acc.z*sc + p0*xs0.z;
    acc.w = acc.w*sc + p0*xs0.w;
    m_run = nm;
  }
  float inv = 1.f/den;
  float yx = geluf(acc.x*inv + bc4.x) + h4.x;
  float yy = geluf(acc.y*inv + bc4.y) + h4.y;
  float yz = geluf(acc.z*inv + bc4.z) + h4.z;
  float yw = geluf(acc.w*inv + bc4.w) + h4.w;
  float mu = wsum64(yx+yy+yz+yw) * (1.0f/HID);
  float dx=yx-mu, dy=yy-mu, dz=yz-mu, dw=yw-mu;
  float var = wsum64(dx*dx+dy*dy+dz*dz+dw*dw) * (1.0f/HID);
  float r = rsqrtf(var + 1e-5f);
  float4 o;
  o.x = dx*r*gg4.x + bb4.x;
  o.y = dy*r*gg4.y + bb4.y;
  o.z = dz*r*gg4.z + bb4.z;
  o.w = dw*r*gg4.w + bb4.w;
  st4(h + hbase, o);
}

// ---------------- gate value per node ----------------
__global__ __launch_bounds__(256) void k_gate2(const float* __restrict__ gh, const float* __restrict__ Wg2,
                       const float* __restrict__ bg2, float* __restrict__ gate){
  int gw = (int)((blockIdx.x * blockDim.x + threadIdx.x) >> 6);
  int lane = threadIdx.x & 63;
  if(gw >= N_NODES) return;
  const float* p = gh + (long)gw*128 + lane*2;
  float t0 = tanhf(p[0]) * Wg2[lane*2];
  float t1 = tanhf(p[1]) * Wg2[lane*2+1];
  float r = wsum64(t0 + t1);
  if(lane == 0) gate[gw] = r + bg2[0];
}

// ---------------- per-graph softmax stats ----------------
__global__ __launch_bounds__(256) void k_gsm(const float* __restrict__ gate, const int* __restrict__ batch,
                     float* __restrict__ gmax, float* __restrict__ gden){
  __shared__ int sr[2];
  __shared__ float red[4];
  int g = blockIdx.x, tid = threadIdx.x;
  if(tid == 0){ sr[0] = lbound(batch, g); sr[1] = lbound(batch, g+1); }
  __syncthreads();
  int r0 = sr[0], r1 = sr[1];
  float mx = -3.4e38f;
  for(int v = r0 + tid; v < r1; v += 256) mx = fmaxf(mx, gate[v]);
  mx = wmax64(mx);
  if((tid&63)==0) red[tid>>6] = mx;
  __syncthreads();
  float m = fmaxf(fmaxf(red[0],red[1]), fmaxf(red[2],red[3]));
  float s = 0.f;
  for(int v = r0 + tid; v < r1; v += 256) s += __expf(gate[v] - m);
  s = wsum64(s);
  if((tid&63)==0) red[tid>>6] = s;
  __syncthreads();
  if(tid == 0){
    gmax[g] = m;
    gden[g] = red[0]+red[1]+red[2]+red[3];
  }
}

// ---------------- pooled[g] += w[v]*h[v] ----------------
__global__ __launch_bounds__(256) void k_gpool(const float* __restrict__ h, const float* __restrict__ gate,
                       const float* __restrict__ gmax, const float* __restrict__ gden,
                       const int* __restrict__ batch, float* __restrict__ pooled){
  __shared__ int sr[2];
  int g = blockIdx.y, c = threadIdx.x;
  if(c == 0){ sr[0] = lbound(batch, g); sr[1] = lbound(batch, g+1); }
  __syncthreads();
  int r0 = sr[0], r1 = sr[1];
  float m = gmax[g], inv = 1.f/gden[g];
  float acc = 0.f;
  for(int v = r0 + blockIdx.x; v < r1; v += 16){
    float w = __expf(gate[v] - m) * inv;
    acc += w * h[(long)v*HID + c];
  }
  atomicAdd(&pooled[g*HID + c], acc);
}

__global__ __launch_bounds__(64) void k_head(const float* __restrict__ pooled, const float* __restrict__ Wh1,
                      const float* __restrict__ bh1, const float* __restrict__ Wh2,
                      const float* __restrict__ bh2, float* __restrict__ out){
  __shared__ float sp[HID];
  int b = blockIdx.x, t = threadIdx.x;
  #pragma unroll
  for(int i=0;i<4;i++) sp[t + i*64] = pooled[b*HID + t + i*64];
  __syncthreads();
  float acc = bh1[t];
  #pragma unroll 8
  for(int k=0;k<HID;k++) acc += sp[k]*Wh1[k*64 + t];
  float g = geluf(acc);
  float contrib = g * Wh2[t];
  float r = wsum64(contrib);
  if(t==0) out[b] = r + bh2[0];
}

extern "C" void kernel_launch(void* const* d_in, const int* in_sizes, int n_in,
                              void* d_out, int out_size, void* d_ws, size_t ws_size,
                              hipStream_t stream) {
  const float* x        = (const float*)d_in[0];
  const float* edge_attr= (const float*)d_in[1];
  const float* W_in     = (const float*)d_in[2];
  const float* b_in     = (const float*)d_in[3];
  const float* ln_in_g  = (const float*)d_in[4];
  const float* ln_in_b  = (const float*)d_in[5];
  const float* W_e1     = (const float*)d_in[6];
  const float* b_e1     = (const float*)d_in[7];
  const float* W_e2     = (const float*)d_in[8];
  const float* b_e2     = (const float*)d_in[9];
  const float* Wl       = (const float*)d_in[10];
  const float* bl       = (const float*)d_in[11];
  const float* Wr       = (const float*)d_in[12];
  const float* br       = (const float*)d_in[13];
  const float* att      = (const float*)d_in[14];
  const float* We       = (const float*)d_in[15];
  const float* bconv    = (const float*)d_in[16];
  const float* ln_g     = (const float*)d_in[17];
  const float* ln_b     = (const float*)d_in[18];
  const float* Wg1      = (const float*)d_in[19];
  const float* bg1      = (const float*)d_in[20];
  const float* Wg2      = (const float*)d_in[21];
  const float* bg2      = (const float*)d_in[22];
  const float* Wh1      = (const float*)d_in[23];
  const float* bh1      = (const float*)d_in[24];
  const float* Wh2      = (const float*)d_in[25];
  const float* bh2      = (const float*)d_in[26];
  const int*   ei       = (const int*)d_in[27];
  const int*   batch    = (const int*)d_in[28];
  float* out = (float*)d_out;

  float* ws = (float*)d_ws;
  float* buf_h     = ws;                         // N*256 fp32
  float* buf_t     = ws + 5120000;               // N*256 fp32 (input-proj tmp; gh reuse)
  short* buf_xlr   = (short*)(ws + 10240000);    // N*512 bf16
  short* buf_tab   = (short*)(ws + 15360000);    // 4*4097*256 bf16
  float* buf_eploop= ws + 17500000;              // 4*256
  float* buf_gate  = ws + 17501040;              // N
  float* buf_gmax  = ws + 17521040;              // 16
  float* buf_gden  = ws + 17521056;              // 16
  float* buf_pooled= ws + 17521072;              // 4096
  float* buf_epart = ws + 17525200;              // 1250*16
  int*   csr_offs  = (int*)(ws + 17545300);      // N+1
  int*   csr_cursor= (int*)(ws + 17565304);      // N
  int2*  csr_meta  = (int2*)(ws + 17585304);     // E int2
  short* W_in_t    = (short*)(ws + 18225304);    // 256x1280
  short* Wlr_t     = (short*)(ws + 18389144);    // 4x512x256
  short* Wg1_t     = (short*)(ws + 18651288);    // 128x256
  float* buf_blr   = ws + 18667672;              // 4*512
  float* buf_W2e   = ws + 18669720;              // 4*16*256
  float* buf_be    = ws + 18686104;              // 4*256
  float* buf_gh    = buf_t;                      // N*128 (reuse)

  // weight prep
  k_wt<<<1280,256,0,stream>>>(W_in, W_in_t, 1280, 256);
  k_wt_lr<<<2048,256,0,stream>>>(Wl, Wr, Wlr_t);
  k_wt<<<128,256,0,stream>>>(Wg1, Wg1_t, 256, 128);
  k_bcat<<<1,256,0,stream>>>(bl, br, buf_blr);
  k_wecomb<<<NLAYER,256,0,stream>>>(W_e2, b_e2, We, buf_W2e, buf_be);
  k_etab<<<dim3(TABN+1,NLAYER),256,0,stream>>>(W_e1, b_e1, buf_W2e, buf_be, buf_tab);

  k_init_small<<<1,256,0,stream>>>(buf_pooled);
  k_csr_zero<<<(N_NODES+255)/256,256,0,stream>>>(csr_cursor);
  k_csr_count<<<(N_EDGES+255)/256,256,0,stream>>>(ei, csr_cursor);
  k_csr_scan<<<1,1024,0,stream>>>(csr_cursor, csr_offs, csr_cursor);
  k_csr_fill<<<(N_EDGES+255)/256,256,0,stream>>>(ei, edge_attr, csr_cursor, csr_meta);

  // input proj: x @ W_in -> buf_t (fp32, ld=256)
  k_gemm_n256<0><<<dim3(313,1),256,0,stream>>>(x, W_in_t, b_in, buf_t, nullptr, N_NODES, NODE_DIMC, 256);
  k_ln_gelu<<<(N_NODES+3)/4,256,0,stream>>>(buf_t, ln_in_g, ln_in_b, buf_h);
  k_edge_mlp<<<EMLP_BLOCKS,256,0,stream>>>(edge_attr, W_e1, b_e1, buf_epart);
  k_const<<<1,256,0,stream>>>(buf_epart, W_e2, b_e2, We, buf_eploop);

  for(int l=0;l<NLAYER;l++){
    k_gemm_n256<1><<<dim3(313,2),256,0,stream>>>(buf_h, Wlr_t + (long)l*131072,
                       buf_blr + l*512, nullptr, buf_xlr, N_NODES, HID, XLRS);
    k_layer<<<5000,256,0,stream>>>(buf_xlr, buf_h, buf_tab + (long)l*(TABN+1)*256,
                       buf_eploop + l*HID, att + l*NHEAD*DHEAD,
                       csr_offs, csr_meta, bconv + l*HID, ln_g + l*HID, ln_b + l*HID);
  }

  k_gemm_bf16<<<dim3(157,1),256,0,stream>>>(buf_h, Wg1_t, bg1, buf_gh, N_NODES, HID, 128);
  k_gate2<<<(N_NODES+3)/4,256,0,stream>>>(buf_gh, Wg2, bg2, buf_gate);
  k_gsm<<<N_GRAPH,256,0,stream>>>(buf_gate, batch, buf_gmax, buf_gden);
  dim3 gP(16, N_GRAPH);
  k_gpool<<<gP,256,0,stream>>>(buf_h, buf_gate, buf_gmax, buf_gden, batch, buf_pooled);
  k_head<<<N_GRAPH,64,0,stream>>>(buf_pooled, Wh1, bh1, Wh2, bh2, out);
}

// Round 8
// 864.784 us; speedup vs baseline: 8.1630x; 1.0543x over previous
//
#include <hip/hip_runtime.h>
#include <hip/hip_bf16.h>
#include <math.h>

#define N_NODES 20000
#define N_EDGES 320000
#define N_GRAPH 16
#define HID 256
#define NLAYER 4
#define NHEAD 4
#define DHEAD 64
#define EHID 16
#define NODE_DIMC 1280
#define EMLP_BLOCKS 1250   /* 1250*256 == 320000 exactly */
#define XLRS 512           /* stride of combined xl|xr buffer (in elements) */
#define TABN 4096          /* ep lookup-table knots (rows = TABN+1) */

typedef short short8 __attribute__((ext_vector_type(8)));
typedef float f32x4 __attribute__((ext_vector_type(4)));

__device__ __forceinline__ float4 ld4(const float* p){ return *reinterpret_cast<const float4*>(p); }
__device__ __forceinline__ void st4(float* p, float4 v){ *reinterpret_cast<float4*>(p) = v; }
__device__ __forceinline__ float geluf(float x){ return 0.5f*x*(1.0f+erff(x*0.70710678118654752440f)); }
__device__ __forceinline__ float wsum64(float v){
  #pragma unroll
  for(int o=32;o;o>>=1) v += __shfl_xor(v,o,64);
  return v;
}
__device__ __forceinline__ float wmax64(float v){
  #pragma unroll
  for(int o=32;o;o>>=1) v = fmaxf(v, __shfl_xor(v,o,64));
  return v;
}
__device__ __forceinline__ int lbound(const int* __restrict__ a, int val){
  int lo=0, hi=N_NODES;
  while(lo<hi){ int mid=(lo+hi)>>1; if(a[mid]<val) lo=mid+1; else hi=mid; }
  return lo;
}
__device__ __forceinline__ short cvt_bf16(float f){
  __hip_bfloat16 h = __float2bfloat16(f);
  return *reinterpret_cast<short*>(&h);
}
__device__ __forceinline__ float bf2f(short s){
  return __uint_as_float(((unsigned)(unsigned short)s) << 16);
}
__device__ __forceinline__ float4 cvt4(short4 s){
  float4 r; r.x=bf2f(s.x); r.y=bf2f(s.y); r.z=bf2f(s.z); r.w=bf2f(s.w); return r;
}
__device__ __forceinline__ short4 f2s4(float4 v){
  short4 s; s.x=cvt_bf16(v.x); s.y=cvt_bf16(v.y); s.z=cvt_bf16(v.z); s.w=cvt_bf16(v.w); return s;
}
// async global->LDS, 16B per lane; LDS dest is wave-uniform base + lane*16
__device__ __forceinline__ void glds16(const short* g, short* l){
  __builtin_amdgcn_global_load_lds((const __attribute__((address_space(1))) void*)g,
                                   (__attribute__((address_space(3))) void*)l, 16, 0, 0);
}

// ---------------- weight transpose + cvt: Wt[n*K+k] = bf16(W[k*N+n]) ----------------
__global__ __launch_bounds__(256) void k_wt(const float* __restrict__ W, short* __restrict__ Wt, int K, int N){
  int idx = blockIdx.x*256 + threadIdx.x;
  if(idx >= K*N) return;
  int n = idx / K, k = idx - n*K;
  Wt[idx] = cvt_bf16(W[(long)k*N + n]);
}

// all layers of Wl|Wr -> Wlr_t[l][n(512)][k(256)]
__global__ __launch_bounds__(256) void k_wt_lr(const float* __restrict__ Wl, const float* __restrict__ Wr,
                                               short* __restrict__ Wt){
  int idx = blockIdx.x*256 + threadIdx.x;
  if(idx >= NLAYER*512*256) return;
  int l = idx >> 17;
  int rem = idx & 131071;
  int n = rem >> 8, k = rem & 255;
  const float* W = (n < 256) ? (Wl + (long)l*65536 + (long)k*256 + n)
                             : (Wr + (long)l*65536 + (long)k*256 + (n-256));
  Wt[idx] = cvt_bf16(*W);
}

__global__ void k_bcat(const float* __restrict__ bl, const float* __restrict__ br, float* __restrict__ blr){
  int t = threadIdx.x;
  for(int l=0;l<NLAYER;l++){
    blr[l*512 + t]       = bl[l*256 + t];
    blr[l*512 + 256 + t] = br[l*256 + t];
  }
}

// ---------------- x fp32 -> bf16 ----------------
__global__ __launch_bounds__(256) void k_xcvt(const float* __restrict__ x, short* __restrict__ xb){
  long i = (long)blockIdx.x*256 + threadIdx.x;   // one float4 per thread
  float4 v = ld4(x + i*4);
  *(short4*)(xb + i*4) = f2s4(v);
}

// ---------------- W2e[l][k][d]; be[l][d] ----------------
__global__ __launch_bounds__(256) void k_wecomb(const float* __restrict__ W2, const float* __restrict__ b2,
                        const float* __restrict__ We, float* __restrict__ W2e, float* __restrict__ be){
  int l = blockIdx.x, d = threadIdx.x;
  float sb = 0.f;
  #pragma unroll
  for(int j=0;j<16;j++) sb += b2[j]*We[l*4096 + j*256 + d];
  be[l*256 + d] = sb;
  for(int k=0;k<16;k++){
    float s = 0.f;
    #pragma unroll
    for(int j=0;j<16;j++) s += W2[k*16+j]*We[l*4096 + j*256 + d];
    W2e[(l*16+k)*256 + d] = s;
  }
}

// ---------------- ep lookup table ----------------
__global__ __launch_bounds__(256) void k_etab(const float* __restrict__ W1, const float* __restrict__ b1,
                      const float* __restrict__ W2e, const float* __restrict__ be,
                      short* __restrict__ tab){
  __shared__ float t[16];
  int idx = blockIdx.x, l = blockIdx.y, d = threadIdx.x;
  if(d < 16) t[d] = geluf(((float)idx*(1.0f/TABN))*W1[d] + b1[d]);
  __syncthreads();
  float s = be[l*256 + d];
  #pragma unroll
  for(int k=0;k<16;k++) s += t[k]*W2e[(l*16+k)*256 + d];
  tab[((long)l*(TABN+1) + idx)*256 + d] = cvt_bf16(s);
}

// ---------------- pipelined bf16 GEMM: C = A(MxK,bf16) @ Bt(N x K bf16)^T + bias ----------------
// BM=128, BN=128, BK=32; async global_load_lds double-buffer; raw s_barrier + vmcnt(4).
template<int OUTB>
__global__ __launch_bounds__(256) void k_gemm_p(const short* __restrict__ A,
    const short* __restrict__ Bt, const float* __restrict__ bias,
    float* __restrict__ Cf, short* __restrict__ Cb, int M, int K, int ldc){
  __shared__ short As[2][128*32];
  __shared__ short Bs[2][128*32];
  int tid = threadIdx.x;
  int w = tid>>6, lane = tid&63;
  int g = lane>>4, m = lane&15;
  int bm = blockIdx.x*128, bn = blockIdx.y*128;
  int crow = lane>>2;          // row within 16-row chunk
  int coff = (lane&3)*8;       // short offset within row
  int ar0 = bm + (w*2+0)*16 + crow; ar0 = ar0 < M ? ar0 : M-1;
  int ar1 = bm + (w*2+1)*16 + crow; ar1 = ar1 < M ? ar1 : M-1;
  const short* Ap0 = A + (long)ar0*K + coff;
  const short* Ap1 = A + (long)ar1*K + coff;
  const short* Bp0 = Bt + (long)(bn + (w*2+0)*16 + crow)*K + coff;
  const short* Bp1 = Bt + (long)(bn + (w*2+1)*16 + crow)*K + coff;
  short* As0 = &As[0][(w*2+0)*512]; short* As1 = &As[0][(w*2+1)*512];
  short* Bs0 = &Bs[0][(w*2+0)*512]; short* Bs1 = &Bs[0][(w*2+1)*512];
  const int bufstride = 128*32;   // shorts
  f32x4 acc[2][8];
  #pragma unroll
  for(int i=0;i<2;i++)
    #pragma unroll
    for(int j=0;j<8;j++) acc[i][j] = (f32x4){0.f,0.f,0.f,0.f};
  int niter = K >> 5;
  glds16(Ap0, As0); glds16(Ap1, As1); glds16(Bp0, Bs0); glds16(Bp1, Bs1);
  for(int i=0;i<niter;i++){
    int cur = i&1, nxt = cur^1;
    if(i+1 < niter){
      int k = (i+1)<<5;
      glds16(Ap0 + k, As0 + nxt*bufstride);
      glds16(Ap1 + k, As1 + nxt*bufstride);
      glds16(Bp0 + k, Bs0 + nxt*bufstride);
      glds16(Bp1 + k, Bs1 + nxt*bufstride);
      __builtin_amdgcn_s_waitcnt(0x0F74);   // vmcnt(4): current buffer's 4 chunks done
    } else {
      __builtin_amdgcn_s_waitcnt(0x0F70);   // vmcnt(0)
    }
    __builtin_amdgcn_s_barrier();           // raw barrier: prefetch stays in flight
    const short* ab = &As[cur][0];
    const short* bb = &Bs[cur][0];
    short8 a0 = *(const short8*)&ab[(w*32 + m)*32 + g*8];
    short8 a1 = *(const short8*)&ab[(w*32 + 16 + m)*32 + g*8];
    #pragma unroll
    for(int j=0;j<8;j++){
      short8 bf = *(const short8*)&bb[(j*16 + m)*32 + g*8];
      acc[0][j] = __builtin_amdgcn_mfma_f32_16x16x32_bf16(a0, bf, acc[0][j], 0,0,0);
      acc[1][j] = __builtin_amdgcn_mfma_f32_16x16x32_bf16(a1, bf, acc[1][j], 0,0,0);
    }
    __builtin_amdgcn_s_barrier();
  }
  #pragma unroll
  for(int mi=0;mi<2;mi++){
    int r0 = bm + w*32 + mi*16 + g*4;
    #pragma unroll
    for(int j=0;j<8;j++){
      int col = bn + j*16 + m;
      float bv = bias[col];
      #pragma unroll
      for(int r=0;r<4;r++){
        int row = r0 + r;
        if(row < M){
          float v = acc[mi][j][r] + bv;
          if(OUTB) Cb[(long)row*ldc + col] = cvt_bf16(v);
          else     Cf[(long)row*ldc + col] = v;
        }
      }
    }
  }
}

// ---------------- LayerNorm + GELU (input proj epilogue); writes fp32 h + bf16 h ----------------
__global__ __launch_bounds__(256) void k_ln_gelu(const float* __restrict__ in, const float* __restrict__ g,
                          const float* __restrict__ b, float* __restrict__ out, short* __restrict__ outb){
  int gw = (int)((blockIdx.x * blockDim.x + threadIdx.x) >> 6);
  int lane = threadIdx.x & 63;
  if (gw >= N_NODES) return;
  long base = (long)gw*HID + lane*4;
  float4 v = ld4(in + base);
  float mu = wsum64(v.x+v.y+v.z+v.w) * (1.0f/HID);
  float dx=v.x-mu, dy=v.y-mu, dz=v.z-mu, dw=v.w-mu;
  float var = wsum64(dx*dx+dy*dy+dz*dz+dw*dw) * (1.0f/HID);
  float r = rsqrtf(var + 1e-5f);
  float4 gg = ld4(g + lane*4), bb = ld4(b + lane*4);
  float4 o;
  o.x = geluf(dx*r*gg.x + bb.x);
  o.y = geluf(dy*r*gg.y + bb.y);
  o.z = geluf(dz*r*gg.z + bb.z);
  o.w = geluf(dw*r*gg.w + bb.w);
  st4(out + base, o);
  *(short4*)(outb + base) = f2s4(o);
}

// ---------------- edge MLP t-partials only (mean path) ----------------
__global__ __launch_bounds__(256) void k_edge_mlp(const float* __restrict__ ea, const float* __restrict__ W1,
                          const float* __restrict__ b1, float* __restrict__ epart){
  __shared__ float sW1[16], sB1[16];
  __shared__ float red[4][16];
  int tid = threadIdx.x;
  if(tid<16){ sW1[tid]=W1[tid]; sB1[tid]=b1[tid]; }
  __syncthreads();
  int e = blockIdx.x*256 + tid;
  float u = ea[e];
  int wv = tid>>6, lane = tid&63;
  #pragma unroll
  for(int j=0;j<16;j++){
    float t = geluf(u*sW1[j] + sB1[j]);
    float r = wsum64(t);
    if(lane == 0) red[wv][j] = r;
  }
  __syncthreads();
  if(tid < 16) epart[blockIdx.x*16 + tid] = red[0][tid]+red[1][tid]+red[2][tid]+red[3][tid];
}

// ---------------- reduce t-partials -> e_mean -> ep_loop[l] ----------------
__global__ __launch_bounds__(256) void k_const(const float* __restrict__ epart, const float* __restrict__ W2,
                       const float* __restrict__ b2, const float* __restrict__ We,
                       float* __restrict__ eploop){
  __shared__ float red[16][16];
  __shared__ float em[16];
  int tid = threadIdx.x;
  int j = tid & 15, p0 = tid >> 4;
  float s = 0.f;
  for(int p = p0; p < EMLP_BLOCKS; p += 16) s += epart[p*16 + j];
  red[p0][j] = s;
  __syncthreads();
  if(tid < 16){
    #pragma unroll
    for(int k=0;k<16;k++){
      float t = 0.f;
      #pragma unroll
      for(int q=0;q<16;q++) t += red[q][k];
      red[0][k] = t * (1.0f/N_EDGES);
    }
  }
  __syncthreads();
  if(tid < 16){
    float acc = b2[tid];
    #pragma unroll
    for(int k=0;k<16;k++) acc += red[0][k]*W2[k*16 + tid];
    em[tid] = acc;
  }
  __syncthreads();
  for(int l=0;l<NLAYER;l++){
    float acc = 0.f;
    #pragma unroll
    for(int k=0;k<16;k++) acc += em[k]*We[l*EHID*HID + k*HID + tid];
    eploop[l*HID + tid] = acc;
  }
}

__global__ void k_init_small(float* pooled){
  int tid = threadIdx.x;
  for(int i=tid;i<N_GRAPH*HID;i+=256) pooled[i]=0.f;
}

// ---------------- CSR build ----------------
__global__ __launch_bounds__(256) void k_csr_zero(int* __restrict__ counts){
  int i = blockIdx.x*256 + threadIdx.x;
  if(i < N_NODES) counts[i] = 0;
}

__global__ __launch_bounds__(256) void k_csr_count(const int* __restrict__ ei, int* __restrict__ counts){
  int e = blockIdx.x*256 + threadIdx.x;
  if(e < N_EDGES) atomicAdd(&counts[ei[N_EDGES + e]], 1);
}

__global__ __launch_bounds__(1024) void k_csr_scan(const int* __restrict__ counts, int* __restrict__ offs,
                                                   int* __restrict__ cursor){
  __shared__ int part[1024];
  int t = threadIdx.x;
  const int chunk = (N_NODES + 1023) / 1024;
  int b0 = t * chunk;
  int s = 0;
  for(int i=0;i<chunk;i++){ int idx=b0+i; if(idx<N_NODES) s += counts[idx]; }
  part[t] = s;
  __syncthreads();
  for(int off=1; off<1024; off<<=1){
    int v = part[t];
    int add = (t>=off) ? part[t-off] : 0;
    __syncthreads();
    part[t] = v + add;
    __syncthreads();
  }
  int run = (t==0) ? 0 : part[t-1];
  for(int i=0;i<chunk;i++){
    int idx = b0+i;
    if(idx < N_NODES){
      int c = counts[idx];
      offs[idx] = run; cursor[idx] = run;
      run += c;
    }
  }
  if(t == 1023) offs[N_NODES] = part[1023];
}

__global__ __launch_bounds__(256) void k_csr_fill(const int* __restrict__ ei, const float* __restrict__ ea,
                          int* __restrict__ cursor, int2* __restrict__ meta){
  int e = blockIdx.x*256 + threadIdx.x;
  if(e >= N_EDGES) return;
  int d = ei[N_EDGES + e];
  int pos = atomicAdd(&cursor[d], 1);
  meta[pos] = make_int2(ei[e], __float_as_int(ea[e]));
}

// ---------------- fused per-layer: gather + table-ep + online softmax + agg + GELU + residual + LN ----------------
__global__ __launch_bounds__(256) void k_layer(
    const short* __restrict__ xlr, float* __restrict__ h, short* __restrict__ hb,
    const short* __restrict__ tab_l,
    const float* __restrict__ eploop_l, const float* __restrict__ att_l,
    const int* __restrict__ offs, const int2* __restrict__ meta,
    const float* __restrict__ bconv_l, const float* __restrict__ g_l,
    const float* __restrict__ b_l){
  int tid = threadIdx.x;
  int lane = tid & 63;
  int d = blockIdx.x*4 + (tid >> 6);
  float4 at4 = ld4(att_l + lane*4);
  float4 epl = ld4(eploop_l + lane*4);
  float4 bc4 = ld4(bconv_l + lane*4);
  float4 gg4 = ld4(g_l + lane*4);
  float4 bb4 = ld4(b_l + lane*4);
  const short4* xp = (const short4*)(xlr + (long)d*XLRS);
  float4 xld = cvt4(xp[lane]);
  float4 xr4 = cvt4(xp[64 + lane]);
  long hbase = (long)d*HID + lane*4;
  float4 h4 = ld4(h + hbase);
  int beg = offs[d], end = offs[d+1];

  short4 xsb[2], ta[2], tb[2];
  float frv[2];
  auto issue = [&](int slot, int j){
    int2 mm = meta[j];
    float u = __int_as_float(mm.y);
    float f = u * (float)TABN;
    f = fminf(fmaxf(f, 0.f), (float)TABN - 0.001f);
    int i0 = (int)f;
    frv[slot] = f - (float)i0;
    xsb[slot] = ((const short4*)(xlr + (long)mm.x*XLRS))[lane];
    const short4* tp = (const short4*)(tab_l + (long)i0*256);
    ta[slot] = tp[lane];
    tb[slot] = tp[64 + lane];
  };
  auto logit = [&](int slot, float4 &xsf)->float{
    xsf = cvt4(xsb[slot]);
    float4 t0 = cvt4(ta[slot]), t1 = cvt4(tb[slot]);
    float fr = frv[slot];
    float ex = t0.x + fr*(t1.x - t0.x);
    float ey = t0.y + fr*(t1.y - t0.y);
    float ez = t0.z + fr*(t1.z - t0.z);
    float ew = t0.w + fr*(t1.w - t0.w);
    float mx = xsf.x + xr4.x + ex; mx = mx>0.f?mx:0.2f*mx;
    float my = xsf.y + xr4.y + ey; my = my>0.f?my:0.2f*my;
    float mz = xsf.z + xr4.z + ez; mz = mz>0.f?mz:0.2f*mz;
    float mw = xsf.w + xr4.w + ew; mw = mw>0.f?mw:0.2f*mw;
    float q = mx*at4.x + my*at4.y + mz*at4.z + mw*at4.w;
    q += __shfl_xor(q, 1, 16);
    q += __shfl_xor(q, 2, 16);
    q += __shfl_xor(q, 4, 16);
    q += __shfl_xor(q, 8, 16);
    return q;
  };

  int i = beg;
  if(i < end)   issue(0, i);
  if(i+1 < end) issue(1, i+1);
  float ax = xld.x + xr4.x + epl.x; ax = ax>0.f?ax:0.2f*ax;
  float ay = xld.y + xr4.y + epl.y; ay = ay>0.f?ay:0.2f*ay;
  float az = xld.z + xr4.z + epl.z; az = az>0.f?az:0.2f*az;
  float aw = xld.w + xr4.w + epl.w; aw = aw>0.f?aw:0.2f*aw;
  float p = ax*at4.x + ay*at4.y + az*at4.z + aw*at4.w;
  p += __shfl_xor(p, 1, 16);
  p += __shfl_xor(p, 2, 16);
  p += __shfl_xor(p, 4, 16);
  p += __shfl_xor(p, 8, 16);
  float m_run = p;
  float den = 1.f;
  float4 acc = xld;

  for(; i+1 < end; i += 2){
    float4 xs0, xs1;
    float q0 = logit(0, xs0);
    float q1 = logit(1, xs1);
    if(i+2 < end) issue(0, i+2);
    if(i+3 < end) issue(1, i+3);
    float nm = fmaxf(m_run, fmaxf(q0, q1));
    float sc = __expf(m_run - nm);
    float p0 = __expf(q0 - nm);
    float p1 = __expf(q1 - nm);
    den = den*sc + p0 + p1;
    acc.x = acc.x*sc + p0*xs0.x + p1*xs1.x;
    acc.y = acc.y*sc + p0*xs0.y + p1*xs1.y;
    acc.z = acc.z*sc + p0*xs0.z + p1*xs1.z;
    acc.w = acc.w*sc + p0*xs0.w + p1*xs1.w;
    m_run = nm;
  }
  if(i < end){
    float4 xs0;
    float q0 = logit(0, xs0);
    float nm = fmaxf(m_run, q0);
    float sc = __expf(m_run - nm);
    float p0 = __expf(q0 - nm);
    den = den*sc + p0;
    acc.x = acc.x*sc + p0*xs0.x;
    acc.y = acc.y*sc + p0*xs0.y;
    acc.z = acc.z*sc + p0*xs0.z;
    acc.w = acc.w*sc + p0*xs0.w;
    m_run = nm;
  }
  float inv = 1.f/den;
  float yx = geluf(acc.x*inv + bc4.x) + h4.x;
  float yy = geluf(acc.y*inv + bc4.y) + h4.y;
  float yz = geluf(acc.z*inv + bc4.z) + h4.z;
  float yw = geluf(acc.w*inv + bc4.w) + h4.w;
  float mu = wsum64(yx+yy+yz+yw) * (1.0f/HID);
  float dx=yx-mu, dy=yy-mu, dz=yz-mu, dw=yw-mu;
  float var = wsum64(dx*dx+dy*dy+dz*dz+dw*dw) * (1.0f/HID);
  float r = rsqrtf(var + 1e-5f);
  float4 o;
  o.x = dx*r*gg4.x + bb4.x;
  o.y = dy*r*gg4.y + bb4.y;
  o.z = dz*r*gg4.z + bb4.z;
  o.w = dw*r*gg4.w + bb4.w;
  st4(h + hbase, o);
  *(short4*)(hb + hbase) = f2s4(o);
}

// ---------------- gate value per node ----------------
__global__ __launch_bounds__(256) void k_gate2(const float* __restrict__ gh, const float* __restrict__ Wg2,
                       const float* __restrict__ bg2, float* __restrict__ gate){
  int gw = (int)((blockIdx.x * blockDim.x + threadIdx.x) >> 6);
  int lane = threadIdx.x & 63;
  if(gw >= N_NODES) return;
  const float* p = gh + (long)gw*128 + lane*2;
  float t0 = tanhf(p[0]) * Wg2[lane*2];
  float t1 = tanhf(p[1]) * Wg2[lane*2+1];
  float r = wsum64(t0 + t1);
  if(lane == 0) gate[gw] = r + bg2[0];
}

// ---------------- per-graph softmax stats ----------------
__global__ __launch_bounds__(256) void k_gsm(const float* __restrict__ gate, const int* __restrict__ batch,
                     float* __restrict__ gmax, float* __restrict__ gden){
  __shared__ int sr[2];
  __shared__ float red[4];
  int g = blockIdx.x, tid = threadIdx.x;
  if(tid == 0){ sr[0] = lbound(batch, g); sr[1] = lbound(batch, g+1); }
  __syncthreads();
  int r0 = sr[0], r1 = sr[1];
  float mx = -3.4e38f;
  for(int v = r0 + tid; v < r1; v += 256) mx = fmaxf(mx, gate[v]);
  mx = wmax64(mx);
  if((tid&63)==0) red[tid>>6] = mx;
  __syncthreads();
  float m = fmaxf(fmaxf(red[0],red[1]), fmaxf(red[2],red[3]));
  float s = 0.f;
  for(int v = r0 + tid; v < r1; v += 256) s += __expf(gate[v] - m);
  s = wsum64(s);
  if((tid&63)==0) red[tid>>6] = s;
  __syncthreads();
  if(tid == 0){
    gmax[g] = m;
    gden[g] = red[0]+red[1]+red[2]+red[3];
  }
}

// ---------------- pooled[g] += w[v]*h[v] ----------------
__global__ __launch_bounds__(256) void k_gpool(const float* __restrict__ h, const float* __restrict__ gate,
                       const float* __restrict__ gmax, const float* __restrict__ gden,
                       const int* __restrict__ batch, float* __restrict__ pooled){
  __shared__ int sr[2];
  int g = blockIdx.y, c = threadIdx.x;
  if(c == 0){ sr[0] = lbound(batch, g); sr[1] = lbound(batch, g+1); }
  __syncthreads();
  int r0 = sr[0], r1 = sr[1];
  float m = gmax[g], inv = 1.f/gden[g];
  float acc = 0.f;
  for(int v = r0 + blockIdx.x; v < r1; v += 16){
    float w = __expf(gate[v] - m) * inv;
    acc += w * h[(long)v*HID + c];
  }
  atomicAdd(&pooled[g*HID + c], acc);
}

__global__ __launch_bounds__(64) void k_head(const float* __restrict__ pooled, const float* __restrict__ Wh1,
                      const float* __restrict__ bh1, const float* __restrict__ Wh2,
                      const float* __restrict__ bh2, float* __restrict__ out){
  __shared__ float sp[HID];
  int b = blockIdx.x, t = threadIdx.x;
  #pragma unroll
  for(int i=0;i<4;i++) sp[t + i*64] = pooled[b*HID + t + i*64];
  __syncthreads();
  float acc = bh1[t];
  #pragma unroll 8
  for(int k=0;k<HID;k++) acc += sp[k]*Wh1[k*64 + t];
  float g = geluf(acc);
  float contrib = g * Wh2[t];
  float r = wsum64(contrib);
  if(t==0) out[b] = r + bh2[0];
}

extern "C" void kernel_launch(void* const* d_in, const int* in_sizes, int n_in,
                              void* d_out, int out_size, void* d_ws, size_t ws_size,
                              hipStream_t stream) {
  const float* x        = (const float*)d_in[0];
  const float* edge_attr= (const float*)d_in[1];
  const float* W_in     = (const float*)d_in[2];
  const float* b_in     = (const float*)d_in[3];
  const float* ln_in_g  = (const float*)d_in[4];
  const float* ln_in_b  = (const float*)d_in[5];
  const float* W_e1     = (const float*)d_in[6];
  const float* b_e1     = (const float*)d_in[7];
  const float* W_e2     = (const float*)d_in[8];
  const float* b_e2     = (const float*)d_in[9];
  const float* Wl       = (const float*)d_in[10];
  const float* bl       = (const float*)d_in[11];
  const float* Wr       = (const float*)d_in[12];
  const float* br       = (const float*)d_in[13];
  const float* att      = (const float*)d_in[14];
  const float* We       = (const float*)d_in[15];
  const float* bconv    = (const float*)d_in[16];
  const float* ln_g     = (const float*)d_in[17];
  const float* ln_b     = (const float*)d_in[18];
  const float* Wg1      = (const float*)d_in[19];
  const float* bg1      = (const float*)d_in[20];
  const float* Wg2      = (const float*)d_in[21];
  const float* bg2      = (const float*)d_in[22];
  const float* Wh1      = (const float*)d_in[23];
  const float* bh1      = (const float*)d_in[24];
  const float* Wh2      = (const float*)d_in[25];
  const float* bh2      = (const float*)d_in[26];
  const int*   ei       = (const int*)d_in[27];
  const int*   batch    = (const int*)d_in[28];
  float* out = (float*)d_out;

  // ---- workspace layout (float offsets). x_bf16 (12.8M floats, 10.24M..23.04M) is dead
  // after the input GEMM; ONLY buffers first written after it may overlap:
  // buf_xlr (layer GEMM out), buf_tab (k_etab), buf_hb (k_ln_gelu). Everything written
  // before the input GEMM (CSR, weights, small bufs) lives above 23.04M. Total ~24.3M floats.
  float* ws = (float*)d_ws;
  float* buf_h     = ws;                         // 0 .. 5.12M
  float* buf_t     = ws + 5120000;               // 5.12M .. 10.24M (input-proj tmp; gh reuse)
  short* buf_xlr   = (short*)(ws + 10240000);    // N*512 bf16 (2.56M shorts -> 5.12M floats)
  short* x_bf16    = (short*)(ws + 10240000);    // 25.6M shorts = 12.8M floats -> ends 23.04M
  short* buf_tab   = (short*)(ws + 15360000);    // 4*4097*256 shorts -> ends 17,457,664
  short* buf_hb    = (short*)(ws + 17460000);    // N*256 bf16 -> ends 20,020,000
  float* buf_eploop= ws + 23040000;              // 1024
  float* buf_gate  = ws + 23041024;              // 20000
  float* buf_gmax  = ws + 23061024;              // 16
  float* buf_gden  = ws + 23061040;              // 16
  float* buf_pooled= ws + 23061056;              // 4096
  float* buf_epart = ws + 23065200;              // 20000
  int*   csr_offs  = (int*)(ws + 23085200);      // 20001
  int*   csr_cursor= (int*)(ws + 23105204);      // 20000
  int2*  csr_meta  = (int2*)(ws + 23125204);     // 320000 int2 = 640000 ints -> 23,765,204
  short* W_in_t    = (short*)(ws + 23765204);    // 327,680 shorts -> 23,929,044
  short* Wlr_t     = (short*)(ws + 23929044);    // 524,288 shorts -> 24,191,188
  short* Wg1_t     = (short*)(ws + 24191188);    // 32,768 shorts -> 24,207,572
  float* buf_blr   = ws + 24207572;              // 2048
  float* buf_W2e   = ws + 24209620;              // 16384
  float* buf_be    = ws + 24226004;              // 1024 -> 24,227,028 total (~97 MB)
  float* buf_gh    = buf_t;                      // N*128 (reuse)

  // weight prep
  k_wt<<<1280,256,0,stream>>>(W_in, W_in_t, 1280, 256);
  k_wt_lr<<<2048,256,0,stream>>>(Wl, Wr, Wlr_t);
  k_wt<<<128,256,0,stream>>>(Wg1, Wg1_t, 256, 128);
  k_bcat<<<1,256,0,stream>>>(bl, br, buf_blr);
  k_wecomb<<<NLAYER,256,0,stream>>>(W_e2, b_e2, We, buf_W2e, buf_be);

  k_init_small<<<1,256,0,stream>>>(buf_pooled);
  k_csr_zero<<<(N_NODES+255)/256,256,0,stream>>>(csr_cursor);
  k_csr_count<<<(N_EDGES+255)/256,256,0,stream>>>(ei, csr_cursor);
  k_csr_scan<<<1,1024,0,stream>>>(csr_cursor, csr_offs, csr_cursor);
  k_csr_fill<<<(N_EDGES+255)/256,256,0,stream>>>(ei, edge_attr, csr_cursor, csr_meta);

  // x -> bf16, then input proj: x_bf16 @ W_in -> buf_t (fp32, ld=256)
  k_xcvt<<<25000,256,0,stream>>>(x, x_bf16);
  k_gemm_p<0><<<dim3(157,2),256,0,stream>>>(x_bf16, W_in_t, b_in, buf_t, nullptr, N_NODES, NODE_DIMC, 256);
  k_ln_gelu<<<(N_NODES+3)/4,256,0,stream>>>(buf_t, ln_in_g, ln_in_b, buf_h, buf_hb);
  // ep table AFTER input GEMM (tab region overlaps x_bf16)
  k_etab<<<dim3(TABN+1,NLAYER),256,0,stream>>>(W_e1, b_e1, buf_W2e, buf_be, buf_tab);
  k_edge_mlp<<<EMLP_BLOCKS,256,0,stream>>>(edge_attr, W_e1, b_e1, buf_epart);
  k_const<<<1,256,0,stream>>>(buf_epart, W_e2, b_e2, We, buf_eploop);

  for(int l=0;l<NLAYER;l++){
    k_gemm_p<1><<<dim3(157,4),256,0,stream>>>(buf_hb, Wlr_t + (long)l*131072,
                       buf_blr + l*512, nullptr, buf_xlr, N_NODES, HID, XLRS);
    k_layer<<<5000,256,0,stream>>>(buf_xlr, buf_h, buf_hb, buf_tab + (long)l*(TABN+1)*256,
                       buf_eploop + l*HID, att + l*NHEAD*DHEAD,
                       csr_offs, csr_meta, bconv + l*HID, ln_g + l*HID, ln_b + l*HID);
  }

  k_gemm_p<0><<<dim3(157,1),256,0,stream>>>(buf_hb, Wg1_t, bg1, buf_gh, nullptr, N_NODES, HID, 128);
  k_gate2<<<(N_NODES+3)/4,256,0,stream>>>(buf_gh, Wg2, bg2, buf_gate);
  k_gsm<<<N_GRAPH,256,0,stream>>>(buf_gate, batch, buf_gmax, buf_gden);
  dim3 gP(16, N_GRAPH);
  k_gpool<<<gP,256,0,stream>>>(buf_h, buf_gate, buf_gmax, buf_gden, batch, buf_pooled);
  k_head<<<N_GRAPH,64,0,stream>>>(buf_pooled, Wh1, bh1, Wh2, bh2, out);
}

// Round 9
// 739.770 us; speedup vs baseline: 9.5425x; 1.1690x over previous
//
#include <hip/hip_runtime.h>
#include <hip/hip_bf16.h>
#include <math.h>

#define N_NODES 20000
#define N_EDGES 320000
#define N_GRAPH 16
#define HID 256
#define NLAYER 4
#define NHEAD 4
#define DHEAD 64
#define EHID 16
#define NODE_DIMC 1280
#define EMLP_BLOCKS 1250   /* 1250*256 == 320000 exactly */
#define XLRS 512           /* stride of combined xl|xr buffer (in elements) */
#define TABN 4096          /* ep lookup-table knots (rows = TABN+1); nearest-knot lookup */

typedef short short8 __attribute__((ext_vector_type(8)));
typedef float f32x4 __attribute__((ext_vector_type(4)));

__device__ __forceinline__ float4 ld4(const float* p){ return *reinterpret_cast<const float4*>(p); }
__device__ __forceinline__ void st4(float* p, float4 v){ *reinterpret_cast<float4*>(p) = v; }
__device__ __forceinline__ float geluf(float x){ return 0.5f*x*(1.0f+erff(x*0.70710678118654752440f)); }
__device__ __forceinline__ float wsum64(float v){
  #pragma unroll
  for(int o=32;o;o>>=1) v += __shfl_xor(v,o,64);
  return v;
}
__device__ __forceinline__ float wmax64(float v){
  #pragma unroll
  for(int o=32;o;o>>=1) v = fmaxf(v, __shfl_xor(v,o,64));
  return v;
}
__device__ __forceinline__ int lbound(const int* __restrict__ a, int val){
  int lo=0, hi=N_NODES;
  while(lo<hi){ int mid=(lo+hi)>>1; if(a[mid]<val) lo=mid+1; else hi=mid; }
  return lo;
}
__device__ __forceinline__ short cvt_bf16(float f){
  __hip_bfloat16 h = __float2bfloat16(f);
  return *reinterpret_cast<short*>(&h);
}
__device__ __forceinline__ float bf2f(short s){
  return __uint_as_float(((unsigned)(unsigned short)s) << 16);
}
__device__ __forceinline__ float4 cvt4(short4 s){
  float4 r; r.x=bf2f(s.x); r.y=bf2f(s.y); r.z=bf2f(s.z); r.w=bf2f(s.w); return r;
}
__device__ __forceinline__ short4 f2s4(float4 v){
  short4 s; s.x=cvt_bf16(v.x); s.y=cvt_bf16(v.y); s.z=cvt_bf16(v.z); s.w=cvt_bf16(v.w); return s;
}
// async global->LDS, 16B per lane; LDS dest is wave-uniform base + lane*16
__device__ __forceinline__ void glds16(const short* g, short* l){
  __builtin_amdgcn_global_load_lds((const __attribute__((address_space(1))) void*)g,
                                   (__attribute__((address_space(3))) void*)l, 16, 0, 0);
}

// ---------------- fused weight prep (replaces 5 kernels) ----------------
// seg0 W_in_t 327680 | seg1 Wlr_t 524288 | seg2 Wg1_t 32768 | seg3 blr 2048 | seg4 W2e 16384 | seg5 be 1024
#define PREP_TOTAL 904192
__global__ __launch_bounds__(256) void k_prep(const float* __restrict__ W_in, const float* __restrict__ Wl,
    const float* __restrict__ Wr, const float* __restrict__ Wg1, const float* __restrict__ bl,
    const float* __restrict__ br, const float* __restrict__ W2, const float* __restrict__ b2,
    const float* __restrict__ We,
    short* __restrict__ W_in_t, short* __restrict__ Wlr_t, short* __restrict__ Wg1_t,
    float* __restrict__ blr, float* __restrict__ W2e, float* __restrict__ be){
  int idx = blockIdx.x*256 + threadIdx.x;
  if(idx < 327680){
    int n = idx / 1280, k = idx - n*1280;
    W_in_t[idx] = cvt_bf16(W_in[(long)k*256 + n]);
  } else if(idx < 851968){
    int t = idx - 327680;
    int l = t >> 17; int rem = t & 131071; int n = rem >> 8, k = rem & 255;
    const float* W = (n < 256) ? (Wl + (long)l*65536 + (long)k*256 + n)
                               : (Wr + (long)l*65536 + (long)k*256 + (n-256));
    Wlr_t[t] = cvt_bf16(*W);
  } else if(idx < 884736){
    int t = idx - 851968;
    int n = t >> 8, k = t & 255;
    Wg1_t[t] = cvt_bf16(Wg1[(long)k*128 + n]);
  } else if(idx < 886784){
    int t = idx - 884736;
    int l = t >> 9, c = t & 511;
    blr[t] = (c < 256) ? bl[l*256 + c] : br[l*256 + c - 256];
  } else if(idx < 903168){
    int t = idx - 886784;
    int l = t >> 12; int rem = t & 4095; int k = rem >> 8, dd = rem & 255;
    float s = 0.f;
    #pragma unroll
    for(int j=0;j<16;j++) s += W2[k*16+j]*We[l*4096 + j*256 + dd];
    W2e[t] = s;
  } else if(idx < 904192){
    int t = idx - 903168;
    int l = t >> 8, dd = t & 255;
    float s = 0.f;
    #pragma unroll
    for(int j=0;j<16;j++) s += b2[j]*We[l*4096 + j*256 + dd];
    be[t] = s;
  }
}

// ---------------- x fp32 -> bf16 ----------------
__global__ __launch_bounds__(256) void k_xcvt(const float* __restrict__ x, short* __restrict__ xb){
  long i = (long)blockIdx.x*256 + threadIdx.x;
  float4 v = ld4(x + i*4);
  *(short4*)(xb + i*4) = f2s4(v);
}

// ---------------- ep lookup table ----------------
__global__ __launch_bounds__(256) void k_etab(const float* __restrict__ W1, const float* __restrict__ b1,
                      const float* __restrict__ W2e, const float* __restrict__ be,
                      short* __restrict__ tab){
  __shared__ float t[16];
  int idx = blockIdx.x, l = blockIdx.y, d = threadIdx.x;
  if(d < 16) t[d] = geluf(((float)idx*(1.0f/TABN))*W1[d] + b1[d]);
  __syncthreads();
  float s = be[l*256 + d];
  #pragma unroll
  for(int k=0;k<16;k++) s += t[k]*W2e[(l*16+k)*256 + d];
  tab[((long)l*(TABN+1) + idx)*256 + d] = cvt_bf16(s);
}

// ---------------- pipelined bf16 GEMM (async dbuf, raw s_barrier + vmcnt(4)) ----------------
// OUTB: 0 = fp32 C, 1 = bf16 C, 2 = gate mode (N=128; writes gate[row] = tanh(row)·Wg2 + bg2)
template<int OUTB>
__global__ __launch_bounds__(256) void k_gemm_p(const short* __restrict__ A,
    const short* __restrict__ Bt, const float* __restrict__ bias,
    float* __restrict__ Cf, short* __restrict__ Cb,
    const float* __restrict__ Wg2, const float* __restrict__ bg2, float* __restrict__ gate,
    int M, int K, int ldc){
  __shared__ short As[2][128*32];
  __shared__ short Bs[2][128*32];
  int tid = threadIdx.x;
  int w = tid>>6, lane = tid&63;
  int g = lane>>4, m = lane&15;
  int bm = blockIdx.x*128, bn = blockIdx.y*128;
  int crow = lane>>2;
  int coff = (lane&3)*8;
  int ar0 = bm + (w*2+0)*16 + crow; ar0 = ar0 < M ? ar0 : M-1;
  int ar1 = bm + (w*2+1)*16 + crow; ar1 = ar1 < M ? ar1 : M-1;
  const short* Ap0 = A + (long)ar0*K + coff;
  const short* Ap1 = A + (long)ar1*K + coff;
  const short* Bp0 = Bt + (long)(bn + (w*2+0)*16 + crow)*K + coff;
  const short* Bp1 = Bt + (long)(bn + (w*2+1)*16 + crow)*K + coff;
  short* As0 = &As[0][(w*2+0)*512]; short* As1 = &As[0][(w*2+1)*512];
  short* Bs0 = &Bs[0][(w*2+0)*512]; short* Bs1 = &Bs[0][(w*2+1)*512];
  const int bufstride = 128*32;
  f32x4 acc[2][8];
  #pragma unroll
  for(int i=0;i<2;i++)
    #pragma unroll
    for(int j=0;j<8;j++) acc[i][j] = (f32x4){0.f,0.f,0.f,0.f};
  int niter = K >> 5;
  glds16(Ap0, As0); glds16(Ap1, As1); glds16(Bp0, Bs0); glds16(Bp1, Bs1);
  for(int i=0;i<niter;i++){
    int cur = i&1, nxt = cur^1;
    if(i+1 < niter){
      int k = (i+1)<<5;
      glds16(Ap0 + k, As0 + nxt*bufstride);
      glds16(Ap1 + k, As1 + nxt*bufstride);
      glds16(Bp0 + k, Bs0 + nxt*bufstride);
      glds16(Bp1 + k, Bs1 + nxt*bufstride);
      __builtin_amdgcn_s_waitcnt(0x0F74);   // vmcnt(4)
    } else {
      __builtin_amdgcn_s_waitcnt(0x0F70);   // vmcnt(0)
    }
    __builtin_amdgcn_s_barrier();
    const short* ab = &As[cur][0];
    const short* bb = &Bs[cur][0];
    short8 a0 = *(const short8*)&ab[(w*32 + m)*32 + g*8];
    short8 a1 = *(const short8*)&ab[(w*32 + 16 + m)*32 + g*8];
    #pragma unroll
    for(int j=0;j<8;j++){
      short8 bf = *(const short8*)&bb[(j*16 + m)*32 + g*8];
      acc[0][j] = __builtin_amdgcn_mfma_f32_16x16x32_bf16(a0, bf, acc[0][j], 0,0,0);
      acc[1][j] = __builtin_amdgcn_mfma_f32_16x16x32_bf16(a1, bf, acc[1][j], 0,0,0);
    }
    __builtin_amdgcn_s_barrier();
  }
  if(OUTB == 2){
    float bg2v = bg2[0];
    #pragma unroll
    for(int mi=0;mi<2;mi++){
      float part[4] = {0.f,0.f,0.f,0.f};
      #pragma unroll
      for(int j=0;j<8;j++){
        int col = j*16 + m;
        float wg = Wg2[col];
        float bv = bias[col];
        #pragma unroll
        for(int r=0;r<4;r++) part[r] += tanhf(acc[mi][j][r] + bv) * wg;
      }
      #pragma unroll
      for(int r=0;r<4;r++){
        #pragma unroll
        for(int o=1;o<16;o<<=1) part[r] += __shfl_xor(part[r], o, 16);
      }
      if(m == 0){
        #pragma unroll
        for(int r=0;r<4;r++){
          int row = bm + w*32 + mi*16 + g*4 + r;
          if(row < M) gate[row] = part[r] + bg2v;
        }
      }
    }
  } else {
    #pragma unroll
    for(int mi=0;mi<2;mi++){
      int r0 = bm + w*32 + mi*16 + g*4;
      #pragma unroll
      for(int j=0;j<8;j++){
        int col = bn + j*16 + m;
        float bv = bias[col];
        #pragma unroll
        for(int r=0;r<4;r++){
          int row = r0 + r;
          if(row < M){
            float v = acc[mi][j][r] + bv;
            if(OUTB) Cb[(long)row*ldc + col] = cvt_bf16(v);
            else     Cf[(long)row*ldc + col] = v;
          }
        }
      }
    }
  }
}

// ---------------- LayerNorm + GELU (input proj epilogue); writes fp32 h + bf16 h ----------------
__global__ __launch_bounds__(256) void k_ln_gelu(const float* __restrict__ in, const float* __restrict__ g,
                          const float* __restrict__ b, float* __restrict__ out, short* __restrict__ outb){
  int gw = (int)((blockIdx.x * blockDim.x + threadIdx.x) >> 6);
  int lane = threadIdx.x & 63;
  if (gw >= N_NODES) return;
  long base = (long)gw*HID + lane*4;
  float4 v = ld4(in + base);
  float mu = wsum64(v.x+v.y+v.z+v.w) * (1.0f/HID);
  float dx=v.x-mu, dy=v.y-mu, dz=v.z-mu, dw=v.w-mu;
  float var = wsum64(dx*dx+dy*dy+dz*dz+dw*dw) * (1.0f/HID);
  float r = rsqrtf(var + 1e-5f);
  float4 gg = ld4(g + lane*4), bb = ld4(b + lane*4);
  float4 o;
  o.x = geluf(dx*r*gg.x + bb.x);
  o.y = geluf(dy*r*gg.y + bb.y);
  o.z = geluf(dz*r*gg.z + bb.z);
  o.w = geluf(dw*r*gg.w + bb.w);
  st4(out + base, o);
  *(short4*)(outb + base) = f2s4(o);
}

// ---------------- edge MLP t-partials only (mean path) ----------------
__global__ __launch_bounds__(256) void k_edge_mlp(const float* __restrict__ ea, const float* __restrict__ W1,
                          const float* __restrict__ b1, float* __restrict__ epart){
  __shared__ float sW1[16], sB1[16];
  __shared__ float red[4][16];
  int tid = threadIdx.x;
  if(tid<16){ sW1[tid]=W1[tid]; sB1[tid]=b1[tid]; }
  __syncthreads();
  int e = blockIdx.x*256 + tid;
  float u = ea[e];
  int wv = tid>>6, lane = tid&63;
  #pragma unroll
  for(int j=0;j<16;j++){
    float t = geluf(u*sW1[j] + sB1[j]);
    float r = wsum64(t);
    if(lane == 0) red[wv][j] = r;
  }
  __syncthreads();
  if(tid < 16) epart[blockIdx.x*16 + tid] = red[0][tid]+red[1][tid]+red[2][tid]+red[3][tid];
}

// ---------------- reduce t-partials -> e_mean -> ep_loop[l] ----------------
__global__ __launch_bounds__(256) void k_const(const float* __restrict__ epart, const float* __restrict__ W2,
                       const float* __restrict__ b2, const float* __restrict__ We,
                       float* __restrict__ eploop){
  __shared__ float red[16][16];
  __shared__ float em[16];
  int tid = threadIdx.x;
  int j = tid & 15, p0 = tid >> 4;
  float s = 0.f;
  for(int p = p0; p < EMLP_BLOCKS; p += 16) s += epart[p*16 + j];
  red[p0][j] = s;
  __syncthreads();
  if(tid < 16){
    #pragma unroll
    for(int k=0;k<16;k++){
      float t = 0.f;
      #pragma unroll
      for(int q=0;q<16;q++) t += red[q][k];
      red[0][k] = t * (1.0f/N_EDGES);
    }
  }
  __syncthreads();
  if(tid < 16){
    float acc = b2[tid];
    #pragma unroll
    for(int k=0;k<16;k++) acc += red[0][k]*W2[k*16 + tid];
    em[tid] = acc;
  }
  __syncthreads();
  for(int l=0;l<NLAYER;l++){
    float acc = 0.f;
    #pragma unroll
    for(int k=0;k<16;k++) acc += em[k]*We[l*EHID*HID + k*HID + tid];
    eploop[l*HID + tid] = acc;
  }
}

// ---------------- zero cursor + pooled ----------------
__global__ __launch_bounds__(256) void k_zero(int* __restrict__ counts, float* __restrict__ pooled){
  int i = blockIdx.x*256 + threadIdx.x;
  if(i < N_NODES) counts[i] = 0;
  if(i < N_GRAPH*HID) pooled[i] = 0.f;
}

__global__ __launch_bounds__(256) void k_csr_count(const int* __restrict__ ei, int* __restrict__ counts){
  int e = blockIdx.x*256 + threadIdx.x;
  if(e < N_EDGES) atomicAdd(&counts[ei[N_EDGES + e]], 1);
}

__global__ __launch_bounds__(1024) void k_csr_scan(const int* __restrict__ counts, int* __restrict__ offs,
                                                   int* __restrict__ cursor){
  __shared__ int part[1024];
  int t = threadIdx.x;
  const int chunk = (N_NODES + 1023) / 1024;
  int b0 = t * chunk;
  int s = 0;
  for(int i=0;i<chunk;i++){ int idx=b0+i; if(idx<N_NODES) s += counts[idx]; }
  part[t] = s;
  __syncthreads();
  for(int off=1; off<1024; off<<=1){
    int v = part[t];
    int add = (t>=off) ? part[t-off] : 0;
    __syncthreads();
    part[t] = v + add;
    __syncthreads();
  }
  int run = (t==0) ? 0 : part[t-1];
  for(int i=0;i<chunk;i++){
    int idx = b0+i;
    if(idx < N_NODES){
      int c = counts[idx];
      offs[idx] = run; cursor[idx] = run;
      run += c;
    }
  }
  if(t == 1023) offs[N_NODES] = part[1023];
}

__global__ __launch_bounds__(256) void k_csr_fill(const int* __restrict__ ei, const float* __restrict__ ea,
                          int* __restrict__ cursor, int2* __restrict__ meta){
  int e = blockIdx.x*256 + threadIdx.x;
  if(e >= N_EDGES) return;
  int d = ei[N_EDGES + e];
  int pos = atomicAdd(&cursor[d], 1);
  meta[pos] = make_int2(ei[e], __float_as_int(ea[e]));
}

// ---------------- fused per-layer: 4-deep pipelined gather + nearest-knot ep + batched online softmax ----------------
__global__ __launch_bounds__(256) void k_layer(
    const short* __restrict__ xlr, float* __restrict__ h, short* __restrict__ hb,
    const short* __restrict__ tab_l,
    const float* __restrict__ eploop_l, const float* __restrict__ att_l,
    const int* __restrict__ offs, const int2* __restrict__ meta,
    const float* __restrict__ bconv_l, const float* __restrict__ g_l,
    const float* __restrict__ b_l){
  int tid = threadIdx.x;
  int lane = tid & 63;
  int d = blockIdx.x*4 + (tid >> 6);
  float4 at4 = ld4(att_l + lane*4);
  float4 epl = ld4(eploop_l + lane*4);
  const short4* xp = (const short4*)(xlr + (long)d*XLRS);
  float4 xld = cvt4(xp[lane]);
  float4 xr4 = cvt4(xp[64 + lane]);
  long hbase = (long)d*HID + lane*4;
  float4 h4 = ld4(h + hbase);
  int beg = offs[d], end = offs[d+1];

  short4 xsb0, xsb1, xsb2, xsb3, ta0, ta1, ta2, ta3;
  auto issue = [&](short4 &xsb, short4 &ta, int j){
    int2 mm = meta[j];
    float u = __int_as_float(mm.y);
    int i0 = (int)(u * (float)TABN + 0.5f);
    xsb = ((const short4*)(xlr + (long)mm.x*XLRS))[lane];
    ta  = ((const short4*)(tab_l + (long)i0*256))[lane];
  };
  auto logit = [&](short4 xsbv, short4 tav, float4 &xsf)->float{
    xsf = cvt4(xsbv);
    float4 t0 = cvt4(tav);
    float mx = xsf.x + xr4.x + t0.x; mx = mx>0.f?mx:0.2f*mx;
    float my = xsf.y + xr4.y + t0.y; my = my>0.f?my:0.2f*my;
    float mz = xsf.z + xr4.z + t0.z; mz = mz>0.f?mz:0.2f*mz;
    float mw = xsf.w + xr4.w + t0.w; mw = mw>0.f?mw:0.2f*mw;
    float q = mx*at4.x + my*at4.y + mz*at4.z + mw*at4.w;
    q += __shfl_xor(q, 1, 16);
    q += __shfl_xor(q, 2, 16);
    q += __shfl_xor(q, 4, 16);
    q += __shfl_xor(q, 8, 16);
    return q;
  };

  float m_run, den;
  float4 acc;
  auto upd = [&](float q, float4 xs){
    float nm = fmaxf(m_run, q);
    float sc = __expf(m_run - nm);
    float pe = __expf(q - nm);
    den = den*sc + pe;
    acc.x = acc.x*sc + pe*xs.x;
    acc.y = acc.y*sc + pe*xs.y;
    acc.z = acc.z*sc + pe*xs.z;
    acc.w = acc.w*sc + pe*xs.w;
    m_run = nm;
  };

  int i = beg;
  if(beg < end){
    int e1 = (beg+1 < end) ? beg+1 : end-1;
    int e2 = (beg+2 < end) ? beg+2 : end-1;
    int e3 = (beg+3 < end) ? beg+3 : end-1;
    issue(xsb0, ta0, beg);
    issue(xsb1, ta1, e1);
    issue(xsb2, ta2, e2);
    issue(xsb3, ta3, e3);
  }
  // self-loop seed (overlaps prefetch latency)
  float ax = xld.x + xr4.x + epl.x; ax = ax>0.f?ax:0.2f*ax;
  float ay = xld.y + xr4.y + epl.y; ay = ay>0.f?ay:0.2f*ay;
  float az = xld.z + xr4.z + epl.z; az = az>0.f?az:0.2f*az;
  float aw = xld.w + xr4.w + epl.w; aw = aw>0.f?aw:0.2f*aw;
  float p = ax*at4.x + ay*at4.y + az*at4.z + aw*at4.w;
  p += __shfl_xor(p, 1, 16);
  p += __shfl_xor(p, 2, 16);
  p += __shfl_xor(p, 4, 16);
  p += __shfl_xor(p, 8, 16);
  m_run = p;
  den = 1.f;
  acc = xld;

  for(; i+3 < end; i += 4){
    float4 xs0, xs1, xs2, xs3;
    float q0 = logit(xsb0, ta0, xs0);
    float q1 = logit(xsb1, ta1, xs1);
    float q2 = logit(xsb2, ta2, xs2);
    float q3 = logit(xsb3, ta3, xs3);
    int j0 = (i+4 < end) ? i+4 : end-1;
    int j1 = (i+5 < end) ? i+5 : end-1;
    int j2 = (i+6 < end) ? i+6 : end-1;
    int j3 = (i+7 < end) ? i+7 : end-1;
    issue(xsb0, ta0, j0);
    issue(xsb1, ta1, j1);
    issue(xsb2, ta2, j2);
    issue(xsb3, ta3, j3);
    float nm = fmaxf(fmaxf(fmaxf(q0,q1), fmaxf(q2,q3)), m_run);
    float sc = __expf(m_run - nm);
    float p0 = __expf(q0 - nm), p1 = __expf(q1 - nm);
    float p2 = __expf(q2 - nm), p3 = __expf(q3 - nm);
    den = den*sc + ((p0+p1)+(p2+p3));
    acc.x = acc.x*sc + p0*xs0.x + p1*xs1.x + p2*xs2.x + p3*xs3.x;
    acc.y = acc.y*sc + p0*xs0.y + p1*xs1.y + p2*xs2.y + p3*xs3.y;
    acc.z = acc.z*sc + p0*xs0.z + p1*xs1.z + p2*xs2.z + p3*xs3.z;
    acc.w = acc.w*sc + p0*xs0.w + p1*xs1.w + p2*xs2.w + p3*xs3.w;
    m_run = nm;
  }
  // tail (slots hold edges i..i+3 clamped)
  int rem = end - i;
  if(rem > 0){ float4 xs; float q = logit(xsb0, ta0, xs); upd(q, xs); }
  if(rem > 1){ float4 xs; float q = logit(xsb1, ta1, xs); upd(q, xs); }
  if(rem > 2){ float4 xs; float q = logit(xsb2, ta2, xs); upd(q, xs); }

  float inv = 1.f/den;
  float4 bc4 = ld4(bconv_l + lane*4);
  float4 gg4 = ld4(g_l + lane*4);
  float4 bb4 = ld4(b_l + lane*4);
  float yx = geluf(acc.x*inv + bc4.x) + h4.x;
  float yy = geluf(acc.y*inv + bc4.y) + h4.y;
  float yz = geluf(acc.z*inv + bc4.z) + h4.z;
  float yw = geluf(acc.w*inv + bc4.w) + h4.w;
  float mu = wsum64(yx+yy+yz+yw) * (1.0f/HID);
  float dx=yx-mu, dy=yy-mu, dz=yz-mu, dw=yw-mu;
  float var = wsum64(dx*dx+dy*dy+dz*dz+dw*dw) * (1.0f/HID);
  float r = rsqrtf(var + 1e-5f);
  float4 o;
  o.x = dx*r*gg4.x + bb4.x;
  o.y = dy*r*gg4.y + bb4.y;
  o.z = dz*r*gg4.z + bb4.z;
  o.w = dw*r*gg4.w + bb4.w;
  st4(h + hbase, o);
  *(short4*)(hb + hbase) = f2s4(o);
}

// ---------------- per-graph softmax stats ----------------
__global__ __launch_bounds__(256) void k_gsm(const float* __restrict__ gate, const int* __restrict__ batch,
                     float* __restrict__ gmax, float* __restrict__ gden){
  __shared__ int sr[2];
  __shared__ float red[4];
  int g = blockIdx.x, tid = threadIdx.x;
  if(tid == 0){ sr[0] = lbound(batch, g); sr[1] = lbound(batch, g+1); }
  __syncthreads();
  int r0 = sr[0], r1 = sr[1];
  float mx = -3.4e38f;
  for(int v = r0 + tid; v < r1; v += 256) mx = fmaxf(mx, gate[v]);
  mx = wmax64(mx);
  if((tid&63)==0) red[tid>>6] = mx;
  __syncthreads();
  float m = fmaxf(fmaxf(red[0],red[1]), fmaxf(red[2],red[3]));
  float s = 0.f;
  for(int v = r0 + tid; v < r1; v += 256) s += __expf(gate[v] - m);
  s = wsum64(s);
  if((tid&63)==0) red[tid>>6] = s;
  __syncthreads();
  if(tid == 0){
    gmax[g] = m;
    gden[g] = red[0]+red[1]+red[2]+red[3];
  }
}

// ---------------- pooled[g] += w[v]*h[v] ----------------
__global__ __launch_bounds__(256) void k_gpool(const float* __restrict__ h, const float* __restrict__ gate,
                       const float* __restrict__ gmax, const float* __restrict__ gden,
                       const int* __restrict__ batch, float* __restrict__ pooled){
  __shared__ int sr[2];
  int g = blockIdx.y, c = threadIdx.x;
  if(c == 0){ sr[0] = lbound(batch, g); sr[1] = lbound(batch, g+1); }
  __syncthreads();
  int r0 = sr[0], r1 = sr[1];
  float m = gmax[g], inv = 1.f/gden[g];
  float acc = 0.f;
  for(int v = r0 + blockIdx.x; v < r1; v += 16){
    float w = __expf(gate[v] - m) * inv;
    acc += w * h[(long)v*HID + c];
  }
  atomicAdd(&pooled[g*HID + c], acc);
}

__global__ __launch_bounds__(64) void k_head(const float* __restrict__ pooled, const float* __restrict__ Wh1,
                      const float* __restrict__ bh1, const float* __restrict__ Wh2,
                      const float* __restrict__ bh2, float* __restrict__ out){
  __shared__ float sp[HID];
  int b = blockIdx.x, t = threadIdx.x;
  #pragma unroll
  for(int i=0;i<4;i++) sp[t + i*64] = pooled[b*HID + t + i*64];
  __syncthreads();
  float acc = bh1[t];
  #pragma unroll 8
  for(int k=0;k<HID;k++) acc += sp[k]*Wh1[k*64 + t];
  float g = geluf(acc);
  float contrib = g * Wh2[t];
  float r = wsum64(contrib);
  if(t==0) out[b] = r + bh2[0];
}

extern "C" void kernel_launch(void* const* d_in, const int* in_sizes, int n_in,
                              void* d_out, int out_size, void* d_ws, size_t ws_size,
                              hipStream_t stream) {
  const float* x        = (const float*)d_in[0];
  const float* edge_attr= (const float*)d_in[1];
  const float* W_in     = (const float*)d_in[2];
  const float* b_in     = (const float*)d_in[3];
  const float* ln_in_g  = (const float*)d_in[4];
  const float* ln_in_b  = (const float*)d_in[5];
  const float* W_e1     = (const float*)d_in[6];
  const float* b_e1     = (const float*)d_in[7];
  const float* W_e2     = (const float*)d_in[8];
  const float* b_e2     = (const float*)d_in[9];
  const float* Wl       = (const float*)d_in[10];
  const float* bl       = (const float*)d_in[11];
  const float* Wr       = (const float*)d_in[12];
  const float* br       = (const float*)d_in[13];
  const float* att      = (const float*)d_in[14];
  const float* We       = (const float*)d_in[15];
  const float* bconv    = (const float*)d_in[16];
  const float* ln_g     = (const float*)d_in[17];
  const float* ln_b     = (const float*)d_in[18];
  const float* Wg1      = (const float*)d_in[19];
  const float* bg1      = (const float*)d_in[20];
  const float* Wg2      = (const float*)d_in[21];
  const float* bg2      = (const float*)d_in[22];
  const float* Wh1      = (const float*)d_in[23];
  const float* bh1      = (const float*)d_in[24];
  const float* Wh2      = (const float*)d_in[25];
  const float* bh2      = (const float*)d_in[26];
  const int*   ei       = (const int*)d_in[27];
  const int*   batch    = (const int*)d_in[28];
  float* out = (float*)d_out;

  // ---- workspace layout (float offsets). x_bf16 (10.24M..23.04M) is dead after input GEMM;
  // only buf_xlr / buf_tab / buf_hb (first written after it) overlap that region.
  float* ws = (float*)d_ws;
  float* buf_h     = ws;                         // 0 .. 5.12M
  float* buf_t     = ws + 5120000;               // 5.12M .. 10.24M (input-proj tmp)
  short* buf_xlr   = (short*)(ws + 10240000);    // N*512 bf16
  short* x_bf16    = (short*)(ws + 10240000);    // 25.6M shorts -> ends 23.04M
  short* buf_tab   = (short*)(ws + 15360000);    // 4*4097*256 bf16
  short* buf_hb    = (short*)(ws + 17460000);    // N*256 bf16
  float* buf_eploop= ws + 23040000;              // 1024
  float* buf_gate  = ws + 23041024;              // 20000
  float* buf_gmax  = ws + 23061024;              // 16
  float* buf_gden  = ws + 23061040;              // 16
  float* buf_pooled= ws + 23061056;              // 4096
  float* buf_epart = ws + 23065200;              // 20000
  int*   csr_offs  = (int*)(ws + 23085200);      // 20001
  int*   csr_cursor= (int*)(ws + 23105204);      // 20000
  int2*  csr_meta  = (int2*)(ws + 23125204);     // 320000 int2
  short* W_in_t    = (short*)(ws + 23765204);    // 327,680 shorts
  short* Wlr_t     = (short*)(ws + 23929044);    // 524,288 shorts
  short* Wg1_t     = (short*)(ws + 24191188);    // 32,768 shorts
  float* buf_blr   = ws + 24207572;              // 2048
  float* buf_W2e   = ws + 24209620;              // 16384
  float* buf_be    = ws + 24226004;              // 1024

  // fused weight prep + CSR
  k_prep<<<(PREP_TOTAL+255)/256,256,0,stream>>>(W_in, Wl, Wr, Wg1, bl, br, W_e2, b_e2, We,
                                                W_in_t, Wlr_t, Wg1_t, buf_blr, buf_W2e, buf_be);
  k_zero<<<(N_NODES+255)/256,256,0,stream>>>(csr_cursor, buf_pooled);
  k_csr_count<<<(N_EDGES+255)/256,256,0,stream>>>(ei, csr_cursor);
  k_csr_scan<<<1,1024,0,stream>>>(csr_cursor, csr_offs, csr_cursor);
  k_csr_fill<<<(N_EDGES+255)/256,256,0,stream>>>(ei, edge_attr, csr_cursor, csr_meta);

  // x -> bf16, input proj, epilogue
  k_xcvt<<<25000,256,0,stream>>>(x, x_bf16);
  k_gemm_p<0><<<dim3(157,2),256,0,stream>>>(x_bf16, W_in_t, b_in, buf_t, nullptr,
                                            nullptr, nullptr, nullptr, N_NODES, NODE_DIMC, 256);
  k_ln_gelu<<<(N_NODES+3)/4,256,0,stream>>>(buf_t, ln_in_g, ln_in_b, buf_h, buf_hb);
  k_etab<<<dim3(TABN+1,NLAYER),256,0,stream>>>(W_e1, b_e1, buf_W2e, buf_be, buf_tab);
  k_edge_mlp<<<EMLP_BLOCKS,256,0,stream>>>(edge_attr, W_e1, b_e1, buf_epart);
  k_const<<<1,256,0,stream>>>(buf_epart, W_e2, b_e2, We, buf_eploop);

  for(int l=0;l<NLAYER;l++){
    k_gemm_p<1><<<dim3(157,4),256,0,stream>>>(buf_hb, Wlr_t + (long)l*131072,
                       buf_blr + l*512, nullptr, buf_xlr,
                       nullptr, nullptr, nullptr, N_NODES, HID, XLRS);
    k_layer<<<5000,256,0,stream>>>(buf_xlr, buf_h, buf_hb, buf_tab + (long)l*(TABN+1)*256,
                       buf_eploop + l*HID, att + l*NHEAD*DHEAD,
                       csr_offs, csr_meta, bconv + l*HID, ln_g + l*HID, ln_b + l*HID);
  }

  // gate fused into GEMM epilogue
  k_gemm_p<2><<<dim3(157,1),256,0,stream>>>(buf_hb, Wg1_t, bg1, nullptr, nullptr,
                                            Wg2, bg2, buf_gate, N_NODES, HID, 0);
  k_gsm<<<N_GRAPH,256,0,stream>>>(buf_gate, batch, buf_gmax, buf_gden);
  dim3 gP(16, N_GRAPH);
  k_gpool<<<gP,256,0,stream>>>(buf_h, buf_gate, buf_gmax, buf_gden, batch, buf_pooled);
  k_head<<<N_GRAPH,64,0,stream>>>(buf_pooled, Wh1, bh1, Wh2, bh2, out);
}